// Round 2
// baseline (1398.360 us; speedup 1.0000x reference)
//
#include <hip/hip_runtime.h>
#include <math.h>

#define N_NODES 50000
#define N_EDGES 600000
#define E_TOT   650000   // N_EDGES + N_NODES (self loops appended)
#define F_IN    128
#define HID     64
#define HEADS   8
#define H1      512      // HEADS*HID
#define NCLS    16
#define NC      16
#define NCP     16

typedef unsigned short u16;

__device__ __forceinline__ float bf2f(u16 h) {
    return __uint_as_float(((unsigned)h) << 16);
}
__device__ __forceinline__ u16 f2bf(float f) {
    unsigned u = __float_as_uint(f);
    u += 0x7fffu + ((u >> 16) & 1u);
    return (u16)(u >> 16);
}
__device__ __forceinline__ int edge_src(const int* __restrict__ ei, int e) {
    return (e < N_EDGES) ? ei[e] : (e - N_EDGES);
}
__device__ __forceinline__ int edge_dst(const int* __restrict__ ei, int e) {
    return (e < N_EDGES) ? ei[N_EDGES + e] : (e - N_EDGES);
}

// ---------------- CSR build ----------------
__global__ __launch_bounds__(256) void count_k(const int* __restrict__ ei,
                                               int* __restrict__ src_cnt, int* __restrict__ dst_cnt) {
    int e = blockIdx.x * 256 + threadIdx.x;
    if (e >= E_TOT) return;
    atomicAdd(&src_cnt[edge_src(ei, e)], 1);
    atomicAdd(&dst_cnt[edge_dst(ei, e)], 1);
}

__global__ __launch_bounds__(1024) void scan2_k(const int* __restrict__ src_cnt, const int* __restrict__ dst_cnt,
                                                int* __restrict__ src_off, int* __restrict__ dst_off) {
    __shared__ int lds[1024];
    const int t = threadIdx.x;
    const int CH = (N_NODES + 1023) / 1024;   // 49
    for (int pass = 0; pass < 2; ++pass) {
        const int* cnt = pass ? dst_cnt : src_cnt;
        int* off = pass ? dst_off : src_off;
        int base = t * CH;
        int run = 0;
        for (int i = 0; i < CH; ++i) {
            int idx = base + i;
            run += (idx < N_NODES) ? cnt[idx] : 0;
        }
        lds[t] = run;
        __syncthreads();
        for (int d = 1; d < 1024; d <<= 1) {
            int v = (t >= d) ? lds[t - d] : 0;
            __syncthreads();
            lds[t] += v;
            __syncthreads();
        }
        int prefix = (t == 0) ? 0 : lds[t - 1];
        if (t == 1023) off[N_NODES] = lds[1023];
        for (int i = 0; i < CH; ++i) {
            int idx = base + i;
            if (idx < N_NODES) {
                off[idx] = prefix;
                prefix += cnt[idx];
            }
        }
        __syncthreads();
    }
}

__global__ __launch_bounds__(256) void fill_csr_k(const int* __restrict__ ei,
                                                  const int* __restrict__ src_off, const int* __restrict__ dst_off,
                                                  int* __restrict__ src_cur, int* __restrict__ dst_cur,
                                                  int* __restrict__ src_list, int* __restrict__ dst_list) {
    int e = blockIdx.x * 256 + threadIdx.x;
    if (e >= E_TOT) return;
    int s = edge_src(ei, e), d = edge_dst(ei, e);
    int ps = atomicAdd(&src_cur[s], 1);
    src_list[src_off[s] + ps] = e;
    int pd = atomicAdd(&dst_cur[d], 1);
    dst_list[dst_off[d] + pd] = e;
}

// ---------------- generic 64x64-tile f32 GEMM, fused epilogues ----------------
// EPI 0: C = A@B
// EPI 1: C = leaky_relu(A@B, 0.2)
// EPI 3: C = relu(extra + bias2 + alpha * leaky_relu(A@B + bias, 0.01))   (in-place safe: extra may alias C)
template<int EPI, bool ABF, bool CBF>
__global__ __launch_bounds__(256) void gemm_k(
    const void* __restrict__ A_, const float* __restrict__ B, void* __restrict__ C_,
    int M, int Nn, int K,
    const float* __restrict__ bias, const float* __restrict__ extra,
    const float* __restrict__ bias2, const float* __restrict__ alpha_p)
{
    __shared__ float Ast[16][64];   // [k][m]
    __shared__ float Bs[16][64];    // [k][n]
    const int bm = blockIdx.y * 64;
    const int bn = blockIdx.x * 64;
    const int t  = threadIdx.x;
    const int tx = t & 15, ty = t >> 4;
    const int tm0 = ty * 4, tn0 = tx * 4;
    const int a_m = t >> 2, a_k = (t & 3) * 4;
    const int b_k = t >> 4, b_n = (t & 15) * 4;
    const int arow = bm + a_m;
    const bool aok = arow < M;
    const float* Bptr = B + (size_t)b_k * Nn + bn + b_n;
    float acc[4][4] = {{0.f}};

    for (int k0 = 0; k0 < K; k0 += 16) {
        float4 av = make_float4(0.f, 0.f, 0.f, 0.f);
        if (aok) {
            if constexpr (ABF) {
                const u16* Ab = (const u16*)A_;
                ushort4 h4 = *(const ushort4*)(Ab + (size_t)arow * K + a_k + k0);
                av = make_float4(bf2f(h4.x), bf2f(h4.y), bf2f(h4.z), bf2f(h4.w));
            } else {
                const float* Af = (const float*)A_;
                av = *(const float4*)(Af + (size_t)arow * K + a_k + k0);
            }
        }
        float4 bv = *(const float4*)(Bptr + (size_t)k0 * Nn);
        Ast[a_k + 0][a_m] = av.x;
        Ast[a_k + 1][a_m] = av.y;
        Ast[a_k + 2][a_m] = av.z;
        Ast[a_k + 3][a_m] = av.w;
        *(float4*)&Bs[b_k][b_n] = bv;
        __syncthreads();
        #pragma unroll
        for (int kk = 0; kk < 16; ++kk) {
            float4 a4 = *(const float4*)&Ast[kk][tm0];
            float4 b4 = *(const float4*)&Bs[kk][tn0];
            float a[4] = {a4.x, a4.y, a4.z, a4.w};
            float b[4] = {b4.x, b4.y, b4.z, b4.w};
            #pragma unroll
            for (int i = 0; i < 4; ++i)
                #pragma unroll
                for (int j = 0; j < 4; ++j)
                    acc[i][j] = fmaf(a[i], b[j], acc[i][j]);
        }
        __syncthreads();
    }

    float alpha = 0.f;
    if (EPI == 3) alpha = *alpha_p;

    #pragma unroll
    for (int i = 0; i < 4; ++i) {
        int r = bm + tm0 + i;
        if (r >= M) continue;
        int c0 = bn + tn0;
        float v[4];
        #pragma unroll
        for (int j = 0; j < 4; ++j) v[j] = acc[i][j];
        if (EPI == 1) {
            #pragma unroll
            for (int j = 0; j < 4; ++j) v[j] = v[j] > 0.f ? v[j] : 0.2f * v[j];
        } else if (EPI == 3) {
            float4 ag = *(const float4*)(extra + (size_t)r * Nn + c0);
            float agv[4] = {ag.x, ag.y, ag.z, ag.w};
            #pragma unroll
            for (int j = 0; j < 4; ++j) {
                float p = v[j] + bias[c0 + j];
                p = p > 0.f ? p : 0.01f * p;
                float o = agv[j] + bias2[c0 + j] + alpha * p;
                v[j] = fmaxf(o, 0.f);
            }
        }
        if constexpr (CBF) {
            u16* Cb = (u16*)C_;
            ushort4 pk;
            pk.x = f2bf(v[0]); pk.y = f2bf(v[1]); pk.z = f2bf(v[2]); pk.w = f2bf(v[3]);
            *(ushort4*)(Cb + (size_t)r * Nn + c0) = pk;
        } else {
            *(float4*)((float*)C_ + (size_t)r * Nn + c0) = make_float4(v[0], v[1], v[2], v[3]);
        }
    }
}

// ---------------- N=16 GEMM (xh2 = h @ W_src2), K multiple of 64 ----------------
__global__ __launch_bounds__(256) void gemm_n16_k(
    const float* __restrict__ A, const float* __restrict__ B, float* __restrict__ C,
    int M, int K)
{
    __shared__ float As[16][64];   // [row][k]
    __shared__ float Bs[64][16];   // [k][col]
    const int row0 = blockIdx.x * 16;
    const int t = threadIdx.x;
    const int r = t >> 4, c = t & 15;
    const int ar = t >> 4, ak4 = (t & 15) * 4;
    const int bk = t >> 2, bc4 = (t & 3) * 4;
    float acc = 0.f;
    for (int k0 = 0; k0 < K; k0 += 64) {
        float4 av = make_float4(0.f, 0.f, 0.f, 0.f);
        if (row0 + ar < M) av = *(const float4*)(A + (size_t)(row0 + ar) * K + k0 + ak4);
        *(float4*)&As[ar][ak4] = av;
        *(float4*)&Bs[bk][bc4] = *(const float4*)(B + (size_t)(k0 + bk) * 16 + bc4);
        __syncthreads();
        #pragma unroll
        for (int kk = 0; kk < 64; ++kk)
            acc = fmaf(As[r][kk], Bs[kk][c], acc);
        __syncthreads();
    }
    if (row0 + r < M) C[(size_t)(row0 + r) * 16 + c] = acc;
}

// ---------------- fused per-edge MLP, layer 1 (16 -> 64 -> 64), e = exp(ew) bf16 ----------------
__global__ __launch_bounds__(256) void edge_mlp1_k(
    const float* __restrict__ kr, const float* __restrict__ w1,
    const float* __restrict__ w2, const float* __restrict__ b2,
    u16* __restrict__ eb)
{
    __shared__ float sw1[NC * HID];
    __shared__ float sw2[HID * HID];
    __shared__ float sb2[HID];
    const int t = threadIdx.x;
    for (int i = t; i < NC * HID; i += 256) sw1[i] = w1[i];
    for (int i = t; i < HID * HID; i += 256) sw2[i] = w2[i];
    if (t < HID) sb2[t] = b2[t];
    __syncthreads();
    const int e = blockIdx.x * 256 + t;
    if (e >= E_TOT) return;
    float kri[NC];
    #pragma unroll
    for (int j4 = 0; j4 < NC; j4 += 4) {
        float4 v = *(const float4*)(kr + (size_t)e * NC + j4);
        kri[j4] = v.x; kri[j4 + 1] = v.y; kri[j4 + 2] = v.z; kri[j4 + 3] = v.w;
    }
    float tt[HID];
    #pragma unroll
    for (int c4 = 0; c4 < HID; c4 += 4) {
        float o0 = 0.f, o1 = 0.f, o2 = 0.f, o3 = 0.f;
        #pragma unroll
        for (int j = 0; j < NC; ++j) {
            float4 w = *(const float4*)&sw1[j * HID + c4];
            float kj = kri[j];
            o0 = fmaf(kj, w.x, o0); o1 = fmaf(kj, w.y, o1);
            o2 = fmaf(kj, w.z, o2); o3 = fmaf(kj, w.w, o3);
        }
        tt[c4 + 0] = o0 > 0.f ? o0 : 0.2f * o0;
        tt[c4 + 1] = o1 > 0.f ? o1 : 0.2f * o1;
        tt[c4 + 2] = o2 > 0.f ? o2 : 0.2f * o2;
        tt[c4 + 3] = o3 > 0.f ? o3 : 0.2f * o3;
    }
    #pragma unroll
    for (int c4 = 0; c4 < HID; c4 += 4) {
        float o0 = sb2[c4], o1 = sb2[c4 + 1], o2 = sb2[c4 + 2], o3 = sb2[c4 + 3];
        #pragma unroll
        for (int j = 0; j < HID; ++j) {
            float4 w = *(const float4*)&sw2[j * HID + c4];
            float tj = tt[j];
            o0 = fmaf(tj, w.x, o0); o1 = fmaf(tj, w.y, o1);
            o2 = fmaf(tj, w.z, o2); o3 = fmaf(tj, w.w, o3);
        }
        ushort4 pk;
        pk.x = f2bf(__expf(o0)); pk.y = f2bf(__expf(o1));
        pk.z = f2bf(__expf(o2)); pk.w = f2bf(__expf(o3));
        *(ushort4*)(eb + (size_t)e * HID + c4) = pk;
    }
}

// ---------------- fused per-edge MLP, layer 2 (16 -> 16 -> 16), e = exp(ew) bf16 ----------------
__global__ __launch_bounds__(256) void edge_mlp2_k(
    const float* __restrict__ kr, const float* __restrict__ w1,
    const float* __restrict__ w2, const float* __restrict__ b2,
    u16* __restrict__ eb)
{
    __shared__ float sw1[NC * NCLS];
    __shared__ float sw2[NCLS * NCLS];
    __shared__ float sb2[NCLS];
    const int t = threadIdx.x;
    sw1[t] = w1[t];
    sw2[t] = w2[t];
    if (t < NCLS) sb2[t] = b2[t];
    __syncthreads();
    const int e = blockIdx.x * 256 + t;
    if (e >= E_TOT) return;
    float kri[NC];
    #pragma unroll
    for (int j4 = 0; j4 < NC; j4 += 4) {
        float4 v = *(const float4*)(kr + (size_t)e * NC + j4);
        kri[j4] = v.x; kri[j4 + 1] = v.y; kri[j4 + 2] = v.z; kri[j4 + 3] = v.w;
    }
    float tt[NCLS];
    #pragma unroll
    for (int c4 = 0; c4 < NCLS; c4 += 4) {
        float o[4] = {0.f, 0.f, 0.f, 0.f};
        #pragma unroll
        for (int j = 0; j < NC; ++j) {
            float4 w = *(const float4*)&sw1[j * NCLS + c4];
            float kj = kri[j];
            o[0] = fmaf(kj, w.x, o[0]); o[1] = fmaf(kj, w.y, o[1]);
            o[2] = fmaf(kj, w.z, o[2]); o[3] = fmaf(kj, w.w, o[3]);
        }
        #pragma unroll
        for (int q = 0; q < 4; ++q) tt[c4 + q] = o[q] > 0.f ? o[q] : 0.2f * o[q];
    }
    #pragma unroll
    for (int c4 = 0; c4 < NCLS; c4 += 4) {
        float o[4] = {sb2[c4], sb2[c4 + 1], sb2[c4 + 2], sb2[c4 + 3]};
        #pragma unroll
        for (int j = 0; j < NCLS; ++j) {
            float4 w = *(const float4*)&sw2[j * NCLS + c4];
            float tj = tt[j];
            o[0] = fmaf(tj, w.x, o[0]); o[1] = fmaf(tj, w.y, o[1]);
            o[2] = fmaf(tj, w.z, o[2]); o[3] = fmaf(tj, w.w, o[3]);
        }
        ushort4 pk;
        pk.x = f2bf(__expf(o[0])); pk.y = f2bf(__expf(o[1]));
        pk.z = f2bf(__expf(o[2])); pk.w = f2bf(__expf(o[3]));
        *(ushort4*)(eb + (size_t)e * NCLS + c4) = pk;
    }
}

// ---------------- softmax denominator + in-place normalize, layer 1 (wave per src) ----------------
__global__ __launch_bounds__(256) void s1norm_k(
    u16* __restrict__ eb, const int* __restrict__ src_off, const int* __restrict__ src_list)
{
    int gid = blockIdx.x * 256 + threadIdx.x;
    int wid = gid >> 6, lane = gid & 63;
    if (wid >= N_NODES) return;
    int o0 = src_off[wid], o1 = src_off[wid + 1];
    float sum = 0.f;
    for (int i = o0; i < o1; ++i) {
        int el = src_list[i];
        sum += bf2f(eb[(size_t)el * HID + lane]);
    }
    float inv = 1.f / (sum + 1e-16f);
    for (int i = o0; i < o1; ++i) {
        int el = src_list[i];
        size_t ix = (size_t)el * HID + lane;
        eb[ix] = f2bf(bf2f(eb[ix]) * inv);
    }
}

// ---------------- message pass 1 (wave per dst, 8 heads x 64 ch), no atomics ----------------
__global__ __launch_bounds__(256) void msg1_k(
    const u16* __restrict__ eb, const u16* __restrict__ xb, const int* __restrict__ ei,
    const int* __restrict__ dst_off, const int* __restrict__ dst_list,
    float* __restrict__ agg)
{
    int gid = blockIdx.x * 256 + threadIdx.x;
    int wid = gid >> 6, lane = gid & 63;
    if (wid >= N_NODES) return;
    int o0 = dst_off[wid], o1 = dst_off[wid + 1];
    float acc[HEADS] = {0.f, 0.f, 0.f, 0.f, 0.f, 0.f, 0.f, 0.f};
    for (int i = o0; i < o1; ++i) {
        int el = dst_list[i];
        int s = edge_src(ei, el);
        float a = bf2f(eb[(size_t)el * HID + lane]);
        const u16* xr = xb + (size_t)s * H1 + lane;
        #pragma unroll
        for (int h = 0; h < HEADS; ++h)
            acc[h] = fmaf(a, bf2f(xr[h * 64]), acc[h]);
    }
    float* ar = agg + (size_t)wid * H1 + lane;
    #pragma unroll
    for (int h = 0; h < HEADS; ++h) ar[h * 64] = acc[h];
}

// ---------------- layer-2 normalize (16 threads per src) ----------------
__global__ __launch_bounds__(256) void s2norm_k(
    u16* __restrict__ eb, const int* __restrict__ src_off, const int* __restrict__ src_list)
{
    int t = threadIdx.x;
    int g = blockIdx.x * 16 + (t >> 4), c = t & 15;
    if (g >= N_NODES) return;
    int o0 = src_off[g], o1 = src_off[g + 1];
    float sum = 0.f;
    for (int i = o0; i < o1; ++i) {
        int el = src_list[i];
        sum += bf2f(eb[(size_t)el * NCLS + c]);
    }
    float inv = 1.f / (sum + 1e-16f);
    for (int i = o0; i < o1; ++i) {
        int el = src_list[i];
        size_t ix = (size_t)el * NCLS + c;
        eb[ix] = f2bf(bf2f(eb[ix]) * inv);
    }
}

// ---------------- message pass 2 (16 threads per dst), no atomics ----------------
__global__ __launch_bounds__(256) void msg2_k(
    const u16* __restrict__ eb, const float* __restrict__ xh2, const int* __restrict__ ei,
    const int* __restrict__ dst_off, const int* __restrict__ dst_list,
    float* __restrict__ agg2)
{
    int t = threadIdx.x;
    int g = blockIdx.x * 16 + (t >> 4), c = t & 15;
    if (g >= N_NODES) return;
    int o0 = dst_off[g], o1 = dst_off[g + 1];
    float acc = 0.f;
    for (int i = o0; i < o1; ++i) {
        int el = dst_list[i];
        int s = edge_src(ei, el);
        acc = fmaf(bf2f(eb[(size_t)el * NCLS + c]), xh2[(size_t)s * NCLS + c], acc);
    }
    agg2[(size_t)g * NCLS + c] = acc;
}

// ---------------- final: o = agg2 + bias2 + alpha*p2; log_softmax ----------------
__global__ __launch_bounds__(256) void final_k(
    const float* __restrict__ agg2, const float* __restrict__ ep,
    const float* __restrict__ pw1, const float* __restrict__ pw2,
    const float* __restrict__ pb2, const float* __restrict__ bias,
    const float* __restrict__ alpha_p, float* __restrict__ out)
{
    __shared__ float s1w[256], s2w[256], sb[16], sbias[16];
    const int t = threadIdx.x;
    s1w[t] = pw1[t];
    s2w[t] = pw2[t];
    if (t < 16) { sb[t] = pb2[t]; sbias[t] = bias[t]; }
    __syncthreads();
    const int v = blockIdx.x * 256 + t;
    if (v >= N_NODES) return;
    float alpha = *alpha_p;
    float e_[16];
    #pragma unroll
    for (int j4 = 0; j4 < 16; j4 += 4) {
        float4 vv = *(const float4*)(ep + (size_t)v * 16 + j4);
        e_[j4] = vv.x; e_[j4 + 1] = vv.y; e_[j4 + 2] = vv.z; e_[j4 + 3] = vv.w;
    }
    float t2[16];
    #pragma unroll
    for (int c = 0; c < 16; ++c) {
        float s = 0.f;
        #pragma unroll
        for (int j = 0; j < 16; ++j) s = fmaf(e_[j], s1w[j * 16 + c], s);
        t2[c] = s > 0.f ? s : 0.2f * s;
    }
    float o[16];
    #pragma unroll
    for (int c4 = 0; c4 < 16; c4 += 4) {
        float4 ag = *(const float4*)(agg2 + (size_t)v * 16 + c4);
        float agv[4] = {ag.x, ag.y, ag.z, ag.w};
        #pragma unroll
        for (int q = 0; q < 4; ++q) {
            int c = c4 + q;
            float p = sb[c];
            #pragma unroll
            for (int j = 0; j < 16; ++j) p = fmaf(t2[j], s2w[j * 16 + c], p);
            p = p > 0.f ? p : 0.01f * p;
            o[c] = agv[q] + sbias[c] + alpha * p;
        }
    }
    float mx = o[0];
    #pragma unroll
    for (int c = 1; c < 16; ++c) mx = fmaxf(mx, o[c]);
    float se = 0.f;
    #pragma unroll
    for (int c = 0; c < 16; ++c) se += expf(o[c] - mx);
    float lse = mx + logf(se);
    #pragma unroll
    for (int c4 = 0; c4 < 16; c4 += 4)
        *(float4*)(out + (size_t)v * 16 + c4) =
            make_float4(o[c4] - lse, o[c4 + 1] - lse, o[c4 + 2] - lse, o[c4 + 3] - lse);
}

extern "C" void kernel_launch(void* const* d_in, const int* in_sizes, int n_in,
                              void* d_out, int out_size, void* d_ws, size_t ws_size,
                              hipStream_t stream) {
    const float* x    = (const float*)d_in[0];
    const int*   ei   = (const int*)d_in[1];
    const float* alpha= (const float*)d_in[2];
    const float* kr   = (const float*)d_in[3];
    const float* ep   = (const float*)d_in[4];
    const float* W1   = (const float*)d_in[5];
    const float* h1w1 = (const float*)d_in[6];
    const float* h1w2 = (const float*)d_in[7];
    const float* h1b2 = (const float*)d_in[8];
    const float* p1w1 = (const float*)d_in[9];
    const float* p1w2 = (const float*)d_in[10];
    const float* p1b2 = (const float*)d_in[11];
    const float* b1   = (const float*)d_in[12];
    const float* W2   = (const float*)d_in[13];
    const float* h2w1 = (const float*)d_in[14];
    const float* h2w2 = (const float*)d_in[15];
    const float* h2b2 = (const float*)d_in[16];
    const float* p2w1 = (const float*)d_in[17];
    const float* p2w2 = (const float*)d_in[18];
    const float* p2b2 = (const float*)d_in[19];
    const float* b2   = (const float*)d_in[20];
    float* out = (float*)d_out;

    // ---- workspace layout (249.6 MB total) ----
    char* base = (char*)d_ws;
    float* agg  = (float*)(base + 0);                 // N*512 f32 = 102,400,000 B (agg1, then h in-place)
    u16*   xb   = (u16*)  (base + 102400000);         // N*512 bf16 = 51,200,000 B (xh, then t1)
    u16*   eb   = (u16*)  (base + 153600000);         // E'*64 bf16 = 83,200,000 B (e1; e2 reuses)
    char*  csr  = base + 236800000;
    int* src_cnt  = (int*)(csr + 0);                  // 200,000 B
    int* dst_cnt  = (int*)(csr + 200000);
    int* src_cur  = (int*)(csr + 400000);
    int* dst_cur  = (int*)(csr + 600000);
    int* src_off  = (int*)(csr + 800000);             // (N+1) ints
    int* dst_off  = (int*)(csr + 1000016);
    int* src_list = (int*)(csr + 1200032);            // E' ints
    int* dst_list = (int*)(csr + 3800032);            // E' ints → csr end 6,400,032
    float* xh2  = (float*)(base + 243200032);         // N*16 f32 = 3,200,000 B
    float* agg2 = (float*)(base + 246400032);         // N*16 f32 → end 249,600,032 B

    const dim3 blk(256);
    const dim3 g512(H1 / 64, (N_NODES + 63) / 64);
    const int EB = (E_TOT + 255) / 256;               // edge-parallel blocks
    const int WB = (N_NODES * 64 + 255) / 256;        // wave-per-node blocks
    const int GB16 = (N_NODES + 15) / 16;             // 16-thread-group-per-node blocks

    // ---- CSR build ----
    hipMemsetAsync(csr, 0, 800000, stream);           // cnt + cur
    count_k<<<EB, blk, 0, stream>>>(ei, src_cnt, dst_cnt);
    scan2_k<<<1, 1024, 0, stream>>>(src_cnt, dst_cnt, src_off, dst_off);
    fill_csr_k<<<EB, blk, 0, stream>>>(ei, src_off, dst_off, src_cur, dst_cur, src_list, dst_list);

    // ---- layer 1 ----
    gemm_k<0, false, true><<<g512, blk, 0, stream>>>(x, W1, xb, N_NODES, H1, F_IN,
                                                     nullptr, nullptr, nullptr, nullptr);
    edge_mlp1_k<<<EB, blk, 0, stream>>>(kr, h1w1, h1w2, h1b2, eb);
    s1norm_k<<<WB, blk, 0, stream>>>(eb, src_off, src_list);
    msg1_k<<<WB, blk, 0, stream>>>(eb, xb, ei, dst_off, dst_list, agg);
    gemm_k<1, false, true><<<g512, blk, 0, stream>>>(ep, p1w1, xb, N_NODES, H1, NCP,
                                                     nullptr, nullptr, nullptr, nullptr);  // t1 -> xb
    gemm_k<3, true, false><<<g512, blk, 0, stream>>>(xb, p1w2, agg, N_NODES, H1, H1,
                                                     p1b2, agg, b1, alpha);                // h -> agg (in-place)

    // ---- layer 2 ----
    gemm_n16_k<<<(N_NODES + 15) / 16, blk, 0, stream>>>(agg, W2, xh2, N_NODES, H1);
    edge_mlp2_k<<<EB, blk, 0, stream>>>(kr, h2w1, h2w2, h2b2, eb);
    s2norm_k<<<GB16, blk, 0, stream>>>(eb, src_off, src_list);
    msg2_k<<<GB16, blk, 0, stream>>>(eb, xh2, ei, dst_off, dst_list, agg2);
    final_k<<<(N_NODES + 255) / 256, blk, 0, stream>>>(agg2, ep, p2w1, p2w2, p2b2, b2, alpha, out);
}

// Round 3
// 1137.858 us; speedup vs baseline: 1.2289x; 1.2289x over previous
//
#include <hip/hip_runtime.h>
#include <math.h>

#define N_NODES 50000
#define M_PAD   50048    // N_NODES padded to multiple of 128 for MFMA tiles
#define N_EDGES 600000
#define E_TOT   650000   // N_EDGES + N_NODES (self loops appended)
#define F_IN    128
#define HID     64
#define HEADS   8
#define H1      512      // HEADS*HID
#define NCLS    16
#define NC      16
#define NCP     16

typedef unsigned short u16;
typedef __attribute__((ext_vector_type(8))) short short8;   // 8 bf16 = 4 VGPRs (MFMA A/B frag)
typedef __attribute__((ext_vector_type(4))) float f32x4;    // MFMA C/D frag

__device__ __forceinline__ float bf2f(u16 h) {
    return __uint_as_float(((unsigned)h) << 16);
}
__device__ __forceinline__ u16 f2bf(float f) {
    unsigned u = __float_as_uint(f);
    u += 0x7fffu + ((u >> 16) & 1u);
    return (u16)(u >> 16);
}
__device__ __forceinline__ int edge_src(const int* __restrict__ ei, int e) {
    return (e < N_EDGES) ? ei[e] : (e - N_EDGES);
}
__device__ __forceinline__ int edge_dst(const int* __restrict__ ei, int e) {
    return (e < N_EDGES) ? ei[N_EDGES + e] : (e - N_EDGES);
}

// ---------------- CSR build ----------------
__global__ __launch_bounds__(256) void count_k(const int* __restrict__ ei,
                                               int* __restrict__ src_cnt, int* __restrict__ dst_cnt) {
    int e = blockIdx.x * 256 + threadIdx.x;
    if (e >= E_TOT) return;
    atomicAdd(&src_cnt[edge_src(ei, e)], 1);
    atomicAdd(&dst_cnt[edge_dst(ei, e)], 1);
}

__global__ __launch_bounds__(1024) void scan2_k(const int* __restrict__ src_cnt, const int* __restrict__ dst_cnt,
                                                int* __restrict__ src_off, int* __restrict__ dst_off) {
    __shared__ int lds[1024];
    const int t = threadIdx.x;
    const int CH = (N_NODES + 1023) / 1024;   // 49
    for (int pass = 0; pass < 2; ++pass) {
        const int* cnt = pass ? dst_cnt : src_cnt;
        int* off = pass ? dst_off : src_off;
        int base = t * CH;
        int run = 0;
        for (int i = 0; i < CH; ++i) {
            int idx = base + i;
            run += (idx < N_NODES) ? cnt[idx] : 0;
        }
        lds[t] = run;
        __syncthreads();
        for (int d = 1; d < 1024; d <<= 1) {
            int v = (t >= d) ? lds[t - d] : 0;
            __syncthreads();
            lds[t] += v;
            __syncthreads();
        }
        int prefix = (t == 0) ? 0 : lds[t - 1];
        if (t == 1023) off[N_NODES] = lds[1023];
        for (int i = 0; i < CH; ++i) {
            int idx = base + i;
            if (idx < N_NODES) {
                off[idx] = prefix;
                prefix += cnt[idx];
            }
        }
        __syncthreads();
    }
}

__global__ __launch_bounds__(256) void fill_csr_k(const int* __restrict__ ei,
                                                  const int* __restrict__ src_off, const int* __restrict__ dst_off,
                                                  int* __restrict__ src_cur, int* __restrict__ dst_cur,
                                                  int* __restrict__ src_list, int* __restrict__ dst_list) {
    int e = blockIdx.x * 256 + threadIdx.x;
    if (e >= E_TOT) return;
    int s = edge_src(ei, e), d = edge_dst(ei, e);
    int ps = atomicAdd(&src_cur[s], 1);
    src_list[src_off[s] + ps] = e;
    int pd = atomicAdd(&dst_cur[d], 1);
    dst_list[dst_off[d] + pd] = e;
}

// ---------------- layout converters ----------------
// f32 [M][K] row-major -> bf16 fragment-major Ap[K/8][Mp][8]; pad rows zeroed
__global__ __launch_bounds__(256) void conv_a_k(const float* __restrict__ A, u16* __restrict__ Ap,
                                                int M, int Mp, int K) {
    int i = blockIdx.x * 256 + threadIdx.x;
    int total = (K >> 3) * Mp;
    if (i >= total) return;
    int r = i % Mp;
    int kb = i / Mp;
    u16* o = Ap + (size_t)i * 8;
    u16 tmp[8];
    if (r < M) {
        const float* a = A + (size_t)r * K + kb * 8;
        #pragma unroll
        for (int j = 0; j < 8; ++j) tmp[j] = f2bf(a[j]);
    } else {
        #pragma unroll
        for (int j = 0; j < 8; ++j) tmp[j] = 0;
    }
    *(ushort4*)o = *(ushort4*)tmp;
    *(ushort4*)(o + 4) = *(ushort4*)(tmp + 4);
}

// f32 [K][N] row-major -> bf16 fragment-major Bp[K/8][N][8] (Bp[kb][n][j] = B[kb*8+j][n])
__global__ __launch_bounds__(256) void conv_b_k(const float* __restrict__ B, u16* __restrict__ Bp,
                                                int K, int N) {
    int i = blockIdx.x * 256 + threadIdx.x;
    int total = (K >> 3) * N;
    if (i >= total) return;
    int n = i % N;
    int kb = i / N;
    u16 tmp[8];
    #pragma unroll
    for (int j = 0; j < 8; ++j) tmp[j] = f2bf(B[(size_t)(kb * 8 + j) * N + n]);
    u16* o = Bp + (size_t)i * 8;
    *(ushort4*)o = *(ushort4*)tmp;
    *(ushort4*)(o + 4) = *(ushort4*)(tmp + 4);
}

// ---------------- MFMA GEMM: C[M][N] = epi(Ap @ Bp), frag-major operands, no LDS ----------------
// block tile 128x128, 4 waves in 2x2, wave tile 64x64 (4x4 frags of 16x16x32)
// EPI 0: C = A@B                              (store bf16, row-major)
// EPI 3: C = relu(extra + bias2 + alpha * leaky(A@B + bias, 0.01))   (store bf16)
template<int EPI>
__global__ __launch_bounds__(256) void mfma_gemm_k(
    const u16* __restrict__ Ap, const u16* __restrict__ Bp, u16* __restrict__ C,
    int M, int Mp, int Nn, int K,
    const float* __restrict__ bias, const u16* __restrict__ extra,
    const float* __restrict__ bias2, const float* __restrict__ alpha_p)
{
    const int t = threadIdx.x;
    const int wave = t >> 6, lane = t & 63;
    const int wm = (wave >> 1) * 64, wn = (wave & 1) * 64;
    const int bm = blockIdx.y * 128, bn = blockIdx.x * 128;
    const int lm = lane & 15, quad = lane >> 4;

    size_t rbase[4], cbase[4];
    #pragma unroll
    for (int mi = 0; mi < 4; ++mi) rbase[mi] = (size_t)(bm + wm + mi * 16 + lm) * 8;
    #pragma unroll
    for (int nj = 0; nj < 4; ++nj) cbase[nj] = (size_t)(bn + wn + nj * 16 + lm) * 8;

    f32x4 acc[4][4] = {};

    for (int k0 = 0; k0 < K; k0 += 32) {
        int kb = (k0 >> 3) + quad;
        size_t abase = (size_t)kb * Mp * 8;
        size_t bbase = (size_t)kb * Nn * 8;
        short8 af[4], bf_[4];
        #pragma unroll
        for (int mi = 0; mi < 4; ++mi) af[mi] = *(const short8*)(Ap + abase + rbase[mi]);
        #pragma unroll
        for (int nj = 0; nj < 4; ++nj) bf_[nj] = *(const short8*)(Bp + bbase + cbase[nj]);
        #pragma unroll
        for (int mi = 0; mi < 4; ++mi)
            #pragma unroll
            for (int nj = 0; nj < 4; ++nj)
                acc[mi][nj] = __builtin_amdgcn_mfma_f32_16x16x32_bf16(af[mi], bf_[nj], acc[mi][nj], 0, 0, 0);
    }

    // C/D layout: col = lane&15, row = quad*4 + reg
    const int orow = bm + wm + quad * 4;
    const int ocol = bn + wn + lm;
    if (EPI == 0) {
        #pragma unroll
        for (int mi = 0; mi < 4; ++mi)
            #pragma unroll
            for (int r = 0; r < 4; ++r) {
                int rr = orow + mi * 16 + r;
                if (rr >= M) continue;
                #pragma unroll
                for (int nj = 0; nj < 4; ++nj)
                    C[(size_t)rr * Nn + ocol + nj * 16] = f2bf(acc[mi][nj][r]);
            }
    } else {
        float alpha = *alpha_p;
        #pragma unroll
        for (int mi = 0; mi < 4; ++mi)
            #pragma unroll
            for (int r = 0; r < 4; ++r) {
                int rr = orow + mi * 16 + r;
                if (rr >= M) continue;
                #pragma unroll
                for (int nj = 0; nj < 4; ++nj) {
                    int c = ocol + nj * 16;
                    float v = acc[mi][nj][r] + bias[c];
                    v = v > 0.f ? v : 0.01f * v;
                    float o = bf2f(extra[(size_t)rr * Nn + c]) + bias2[c] + alpha * v;
                    o = fmaxf(o, 0.f);
                    C[(size_t)rr * Nn + c] = f2bf(o);
                }
            }
    }
}

// ---------------- t1 = leaky(ep @ p1w1, 0.2), K=16, written in frag-major Ap layout ----------------
__global__ __launch_bounds__(256) void gemm_t1_k(
    const float* __restrict__ ep, const float* __restrict__ W, u16* __restrict__ t1p)
{
    __shared__ float Bs[16][64];
    const int bm = blockIdx.y * 64, bn = blockIdx.x * 64;
    const int t = threadIdx.x;
    const int tx = t & 15, ty = t >> 4;
    // stage B tile 16x64
    *(float4*)&Bs[t >> 4][(t & 15) * 4] = *(const float4*)&W[(size_t)(t >> 4) * H1 + bn + (t & 15) * 4];
    __syncthreads();
    const int r0 = bm + ty * 4;
    const int c0 = bn + tx * 4;
    for (int i = 0; i < 4; ++i) {
        int r = r0 + i;
        if (r >= N_NODES) continue;
        float av[16];
        #pragma unroll
        for (int j4 = 0; j4 < 16; j4 += 4) {
            float4 v = *(const float4*)(ep + (size_t)r * NCP + j4);
            av[j4] = v.x; av[j4 + 1] = v.y; av[j4 + 2] = v.z; av[j4 + 3] = v.w;
        }
        u16 pk[4];
        #pragma unroll
        for (int q = 0; q < 4; ++q) {
            float s = 0.f;
            #pragma unroll
            for (int k = 0; k < 16; ++k) s = fmaf(av[k], Bs[k][tx * 4 + q], s);
            s = s > 0.f ? s : 0.2f * s;
            pk[q] = f2bf(s);
        }
        // frag-major: t1p[c/8][r][c%8]
        u16* o = t1p + ((size_t)(c0 >> 3) * M_PAD + r) * 8 + (c0 & 7);
        *(ushort4*)o = *(ushort4*)pk;
    }
}

// ---------------- N=16 GEMM (xh2 = h @ W_src2), bf16 A, K multiple of 64 ----------------
__global__ __launch_bounds__(256) void gemm_n16_k(
    const u16* __restrict__ A, const float* __restrict__ B, float* __restrict__ C,
    int M, int K)
{
    __shared__ float As[16][64];   // [row][k]
    __shared__ float Bs[64][16];   // [k][col]
    const int row0 = blockIdx.x * 16;
    const int t = threadIdx.x;
    const int r = t >> 4, c = t & 15;
    const int ar = t >> 4, ak4 = (t & 15) * 4;
    const int bk = t >> 2, bc4 = (t & 3) * 4;
    float acc = 0.f;
    for (int k0 = 0; k0 < K; k0 += 64) {
        float4 av = make_float4(0.f, 0.f, 0.f, 0.f);
        if (row0 + ar < M) {
            ushort4 h4 = *(const ushort4*)(A + (size_t)(row0 + ar) * K + k0 + ak4);
            av = make_float4(bf2f(h4.x), bf2f(h4.y), bf2f(h4.z), bf2f(h4.w));
        }
        *(float4*)&As[ar][ak4] = av;
        *(float4*)&Bs[bk][bc4] = *(const float4*)(B + (size_t)(k0 + bk) * 16 + bc4);
        __syncthreads();
        #pragma unroll
        for (int kk = 0; kk < 64; ++kk)
            acc = fmaf(As[r][kk], Bs[kk][c], acc);
        __syncthreads();
    }
    if (row0 + r < M) C[(size_t)(row0 + r) * 16 + c] = acc;
}

// ---------------- fused per-edge MLP, layer 1 (16 -> 64 -> 64), e = exp(ew) bf16 ----------------
__global__ __launch_bounds__(256) void edge_mlp1_k(
    const float* __restrict__ kr, const float* __restrict__ w1,
    const float* __restrict__ w2, const float* __restrict__ b2,
    u16* __restrict__ eb)
{
    __shared__ float sw1[NC * HID];
    __shared__ float sw2[HID * HID];
    __shared__ float sb2[HID];
    const int t = threadIdx.x;
    for (int i = t; i < NC * HID; i += 256) sw1[i] = w1[i];
    for (int i = t; i < HID * HID; i += 256) sw2[i] = w2[i];
    if (t < HID) sb2[t] = b2[t];
    __syncthreads();
    const int e = blockIdx.x * 256 + t;
    if (e >= E_TOT) return;
    float kri[NC];
    #pragma unroll
    for (int j4 = 0; j4 < NC; j4 += 4) {
        float4 v = *(const float4*)(kr + (size_t)e * NC + j4);
        kri[j4] = v.x; kri[j4 + 1] = v.y; kri[j4 + 2] = v.z; kri[j4 + 3] = v.w;
    }
    float tt[HID];
    #pragma unroll
    for (int c4 = 0; c4 < HID; c4 += 4) {
        float o0 = 0.f, o1 = 0.f, o2 = 0.f, o3 = 0.f;
        #pragma unroll
        for (int j = 0; j < NC; ++j) {
            float4 w = *(const float4*)&sw1[j * HID + c4];
            float kj = kri[j];
            o0 = fmaf(kj, w.x, o0); o1 = fmaf(kj, w.y, o1);
            o2 = fmaf(kj, w.z, o2); o3 = fmaf(kj, w.w, o3);
        }
        tt[c4 + 0] = o0 > 0.f ? o0 : 0.2f * o0;
        tt[c4 + 1] = o1 > 0.f ? o1 : 0.2f * o1;
        tt[c4 + 2] = o2 > 0.f ? o2 : 0.2f * o2;
        tt[c4 + 3] = o3 > 0.f ? o3 : 0.2f * o3;
    }
    #pragma unroll
    for (int c4 = 0; c4 < HID; c4 += 4) {
        float o0 = sb2[c4], o1 = sb2[c4 + 1], o2 = sb2[c4 + 2], o3 = sb2[c4 + 3];
        #pragma unroll
        for (int j = 0; j < HID; ++j) {
            float4 w = *(const float4*)&sw2[j * HID + c4];
            float tj = tt[j];
            o0 = fmaf(tj, w.x, o0); o1 = fmaf(tj, w.y, o1);
            o2 = fmaf(tj, w.z, o2); o3 = fmaf(tj, w.w, o3);
        }
        ushort4 pk;
        pk.x = f2bf(__expf(o0)); pk.y = f2bf(__expf(o1));
        pk.z = f2bf(__expf(o2)); pk.w = f2bf(__expf(o3));
        *(ushort4*)(eb + (size_t)e * HID + c4) = pk;
    }
}

// ---------------- fused per-edge MLP, layer 2 (16 -> 16 -> 16), e = exp(ew) bf16 ----------------
__global__ __launch_bounds__(256) void edge_mlp2_k(
    const float* __restrict__ kr, const float* __restrict__ w1,
    const float* __restrict__ w2, const float* __restrict__ b2,
    u16* __restrict__ eb)
{
    __shared__ float sw1[NC * NCLS];
    __shared__ float sw2[NCLS * NCLS];
    __shared__ float sb2[NCLS];
    const int t = threadIdx.x;
    sw1[t] = w1[t];
    sw2[t] = w2[t];
    if (t < NCLS) sb2[t] = b2[t];
    __syncthreads();
    const int e = blockIdx.x * 256 + t;
    if (e >= E_TOT) return;
    float kri[NC];
    #pragma unroll
    for (int j4 = 0; j4 < NC; j4 += 4) {
        float4 v = *(const float4*)(kr + (size_t)e * NC + j4);
        kri[j4] = v.x; kri[j4 + 1] = v.y; kri[j4 + 2] = v.z; kri[j4 + 3] = v.w;
    }
    float tt[NCLS];
    #pragma unroll
    for (int c4 = 0; c4 < NCLS; c4 += 4) {
        float o[4] = {0.f, 0.f, 0.f, 0.f};
        #pragma unroll
        for (int j = 0; j < NC; ++j) {
            float4 w = *(const float4*)&sw1[j * NCLS + c4];
            float kj = kri[j];
            o[0] = fmaf(kj, w.x, o[0]); o[1] = fmaf(kj, w.y, o[1]);
            o[2] = fmaf(kj, w.z, o[2]); o[3] = fmaf(kj, w.w, o[3]);
        }
        #pragma unroll
        for (int q = 0; q < 4; ++q) tt[c4 + q] = o[q] > 0.f ? o[q] : 0.2f * o[q];
    }
    #pragma unroll
    for (int c4 = 0; c4 < NCLS; c4 += 4) {
        float o[4] = {sb2[c4], sb2[c4 + 1], sb2[c4 + 2], sb2[c4 + 3]};
        #pragma unroll
        for (int j = 0; j < NCLS; ++j) {
            float4 w = *(const float4*)&sw2[j * NCLS + c4];
            float tj = tt[j];
            o[0] = fmaf(tj, w.x, o[0]); o[1] = fmaf(tj, w.y, o[1]);
            o[2] = fmaf(tj, w.z, o[2]); o[3] = fmaf(tj, w.w, o[3]);
        }
        ushort4 pk;
        pk.x = f2bf(__expf(o[0])); pk.y = f2bf(__expf(o[1]));
        pk.z = f2bf(__expf(o[2])); pk.w = f2bf(__expf(o[3]));
        *(ushort4*)(eb + (size_t)e * NCLS + c4) = pk;
    }
}

// ---------------- inverse softmax denominator, layer 1 (wave per src) ----------------
__global__ __launch_bounds__(256) void s1sum_k(
    const u16* __restrict__ eb, const int* __restrict__ src_off, const int* __restrict__ src_list,
    float* __restrict__ inv1)
{
    int gid = blockIdx.x * 256 + threadIdx.x;
    int wid = gid >> 6, lane = gid & 63;
    if (wid >= N_NODES) return;
    int o0 = src_off[wid], o1 = src_off[wid + 1];
    float sum = 0.f;
    for (int i = o0; i < o1; ++i) {
        int el = src_list[i];
        sum += bf2f(eb[(size_t)el * HID + lane]);
    }
    inv1[(size_t)wid * HID + lane] = 1.f / (sum + 1e-16f);
}

// ---------------- message pass 1 (wave per dst, 8 heads x 64 ch), no atomics ----------------
__global__ __launch_bounds__(256) void msg1_k(
    const u16* __restrict__ eb, const float* __restrict__ inv1,
    const u16* __restrict__ xb, const int* __restrict__ ei,
    const int* __restrict__ dst_off, const int* __restrict__ dst_list,
    u16* __restrict__ aggb)
{
    int gid = blockIdx.x * 256 + threadIdx.x;
    int wid = gid >> 6, lane = gid & 63;
    if (wid >= N_NODES) return;
    int o0 = dst_off[wid], o1 = dst_off[wid + 1];
    float acc[HEADS] = {0.f, 0.f, 0.f, 0.f, 0.f, 0.f, 0.f, 0.f};
    for (int i = o0; i < o1; ++i) {
        int el = dst_list[i];
        int s = edge_src(ei, el);
        float a = bf2f(eb[(size_t)el * HID + lane]) * inv1[(size_t)s * HID + lane];
        const u16* xr = xb + (size_t)s * H1 + lane;
        #pragma unroll
        for (int h = 0; h < HEADS; ++h)
            acc[h] = fmaf(a, bf2f(xr[h * 64]), acc[h]);
    }
    u16* ar = aggb + (size_t)wid * H1 + lane;
    #pragma unroll
    for (int h = 0; h < HEADS; ++h) ar[h * 64] = f2bf(acc[h]);
}

// ---------------- inverse denominator, layer 2 (16 threads per src) ----------------
__global__ __launch_bounds__(256) void s2sum_k(
    const u16* __restrict__ eb, const int* __restrict__ src_off, const int* __restrict__ src_list,
    float* __restrict__ inv2)
{
    int t = threadIdx.x;
    int g = blockIdx.x * 16 + (t >> 4), c = t & 15;
    if (g >= N_NODES) return;
    int o0 = src_off[g], o1 = src_off[g + 1];
    float sum = 0.f;
    for (int i = o0; i < o1; ++i) {
        int el = src_list[i];
        sum += bf2f(eb[(size_t)el * NCLS + c]);
    }
    inv2[(size_t)g * NCLS + c] = 1.f / (sum + 1e-16f);
}

// ---------------- message pass 2 (16 threads per dst), no atomics ----------------
__global__ __launch_bounds__(256) void msg2_k(
    const u16* __restrict__ eb, const float* __restrict__ inv2,
    const float* __restrict__ xh2, const int* __restrict__ ei,
    const int* __restrict__ dst_off, const int* __restrict__ dst_list,
    float* __restrict__ agg2)
{
    int t = threadIdx.x;
    int g = blockIdx.x * 16 + (t >> 4), c = t & 15;
    if (g >= N_NODES) return;
    int o0 = dst_off[g], o1 = dst_off[g + 1];
    float acc = 0.f;
    for (int i = o0; i < o1; ++i) {
        int el = dst_list[i];
        int s = edge_src(ei, el);
        float a = bf2f(eb[(size_t)el * NCLS + c]) * inv2[(size_t)s * NCLS + c];
        acc = fmaf(a, xh2[(size_t)s * NCLS + c], acc);
    }
    agg2[(size_t)g * NCLS + c] = acc;
}

// ---------------- final: o = agg2 + bias2 + alpha*p2; log_softmax ----------------
__global__ __launch_bounds__(256) void final_k(
    const float* __restrict__ agg2, const float* __restrict__ ep,
    const float* __restrict__ pw1, const float* __restrict__ pw2,
    const float* __restrict__ pb2, const float* __restrict__ bias,
    const float* __restrict__ alpha_p, float* __restrict__ out)
{
    __shared__ float s1w[256], s2w[256], sb[16], sbias[16];
    const int t = threadIdx.x;
    s1w[t] = pw1[t];
    s2w[t] = pw2[t];
    if (t < 16) { sb[t] = pb2[t]; sbias[t] = bias[t]; }
    __syncthreads();
    const int v = blockIdx.x * 256 + t;
    if (v >= N_NODES) return;
    float alpha = *alpha_p;
    float e_[16];
    #pragma unroll
    for (int j4 = 0; j4 < 16; j4 += 4) {
        float4 vv = *(const float4*)(ep + (size_t)v * 16 + j4);
        e_[j4] = vv.x; e_[j4 + 1] = vv.y; e_[j4 + 2] = vv.z; e_[j4 + 3] = vv.w;
    }
    float t2[16];
    #pragma unroll
    for (int c = 0; c < 16; ++c) {
        float s = 0.f;
        #pragma unroll
        for (int j = 0; j < 16; ++j) s = fmaf(e_[j], s1w[j * 16 + c], s);
        t2[c] = s > 0.f ? s : 0.2f * s;
    }
    float o[16];
    #pragma unroll
    for (int c4 = 0; c4 < 16; c4 += 4) {
        float4 ag = *(const float4*)(agg2 + (size_t)v * 16 + c4);
        float agv[4] = {ag.x, ag.y, ag.z, ag.w};
        #pragma unroll
        for (int q = 0; q < 4; ++q) {
            int c = c4 + q;
            float p = sb[c];
            #pragma unroll
            for (int j = 0; j < 16; ++j) p = fmaf(t2[j], s2w[j * 16 + c], p);
            p = p > 0.f ? p : 0.01f * p;
            o[c] = agv[q] + sbias[c] + alpha * p;
        }
    }
    float mx = o[0];
    #pragma unroll
    for (int c = 1; c < 16; ++c) mx = fmaxf(mx, o[c]);
    float se = 0.f;
    #pragma unroll
    for (int c = 0; c < 16; ++c) se += expf(o[c] - mx);
    float lse = mx + logf(se);
    #pragma unroll
    for (int c4 = 0; c4 < 16; c4 += 4)
        *(float4*)(out + (size_t)v * 16 + c4) =
            make_float4(o[c4] - lse, o[c4 + 1] - lse, o[c4 + 2] - lse, o[c4 + 3] - lse);
}

extern "C" void kernel_launch(void* const* d_in, const int* in_sizes, int n_in,
                              void* d_out, int out_size, void* d_ws, size_t ws_size,
                              hipStream_t stream) {
    const float* x    = (const float*)d_in[0];
    const int*   ei   = (const int*)d_in[1];
    const float* alpha= (const float*)d_in[2];
    const float* kr   = (const float*)d_in[3];
    const float* ep   = (const float*)d_in[4];
    const float* W1   = (const float*)d_in[5];
    const float* h1w1 = (const float*)d_in[6];
    const float* h1w2 = (const float*)d_in[7];
    const float* h1b2 = (const float*)d_in[8];
    const float* p1w1 = (const float*)d_in[9];
    const float* p1w2 = (const float*)d_in[10];
    const float* p1b2 = (const float*)d_in[11];
    const float* b1   = (const float*)d_in[12];
    const float* W2   = (const float*)d_in[13];
    const float* h2w1 = (const float*)d_in[14];
    const float* h2w2 = (const float*)d_in[15];
    const float* h2b2 = (const float*)d_in[16];
    const float* p2w1 = (const float*)d_in[17];
    const float* p2w2 = (const float*)d_in[18];
    const float* p2b2 = (const float*)d_in[19];
    const float* b2   = (const float*)d_in[20];
    float* out = (float*)d_out;

    // ---- workspace bump allocator (total ~215 MB) ----
    char* p = (char*)d_ws;
    auto alloc = [&](size_t bytes) { char* r = p; p += (bytes + 255) & ~(size_t)255; return r; };

    char* r0    = alloc((size_t)64 * M_PAD * 16);          // 51.25 MB: xb (row-major bf16 N x 512), then t1p (frag-major)
    u16*  xb    = (u16*)r0;
    u16*  t1p   = (u16*)r0;
    u16*  aggb  = (u16*)alloc((size_t)N_NODES * H1 * 2);   // 51.2 MB bf16
    char* ebr   = alloc((size_t)E_TOT * HID * 2);          // 83.2 MB: eb (E'x64), then hb (Nx512) + eb2 (E'x16)
    u16*  eb    = (u16*)ebr;
    u16*  hb    = (u16*)ebr;
    u16*  eb2   = (u16*)(ebr + (size_t)N_NODES * H1 * 2);
    char* xpr   = alloc((size_t)16 * M_PAD * 16);          // 12.81 MB: xp (frag-major x), then inv1 (Nx64 f32)
    u16*  xp    = (u16*)xpr;
    float* inv1 = (float*)xpr;
    u16*  W1p   = (u16*)alloc((size_t)16 * H1 * 16);       // 128 KB
    u16*  p1w2p = (u16*)alloc((size_t)64 * H1 * 16);       // 512 KB
    int* src_cnt  = (int*)alloc(N_NODES * 4);
    int* dst_cnt  = (int*)alloc(N_NODES * 4);
    int* src_cur  = (int*)alloc(N_NODES * 4);
    int* dst_cur  = (int*)alloc(N_NODES * 4);
    int* src_off  = (int*)alloc((N_NODES + 1) * 4);
    int* dst_off  = (int*)alloc((N_NODES + 1) * 4);
    int* src_list = (int*)alloc((size_t)E_TOT * 4);
    int* dst_list = (int*)alloc((size_t)E_TOT * 4);
    float* xh2  = (float*)alloc((size_t)N_NODES * NCLS * 4);
    float* agg2 = (float*)alloc((size_t)N_NODES * NCLS * 4);
    float* inv2 = (float*)alloc((size_t)N_NODES * NCLS * 4);

    const dim3 blk(256);
    const int EB = (E_TOT + 255) / 256;
    const int WB = (N_NODES * 64 + 255) / 256;
    const int GB16 = (N_NODES + 15) / 16;
    const dim3 gmm(512 / 128, M_PAD / 128);                 // (4, 391)

    // ---- CSR build + weight/layout conversion ----
    hipMemsetAsync(src_cnt, 0, (char*)src_off - (char*)src_cnt, stream);  // cnts + curs (contiguous allocs)
    count_k<<<EB, blk, 0, stream>>>(ei, src_cnt, dst_cnt);
    scan2_k<<<1, 1024, 0, stream>>>(src_cnt, dst_cnt, src_off, dst_off);
    fill_csr_k<<<EB, blk, 0, stream>>>(ei, src_off, dst_off, src_cur, dst_cur, src_list, dst_list);
    conv_a_k<<<(16 * M_PAD + 255) / 256, blk, 0, stream>>>(x, xp, N_NODES, M_PAD, F_IN);
    conv_b_k<<<(16 * H1 + 255) / 256, blk, 0, stream>>>(W1, W1p, F_IN, H1);
    conv_b_k<<<(64 * H1 + 255) / 256, blk, 0, stream>>>(p1w2, p1w2p, H1, H1);

    // ---- layer 1 ----
    mfma_gemm_k<0><<<gmm, blk, 0, stream>>>(xp, W1p, xb, N_NODES, M_PAD, H1, F_IN,
                                            nullptr, nullptr, nullptr, nullptr);
    edge_mlp1_k<<<EB, blk, 0, stream>>>(kr, h1w1, h1w2, h1b2, eb);
    s1sum_k<<<WB, blk, 0, stream>>>(eb, src_off, src_list, inv1);
    msg1_k<<<WB, blk, 0, stream>>>(eb, inv1, xb, ei, dst_off, dst_list, aggb);
    gemm_t1_k<<<dim3(8, (N_NODES + 63) / 64), blk, 0, stream>>>(ep, p1w1, t1p);   // overwrites xb region
    mfma_gemm_k<3><<<gmm, blk, 0, stream>>>(t1p, p1w2p, hb, N_NODES, M_PAD, H1, H1,
                                            p1b2, aggb, b1, alpha);               // hb overwrites eb region

    // ---- layer 2 ----
    gemm_n16_k<<<(N_NODES + 15) / 16, blk, 0, stream>>>(hb, W2, xh2, N_NODES, H1);
    edge_mlp2_k<<<EB, blk, 0, stream>>>(kr, h2w1, h2w2, h2b2, eb2);
    s2sum_k<<<GB16, blk, 0, stream>>>(eb2, src_off, src_list, inv2);
    msg2_k<<<GB16, blk, 0, stream>>>(eb2, inv2, xh2, ei, dst_off, dst_list, agg2);
    final_k<<<(N_NODES + 255) / 256, blk, 0, stream>>>(agg2, ep, p2w1, p2w2, p2b2, b2, alpha, out);
}

// Round 4
// 955.958 us; speedup vs baseline: 1.4628x; 1.1903x over previous
//
#include <hip/hip_runtime.h>
#include <math.h>

#define N_NODES 50000
#define M_PAD   50048    // N_NODES padded to multiple of 128 for MFMA tiles
#define N_EDGES 600000
#define E_TOT   650000   // N_EDGES + N_NODES (self loops appended)
#define F_IN    128
#define HID     64
#define HEADS   8
#define H1      512      // HEADS*HID
#define NCLS    16
#define NC      16
#define NCP     16

typedef unsigned short u16;
typedef __attribute__((ext_vector_type(8))) short short8;   // 8 bf16 = 4 VGPRs (MFMA A/B frag)
typedef __attribute__((ext_vector_type(4))) float f32x4;    // MFMA C/D frag

__device__ __forceinline__ float bf2f(u16 h) {
    return __uint_as_float(((unsigned)h) << 16);
}
__device__ __forceinline__ u16 f2bf(float f) {
    unsigned u = __float_as_uint(f);
    u += 0x7fffu + ((u >> 16) & 1u);
    return (u16)(u >> 16);
}
__device__ __forceinline__ int edge_src(const int* __restrict__ ei, int e) {
    return (e < N_EDGES) ? ei[e] : (e - N_EDGES);
}
__device__ __forceinline__ int edge_dst(const int* __restrict__ ei, int e) {
    return (e < N_EDGES) ? ei[N_EDGES + e] : (e - N_EDGES);
}

// ---------------- CSR build ----------------
__global__ __launch_bounds__(256) void count_k(const int* __restrict__ ei,
                                               int* __restrict__ src_cnt, int* __restrict__ dst_cnt) {
    int e = blockIdx.x * 256 + threadIdx.x;
    if (e >= E_TOT) return;
    atomicAdd(&src_cnt[edge_src(ei, e)], 1);
    atomicAdd(&dst_cnt[edge_dst(ei, e)], 1);
}

__global__ __launch_bounds__(1024) void scan2_k(const int* __restrict__ src_cnt, const int* __restrict__ dst_cnt,
                                                int* __restrict__ src_off, int* __restrict__ dst_off) {
    __shared__ int lds[1024];
    const int t = threadIdx.x;
    const int CH = (N_NODES + 1023) / 1024;   // 49
    for (int pass = 0; pass < 2; ++pass) {
        const int* cnt = pass ? dst_cnt : src_cnt;
        int* off = pass ? dst_off : src_off;
        int base = t * CH;
        int run = 0;
        for (int i = 0; i < CH; ++i) {
            int idx = base + i;
            run += (idx < N_NODES) ? cnt[idx] : 0;
        }
        lds[t] = run;
        __syncthreads();
        for (int d = 1; d < 1024; d <<= 1) {
            int v = (t >= d) ? lds[t - d] : 0;
            __syncthreads();
            lds[t] += v;
            __syncthreads();
        }
        int prefix = (t == 0) ? 0 : lds[t - 1];
        if (t == 1023) off[N_NODES] = lds[1023];
        for (int i = 0; i < CH; ++i) {
            int idx = base + i;
            if (idx < N_NODES) {
                off[idx] = prefix;
                prefix += cnt[idx];
            }
        }
        __syncthreads();
    }
}

__global__ __launch_bounds__(256) void fill_csr_k(const int* __restrict__ ei,
                                                  const int* __restrict__ src_off, const int* __restrict__ dst_off,
                                                  int* __restrict__ src_cur, int* __restrict__ dst_cur,
                                                  int* __restrict__ src_list, int* __restrict__ dst_list) {
    int e = blockIdx.x * 256 + threadIdx.x;
    if (e >= E_TOT) return;
    int s = edge_src(ei, e), d = edge_dst(ei, e);
    int ps = atomicAdd(&src_cur[s], 1);
    src_list[src_off[s] + ps] = e;
    int pd = atomicAdd(&dst_cur[d], 1);
    dst_list[dst_off[d] + pd] = e;
}

// ---------------- layout converters ----------------
// f32 [M][K] row-major -> bf16 fragment-major Ap[K/8][Mp][8]; pad rows zeroed
__global__ __launch_bounds__(256) void conv_a_k(const float* __restrict__ A, u16* __restrict__ Ap,
                                                int M, int Mp, int K) {
    int i = blockIdx.x * 256 + threadIdx.x;
    int total = (K >> 3) * Mp;
    if (i >= total) return;
    int r = i % Mp;
    int kb = i / Mp;
    u16* o = Ap + (size_t)i * 8;
    u16 tmp[8];
    if (r < M) {
        const float* a = A + (size_t)r * K + kb * 8;
        #pragma unroll
        for (int j = 0; j < 8; ++j) tmp[j] = f2bf(a[j]);
    } else {
        #pragma unroll
        for (int j = 0; j < 8; ++j) tmp[j] = 0;
    }
    *(ushort4*)o = *(ushort4*)tmp;
    *(ushort4*)(o + 4) = *(ushort4*)(tmp + 4);
}

// f32 [K][N] row-major -> bf16 fragment-major Bp[K/8][N][8] (Bp[kb][n][j] = B[kb*8+j][n])
__global__ __launch_bounds__(256) void conv_b_k(const float* __restrict__ B, u16* __restrict__ Bp,
                                                int K, int N) {
    int i = blockIdx.x * 256 + threadIdx.x;
    int total = (K >> 3) * N;
    if (i >= total) return;
    int n = i % N;
    int kb = i / N;
    u16 tmp[8];
    #pragma unroll
    for (int j = 0; j < 8; ++j) tmp[j] = f2bf(B[(size_t)(kb * 8 + j) * N + n]);
    u16* o = Bp + (size_t)i * 8;
    *(ushort4*)o = *(ushort4*)tmp;
    *(ushort4*)(o + 4) = *(ushort4*)(tmp + 4);
}

// f32 W[K][N] row-major -> per-lane B-frag table [Kpad/32][N/16][64][8], zero-padded beyond K
__global__ __launch_bounds__(256) void conv_wfrag_k(const float* __restrict__ W, u16* __restrict__ o,
                                                    int K, int Kpad, int N) {
    int i = blockIdx.x * 256 + threadIdx.x;
    int total = (Kpad / 32) * (N / 16) * 64 * 8;
    if (i >= total) return;
    int j = i & 7, lane = (i >> 3) & 63, rest = i >> 9;
    int ntn = N / 16;
    int nt = rest % ntn, ks = rest / ntn;
    int lm = lane & 15, quad = lane >> 4;
    int k = ks * 32 + quad * 8 + j, n = nt * 16 + lm;
    o[i] = (k < K) ? f2bf(W[(size_t)k * N + n]) : (u16)0;
}

// ---------------- MFMA GEMM: C[M][N] = epi(Ap @ Bp), frag-major operands, no LDS ----------------
// block tile 128x128, 4 waves in 2x2, wave tile 64x64 (4x4 frags of 16x16x32)
// EPI 0: C = A@B                              (store bf16, row-major)
// EPI 3: C = relu(extra + bias2 + alpha * leaky(A@B + bias, 0.01))   (store bf16)
template<int EPI>
__global__ __launch_bounds__(256) void mfma_gemm_k(
    const u16* __restrict__ Ap, const u16* __restrict__ Bp, u16* __restrict__ C,
    int M, int Mp, int Nn, int K,
    const float* __restrict__ bias, const u16* __restrict__ extra,
    const float* __restrict__ bias2, const float* __restrict__ alpha_p)
{
    const int t = threadIdx.x;
    const int wave = t >> 6, lane = t & 63;
    const int wm = (wave >> 1) * 64, wn = (wave & 1) * 64;
    const int bm = blockIdx.y * 128, bn = blockIdx.x * 128;
    const int lm = lane & 15, quad = lane >> 4;

    size_t rbase[4], cbase[4];
    #pragma unroll
    for (int mi = 0; mi < 4; ++mi) rbase[mi] = (size_t)(bm + wm + mi * 16 + lm) * 8;
    #pragma unroll
    for (int nj = 0; nj < 4; ++nj) cbase[nj] = (size_t)(bn + wn + nj * 16 + lm) * 8;

    f32x4 acc[4][4] = {};

    for (int k0 = 0; k0 < K; k0 += 32) {
        int kb = (k0 >> 3) + quad;
        size_t abase = (size_t)kb * Mp * 8;
        size_t bbase = (size_t)kb * Nn * 8;
        short8 af[4], bf_[4];
        #pragma unroll
        for (int mi = 0; mi < 4; ++mi) af[mi] = *(const short8*)(Ap + abase + rbase[mi]);
        #pragma unroll
        for (int nj = 0; nj < 4; ++nj) bf_[nj] = *(const short8*)(Bp + bbase + cbase[nj]);
        #pragma unroll
        for (int mi = 0; mi < 4; ++mi)
            #pragma unroll
            for (int nj = 0; nj < 4; ++nj)
                acc[mi][nj] = __builtin_amdgcn_mfma_f32_16x16x32_bf16(af[mi], bf_[nj], acc[mi][nj], 0, 0, 0);
    }

    // C/D layout: col = lane&15, row = quad*4 + reg
    const int orow = bm + wm + quad * 4;
    const int ocol = bn + wn + lm;
    if (EPI == 0) {
        #pragma unroll
        for (int mi = 0; mi < 4; ++mi)
            #pragma unroll
            for (int r = 0; r < 4; ++r) {
                int rr = orow + mi * 16 + r;
                if (rr >= M) continue;
                #pragma unroll
                for (int nj = 0; nj < 4; ++nj)
                    C[(size_t)rr * Nn + ocol + nj * 16] = f2bf(acc[mi][nj][r]);
            }
    } else {
        float alpha = *alpha_p;
        #pragma unroll
        for (int mi = 0; mi < 4; ++mi)
            #pragma unroll
            for (int r = 0; r < 4; ++r) {
                int rr = orow + mi * 16 + r;
                if (rr >= M) continue;
                #pragma unroll
                for (int nj = 0; nj < 4; ++nj) {
                    int c = ocol + nj * 16;
                    float v = acc[mi][nj][r] + bias[c];
                    v = v > 0.f ? v : 0.01f * v;
                    float o = bf2f(extra[(size_t)rr * Nn + c]) + bias2[c] + alpha * v;
                    o = fmaxf(o, 0.f);
                    C[(size_t)rr * Nn + c] = f2bf(o);
                }
            }
    }
}

// ---------------- t1 = leaky(ep @ p1w1, 0.2), K=16, written in frag-major Ap layout ----------------
__global__ __launch_bounds__(256) void gemm_t1_k(
    const float* __restrict__ ep, const float* __restrict__ W, u16* __restrict__ t1p)
{
    __shared__ float Bs[16][64];
    const int bm = blockIdx.y * 64, bn = blockIdx.x * 64;
    const int t = threadIdx.x;
    const int tx = t & 15, ty = t >> 4;
    *(float4*)&Bs[t >> 4][(t & 15) * 4] = *(const float4*)&W[(size_t)(t >> 4) * H1 + bn + (t & 15) * 4];
    __syncthreads();
    const int r0 = bm + ty * 4;
    const int c0 = bn + tx * 4;
    for (int i = 0; i < 4; ++i) {
        int r = r0 + i;
        if (r >= N_NODES) continue;
        float av[16];
        #pragma unroll
        for (int j4 = 0; j4 < 16; j4 += 4) {
            float4 v = *(const float4*)(ep + (size_t)r * NCP + j4);
            av[j4] = v.x; av[j4 + 1] = v.y; av[j4 + 2] = v.z; av[j4 + 3] = v.w;
        }
        u16 pk[4];
        #pragma unroll
        for (int q = 0; q < 4; ++q) {
            float s = 0.f;
            #pragma unroll
            for (int k = 0; k < 16; ++k) s = fmaf(av[k], Bs[k][tx * 4 + q], s);
            s = s > 0.f ? s : 0.2f * s;
            pk[q] = f2bf(s);
        }
        u16* o = t1p + ((size_t)(c0 >> 3) * M_PAD + r) * 8 + (c0 & 7);
        *(ushort4*)o = *(ushort4*)pk;
    }
}

// ---------------- N=16 GEMM (xh2 = h @ W_src2), bf16 A, K multiple of 64 ----------------
__global__ __launch_bounds__(256) void gemm_n16_k(
    const u16* __restrict__ A, const float* __restrict__ B, float* __restrict__ C,
    int M, int K)
{
    __shared__ float As[16][64];   // [row][k]
    __shared__ float Bs[64][16];   // [k][col]
    const int row0 = blockIdx.x * 16;
    const int t = threadIdx.x;
    const int r = t >> 4, c = t & 15;
    const int ar = t >> 4, ak4 = (t & 15) * 4;
    const int bk = t >> 2, bc4 = (t & 3) * 4;
    float acc = 0.f;
    for (int k0 = 0; k0 < K; k0 += 64) {
        float4 av = make_float4(0.f, 0.f, 0.f, 0.f);
        if (row0 + ar < M) {
            ushort4 h4 = *(const ushort4*)(A + (size_t)(row0 + ar) * K + k0 + ak4);
            av = make_float4(bf2f(h4.x), bf2f(h4.y), bf2f(h4.z), bf2f(h4.w));
        }
        *(float4*)&As[ar][ak4] = av;
        *(float4*)&Bs[bk][bc4] = *(const float4*)(B + (size_t)(k0 + bk) * 16 + bc4);
        __syncthreads();
        #pragma unroll
        for (int kk = 0; kk < 64; ++kk)
            acc = fmaf(As[r][kk], Bs[kk][c], acc);
        __syncthreads();
    }
    if (row0 + r < M) C[(size_t)(row0 + r) * 16 + c] = acc;
}

// ---------------- fused MFMA edge MLPs: eb = exp(mlp1(kr)), eb2 = exp(mlp2(kr)) ----------------
// one wave per 16-edge tile; weights live in VGPRs as B-frags; LDS tile for C->A transform.
#define TSTR 72   // LDS tile row stride in bf16 elems (144 B: 16B-aligned frag reads, <=2-way banks)
__global__ __launch_bounds__(256) void edge_mlps_k(
    const float* __restrict__ kr,
    const u16* __restrict__ w1f, const u16* __restrict__ w2f, const float* __restrict__ b2a,
    const u16* __restrict__ w3f, const u16* __restrict__ w4f, const float* __restrict__ b2b,
    u16* __restrict__ eb, u16* __restrict__ eb2)
{
    __shared__ __align__(16) u16 T[4][16 * TSTR];
    const int t = threadIdx.x, wv = t >> 6, lane = t & 63;
    const int lm = lane & 15, quad = lane >> 4;
    const int tile = blockIdx.x * 4 + wv;
    const int e0 = tile * 16;
    if (e0 >= E_TOT) return;
    u16* Tw = T[wv];

    // weight fragments -> VGPRs (per-lane)
    short8 W1[4], W2[2][4];
    #pragma unroll
    for (int nt = 0; nt < 4; ++nt) W1[nt] = *(const short8*)(w1f + ((size_t)nt * 64 + lane) * 8);
    #pragma unroll
    for (int ks = 0; ks < 2; ++ks)
        #pragma unroll
        for (int nt = 0; nt < 4; ++nt)
            W2[ks][nt] = *(const short8*)(w2f + (((size_t)ks * 4 + nt) * 64 + lane) * 8);
    short8 W3 = *(const short8*)(w3f + (size_t)lane * 8);
    short8 W4 = *(const short8*)(w4f + (size_t)lane * 8);
    float b2av[4];
    #pragma unroll
    for (int nt = 0; nt < 4; ++nt) b2av[nt] = b2a[nt * 16 + lm];
    float b2bv = b2b[lm];

    // A-frag from kr: edge m = e0+lm, k = quad*8+j (K=16 zero-padded to 32)
    short8 af = {};
    if (quad < 2) {
        const float* kp = kr + (size_t)(e0 + lm) * NC + quad * 8;
        float4 v0 = *(const float4*)kp;
        float4 v1 = *(const float4*)(kp + 4);
        u16 tmp[8] = {f2bf(v0.x), f2bf(v0.y), f2bf(v0.z), f2bf(v0.w),
                      f2bf(v1.x), f2bf(v1.y), f2bf(v1.z), f2bf(v1.w)};
        af = *(const short8*)tmp;
    }

    // ---- MLP1 layer 1: [16 edges x 64] = kr @ w1, leaky 0.2 ----
    f32x4 a1[4] = {};
    #pragma unroll
    for (int nt = 0; nt < 4; ++nt)
        a1[nt] = __builtin_amdgcn_mfma_f32_16x16x32_bf16(af, W1[nt], a1[nt], 0, 0, 0);
    #pragma unroll
    for (int nt = 0; nt < 4; ++nt)
        #pragma unroll
        for (int r = 0; r < 4; ++r) {
            float v = a1[nt][r];
            v = v > 0.f ? v : 0.2f * v;
            Tw[(quad * 4 + r) * TSTR + nt * 16 + lm] = f2bf(v);
        }
    __builtin_amdgcn_s_waitcnt(0);   // drain LDS writes before same-wave reads

    // ---- MLP1 layer 2: K=64 from LDS tile ----
    short8 a2[2];
    #pragma unroll
    for (int ks = 0; ks < 2; ++ks)
        a2[ks] = *(const short8*)&Tw[lm * TSTR + ks * 32 + quad * 8];
    f32x4 c2[4] = {};
    #pragma unroll
    for (int nt = 0; nt < 4; ++nt)
        #pragma unroll
        for (int ks = 0; ks < 2; ++ks)
            c2[nt] = __builtin_amdgcn_mfma_f32_16x16x32_bf16(a2[ks], W2[ks][nt], c2[nt], 0, 0, 0);
    // epilogue: + b2, exp -> LDS
    #pragma unroll
    for (int nt = 0; nt < 4; ++nt)
        #pragma unroll
        for (int r = 0; r < 4; ++r)
            Tw[(quad * 4 + r) * TSTR + nt * 16 + lm] = f2bf(__expf(c2[nt][r] + b2av[nt]));
    __builtin_amdgcn_s_waitcnt(0);
    // repack: coalesced 16B stores of full rows
    #pragma unroll
    for (int p = 0; p < 2; ++p) {
        int c = p * 64 + lane;
        int row = c >> 3, off = (c & 7) * 8;
        short8 v = *(const short8*)&Tw[row * TSTR + off];
        *(short8*)(eb + (size_t)(e0 + row) * HID + off) = v;
    }

    // ---- MLP2 (16->16->16), reuses kr A-frag ----
    f32x4 b1 = __builtin_amdgcn_mfma_f32_16x16x32_bf16(af, W3, (f32x4){}, 0, 0, 0);
    __builtin_amdgcn_s_waitcnt(0);   // eb repack reads done before overwrite
    #pragma unroll
    for (int r = 0; r < 4; ++r) {
        float v = b1[r];
        v = v > 0.f ? v : 0.2f * v;
        Tw[(quad * 4 + r) * TSTR + lm] = f2bf(v);
    }
    __builtin_amdgcn_s_waitcnt(0);
    // A-frag: cols 16..31 hold stale finite values, but W4 is zero there -> no effect
    short8 a3 = *(const short8*)&Tw[lm * TSTR + quad * 8];
    f32x4 c3 = __builtin_amdgcn_mfma_f32_16x16x32_bf16(a3, W4, (f32x4){}, 0, 0, 0);
    #pragma unroll
    for (int r = 0; r < 4; ++r)
        Tw[(quad * 4 + r) * TSTR + lm] = f2bf(__expf(c3[r] + b2bv));
    __builtin_amdgcn_s_waitcnt(0);
    if (lane < 32) {
        int row = lane >> 1, off = (lane & 1) * 8;
        short8 v = *(const short8*)&Tw[row * TSTR + off];
        *(short8*)(eb2 + (size_t)(e0 + row) * NCLS + off) = v;
    }
}

// ---------------- inverse softmax denominator, layer 1 (wave per src) ----------------
__global__ __launch_bounds__(256) void s1sum_k(
    const u16* __restrict__ eb, const int* __restrict__ src_off, const int* __restrict__ src_list,
    float* __restrict__ inv1)
{
    int gid = blockIdx.x * 256 + threadIdx.x;
    int wid = gid >> 6, lane = gid & 63;
    if (wid >= N_NODES) return;
    int o0 = src_off[wid], o1 = src_off[wid + 1];
    float sum = 0.f;
    for (int i = o0; i < o1; ++i) {
        int el = src_list[i];
        sum += bf2f(eb[(size_t)el * HID + lane]);
    }
    inv1[(size_t)wid * HID + lane] = 1.f / (sum + 1e-16f);
}

// ---------------- message pass 1 (wave per dst, 8 heads x 64 ch), no atomics ----------------
__global__ __launch_bounds__(256) void msg1_k(
    const u16* __restrict__ eb, const float* __restrict__ inv1,
    const u16* __restrict__ xb, const int* __restrict__ ei,
    const int* __restrict__ dst_off, const int* __restrict__ dst_list,
    u16* __restrict__ aggb)
{
    int gid = blockIdx.x * 256 + threadIdx.x;
    int wid = gid >> 6, lane = gid & 63;
    if (wid >= N_NODES) return;
    int o0 = dst_off[wid], o1 = dst_off[wid + 1];
    float acc[HEADS] = {0.f, 0.f, 0.f, 0.f, 0.f, 0.f, 0.f, 0.f};
    for (int i = o0; i < o1; ++i) {
        int el = dst_list[i];
        int s = edge_src(ei, el);
        float a = bf2f(eb[(size_t)el * HID + lane]) * inv1[(size_t)s * HID + lane];
        const u16* xr = xb + (size_t)s * H1 + lane;
        #pragma unroll
        for (int h = 0; h < HEADS; ++h)
            acc[h] = fmaf(a, bf2f(xr[h * 64]), acc[h]);
    }
    u16* ar = aggb + (size_t)wid * H1 + lane;
    #pragma unroll
    for (int h = 0; h < HEADS; ++h) ar[h * 64] = f2bf(acc[h]);
}

// ---------------- inverse denominator, layer 2 (16 threads per src) ----------------
__global__ __launch_bounds__(256) void s2sum_k(
    const u16* __restrict__ eb, const int* __restrict__ src_off, const int* __restrict__ src_list,
    float* __restrict__ inv2)
{
    int t = threadIdx.x;
    int g = blockIdx.x * 16 + (t >> 4), c = t & 15;
    if (g >= N_NODES) return;
    int o0 = src_off[g], o1 = src_off[g + 1];
    float sum = 0.f;
    for (int i = o0; i < o1; ++i) {
        int el = src_list[i];
        sum += bf2f(eb[(size_t)el * NCLS + c]);
    }
    inv2[(size_t)g * NCLS + c] = 1.f / (sum + 1e-16f);
}

// ---------------- message pass 2 (16 threads per dst), no atomics ----------------
__global__ __launch_bounds__(256) void msg2_k(
    const u16* __restrict__ eb, const float* __restrict__ inv2,
    const float* __restrict__ xh2, const int* __restrict__ ei,
    const int* __restrict__ dst_off, const int* __restrict__ dst_list,
    float* __restrict__ agg2)
{
    int t = threadIdx.x;
    int g = blockIdx.x * 16 + (t >> 4), c = t & 15;
    if (g >= N_NODES) return;
    int o0 = dst_off[g], o1 = dst_off[g + 1];
    float acc = 0.f;
    for (int i = o0; i < o1; ++i) {
        int el = dst_list[i];
        int s = edge_src(ei, el);
        float a = bf2f(eb[(size_t)el * NCLS + c]) * inv2[(size_t)s * NCLS + c];
        acc = fmaf(a, xh2[(size_t)s * NCLS + c], acc);
    }
    agg2[(size_t)g * NCLS + c] = acc;
}

// ---------------- final: o = agg2 + bias2 + alpha*p2; log_softmax ----------------
__global__ __launch_bounds__(256) void final_k(
    const float* __restrict__ agg2, const float* __restrict__ ep,
    const float* __restrict__ pw1, const float* __restrict__ pw2,
    const float* __restrict__ pb2, const float* __restrict__ bias,
    const float* __restrict__ alpha_p, float* __restrict__ out)
{
    __shared__ float s1w[256], s2w[256], sb[16], sbias[16];
    const int t = threadIdx.x;
    s1w[t] = pw1[t];
    s2w[t] = pw2[t];
    if (t < 16) { sb[t] = pb2[t]; sbias[t] = bias[t]; }
    __syncthreads();
    const int v = blockIdx.x * 256 + t;
    if (v >= N_NODES) return;
    float alpha = *alpha_p;
    float e_[16];
    #pragma unroll
    for (int j4 = 0; j4 < 16; j4 += 4) {
        float4 vv = *(const float4*)(ep + (size_t)v * 16 + j4);
        e_[j4] = vv.x; e_[j4 + 1] = vv.y; e_[j4 + 2] = vv.z; e_[j4 + 3] = vv.w;
    }
    float t2[16];
    #pragma unroll
    for (int c = 0; c < 16; ++c) {
        float s = 0.f;
        #pragma unroll
        for (int j = 0; j < 16; ++j) s = fmaf(e_[j], s1w[j * 16 + c], s);
        t2[c] = s > 0.f ? s : 0.2f * s;
    }
    float o[16];
    #pragma unroll
    for (int c4 = 0; c4 < 16; c4 += 4) {
        float4 ag = *(const float4*)(agg2 + (size_t)v * 16 + c4);
        float agv[4] = {ag.x, ag.y, ag.z, ag.w};
        #pragma unroll
        for (int q = 0; q < 4; ++q) {
            int c = c4 + q;
            float p = sb[c];
            #pragma unroll
            for (int j = 0; j < 16; ++j) p = fmaf(t2[j], s2w[j * 16 + c], p);
            p = p > 0.f ? p : 0.01f * p;
            o[c] = agv[q] + sbias[c] + alpha * p;
        }
    }
    float mx = o[0];
    #pragma unroll
    for (int c = 1; c < 16; ++c) mx = fmaxf(mx, o[c]);
    float se = 0.f;
    #pragma unroll
    for (int c = 0; c < 16; ++c) se += expf(o[c] - mx);
    float lse = mx + logf(se);
    #pragma unroll
    for (int c4 = 0; c4 < 16; c4 += 4)
        *(float4*)(out + (size_t)v * 16 + c4) =
            make_float4(o[c4] - lse, o[c4 + 1] - lse, o[c4 + 2] - lse, o[c4 + 3] - lse);
}

extern "C" void kernel_launch(void* const* d_in, const int* in_sizes, int n_in,
                              void* d_out, int out_size, void* d_ws, size_t ws_size,
                              hipStream_t stream) {
    const float* x    = (const float*)d_in[0];
    const int*   ei   = (const int*)d_in[1];
    const float* alpha= (const float*)d_in[2];
    const float* kr   = (const float*)d_in[3];
    const float* ep   = (const float*)d_in[4];
    const float* W1   = (const float*)d_in[5];
    const float* h1w1 = (const float*)d_in[6];
    const float* h1w2 = (const float*)d_in[7];
    const float* h1b2 = (const float*)d_in[8];
    const float* p1w1 = (const float*)d_in[9];
    const float* p1w2 = (const float*)d_in[10];
    const float* p1b2 = (const float*)d_in[11];
    const float* b1   = (const float*)d_in[12];
    const float* W2   = (const float*)d_in[13];
    const float* h2w1 = (const float*)d_in[14];
    const float* h2w2 = (const float*)d_in[15];
    const float* h2b2 = (const float*)d_in[16];
    const float* p2w1 = (const float*)d_in[17];
    const float* p2w2 = (const float*)d_in[18];
    const float* p2b2 = (const float*)d_in[19];
    const float* b2   = (const float*)d_in[20];
    float* out = (float*)d_out;

    // ---- workspace bump allocator (~236 MB) ----
    char* p = (char*)d_ws;
    auto alloc = [&](size_t bytes) { char* r = p; p += (bytes + 255) & ~(size_t)255; return r; };

    char* r0    = alloc((size_t)64 * M_PAD * 16);          // 51.25 MB: xb (row-major bf16 N x 512), then t1p (frag-major)
    u16*  xb    = (u16*)r0;
    u16*  t1p   = (u16*)r0;
    u16*  aggb  = (u16*)alloc((size_t)N_NODES * H1 * 2);   // 51.2 MB bf16
    char* ebr   = alloc((size_t)E_TOT * HID * 2);          // 83.2 MB: eb (E'x64), then hb (Nx512)
    u16*  eb    = (u16*)ebr;
    u16*  hb    = (u16*)ebr;
    u16*  eb2   = (u16*)alloc((size_t)E_TOT * NCLS * 2);   // 20.8 MB (written early by edge_mlps_k)
    char* xpr   = alloc((size_t)16 * M_PAD * 16);          // 12.81 MB: xp (frag-major x), then inv1 (Nx64 f32)
    u16*  xp    = (u16*)xpr;
    float* inv1 = (float*)xpr;
    u16*  W1p   = (u16*)alloc((size_t)16 * H1 * 16);       // 128 KB
    u16*  p1w2p = (u16*)alloc((size_t)64 * H1 * 16);       // 512 KB
    u16*  w1f   = (u16*)alloc(2048 * 2);                   // mlp1 w1 frags [1][4][64][8]
    u16*  w2f   = (u16*)alloc(4096 * 2);                   // mlp1 w2 frags [2][4][64][8]
    u16*  w3f   = (u16*)alloc(512 * 2);                    // mlp2 w1 frags [1][1][64][8]
    u16*  w4f   = (u16*)alloc(512 * 2);                    // mlp2 w2 frags
    int* src_cnt  = (int*)alloc(N_NODES * 4);
    int* dst_cnt  = (int*)alloc(N_NODES * 4);
    int* src_cur  = (int*)alloc(N_NODES * 4);
    int* dst_cur  = (int*)alloc(N_NODES * 4);
    int* src_off  = (int*)alloc((N_NODES + 1) * 4);
    int* dst_off  = (int*)alloc((N_NODES + 1) * 4);
    int* src_list = (int*)alloc((size_t)E_TOT * 4);
    int* dst_list = (int*)alloc((size_t)E_TOT * 4);
    float* xh2  = (float*)alloc((size_t)N_NODES * NCLS * 4);
    float* agg2 = (float*)alloc((size_t)N_NODES * NCLS * 4);
    float* inv2 = (float*)alloc((size_t)N_NODES * NCLS * 4);

    const dim3 blk(256);
    const int EB = (E_TOT + 255) / 256;
    const int WB = (N_NODES * 64 + 255) / 256;
    const int GB16 = (N_NODES + 15) / 16;
    const dim3 gmm(512 / 128, M_PAD / 128);                 // (4, 391)
    const int MLPB = (E_TOT / 16 + 3) / 4;                  // 10157 blocks, 4 wave-tiles each

    // ---- CSR build + weight/layout conversion ----
    hipMemsetAsync(src_cnt, 0, (char*)src_off - (char*)src_cnt, stream);  // cnts + curs (contiguous allocs)
    count_k<<<EB, blk, 0, stream>>>(ei, src_cnt, dst_cnt);
    scan2_k<<<1, 1024, 0, stream>>>(src_cnt, dst_cnt, src_off, dst_off);
    fill_csr_k<<<EB, blk, 0, stream>>>(ei, src_off, dst_off, src_cur, dst_cur, src_list, dst_list);
    conv_a_k<<<(16 * M_PAD + 255) / 256, blk, 0, stream>>>(x, xp, N_NODES, M_PAD, F_IN);
    conv_b_k<<<(16 * H1 + 255) / 256, blk, 0, stream>>>(W1, W1p, F_IN, H1);
    conv_b_k<<<(64 * H1 + 255) / 256, blk, 0, stream>>>(p1w2, p1w2p, H1, H1);
    conv_wfrag_k<<<8, blk, 0, stream>>>(h1w1, w1f, 16, 32, 64);
    conv_wfrag_k<<<16, blk, 0, stream>>>(h1w2, w2f, 64, 64, 64);
    conv_wfrag_k<<<2, blk, 0, stream>>>(h2w1, w3f, 16, 32, 16);
    conv_wfrag_k<<<2, blk, 0, stream>>>(h2w2, w4f, 16, 32, 16);

    // ---- layer 1 ----
    mfma_gemm_k<0><<<gmm, blk, 0, stream>>>(xp, W1p, xb, N_NODES, M_PAD, H1, F_IN,
                                            nullptr, nullptr, nullptr, nullptr);
    edge_mlps_k<<<MLPB, blk, 0, stream>>>(kr, w1f, w2f, h1b2, w3f, w4f, h2b2, eb, eb2);
    s1sum_k<<<WB, blk, 0, stream>>>(eb, src_off, src_list, inv1);
    msg1_k<<<WB, blk, 0, stream>>>(eb, inv1, xb, ei, dst_off, dst_list, aggb);
    gemm_t1_k<<<dim3(8, (N_NODES + 63) / 64), blk, 0, stream>>>(ep, p1w1, t1p);   // overwrites xb region
    mfma_gemm_k<3><<<gmm, blk, 0, stream>>>(t1p, p1w2p, hb, N_NODES, M_PAD, H1, H1,
                                            p1b2, aggb, b1, alpha);               // hb overwrites eb region

    // ---- layer 2 ----
    gemm_n16_k<<<(N_NODES + 15) / 16, blk, 0, stream>>>(hb, W2, xh2, N_NODES, H1);
    s2sum_k<<<GB16, blk, 0, stream>>>(eb2, src_off, src_list, inv2);
    msg2_k<<<GB16, blk, 0, stream>>>(eb2, inv2, xh2, ei, dst_off, dst_list, agg2);
    final_k<<<(N_NODES + 255) / 256, blk, 0, stream>>>(agg2, ep, p2w1, p2w2, p2b2, b2, alpha, out);
}

// Round 5
// 787.050 us; speedup vs baseline: 1.7767x; 1.2146x over previous
//
#include <hip/hip_runtime.h>
#include <math.h>

#define N_NODES 50000
#define M_PAD   50048    // N_NODES padded to multiple of 128 for MFMA tiles
#define N_EDGES 600000
#define E_TOT   650000   // N_EDGES + N_NODES (self loops appended)
#define F_IN    128
#define HID     64
#define HEADS   8
#define H1      512      // HEADS*HID
#define NCLS    16
#define NC      16
#define NCP     16
#define NBLK    ((N_NODES + 255) / 256)   // 196 scan blocks per array

typedef unsigned short u16;
typedef __attribute__((ext_vector_type(8))) short short8;   // 8 bf16 = 4 VGPRs (MFMA A/B frag)
typedef __attribute__((ext_vector_type(4))) float f32x4;    // MFMA C/D frag

__device__ __forceinline__ float bf2f(u16 h) {
    return __uint_as_float(((unsigned)h) << 16);
}
__device__ __forceinline__ u16 f2bf(float f) {
    unsigned u = __float_as_uint(f);
    u += 0x7fffu + ((u >> 16) & 1u);
    return (u16)(u >> 16);
}
__device__ __forceinline__ int edge_src(const int* __restrict__ ei, int e) {
    return (e < N_EDGES) ? ei[e] : (e - N_EDGES);
}
__device__ __forceinline__ int edge_dst(const int* __restrict__ ei, int e) {
    return (e < N_EDGES) ? ei[N_EDGES + e] : (e - N_EDGES);
}

// ---------------- CSR build ----------------
__global__ __launch_bounds__(256) void count_k(const int* __restrict__ ei,
                                               int* __restrict__ src_cnt, int* __restrict__ dst_cnt) {
    int e = blockIdx.x * 256 + threadIdx.x;
    if (e >= E_TOT) return;
    atomicAdd(&src_cnt[edge_src(ei, e)], 1);
    atomicAdd(&dst_cnt[edge_dst(ei, e)], 1);
}

// Phase A: per-block partial sums. grid = 2*NBLK (src blocks, then dst blocks).
__global__ __launch_bounds__(256) void scanA_k(const int* __restrict__ src_cnt,
                                               const int* __restrict__ dst_cnt,
                                               int* __restrict__ partials) {
    int pass = blockIdx.x >= NBLK;
    int b = blockIdx.x - pass * NBLK;
    const int* cnt = pass ? dst_cnt : src_cnt;
    int idx = b * 256 + threadIdx.x;
    int v = (idx < N_NODES) ? cnt[idx] : 0;
    __shared__ int red[4];
    #pragma unroll
    for (int off = 32; off; off >>= 1) v += __shfl_down(v, off, 64);
    if ((threadIdx.x & 63) == 0) red[threadIdx.x >> 6] = v;
    __syncthreads();
    if (threadIdx.x == 0) partials[blockIdx.x] = red[0] + red[1] + red[2] + red[3];
}

// Phase B: two independent exclusive scans of NBLK partials (src seg, dst seg), one block.
__global__ __launch_bounds__(512) void scanB_k(int* __restrict__ partials) {
    __shared__ int lds[512];
    int t = threadIdx.x;           // 512 threads: t<256 -> src segment, else dst
    int seg = t >> 8, i = t & 255;
    int v = (i < NBLK) ? partials[seg * NBLK + i] : 0;
    lds[t] = v;
    __syncthreads();
    for (int d = 1; d < 256; d <<= 1) {
        int x = (i >= d) ? lds[seg * 256 + i - d] : 0;
        __syncthreads();
        lds[t] += x;
        __syncthreads();
    }
    if (i < NBLK) partials[seg * NBLK + i] = lds[t] - v;   // exclusive
}

// Phase C: block-local exclusive scan + block offset -> off[]; off[N]=E_TOT constant.
__global__ __launch_bounds__(256) void scanC_k(const int* __restrict__ src_cnt,
                                               const int* __restrict__ dst_cnt,
                                               const int* __restrict__ partials,
                                               int* __restrict__ src_off, int* __restrict__ dst_off) {
    int pass = blockIdx.x >= NBLK;
    int b = blockIdx.x - pass * NBLK;
    const int* cnt = pass ? dst_cnt : src_cnt;
    int* off = pass ? dst_off : src_off;
    int base = partials[blockIdx.x];
    __shared__ int lds[256];
    int t = threadIdx.x;
    int idx = b * 256 + t;
    int v = (idx < N_NODES) ? cnt[idx] : 0;
    lds[t] = v;
    __syncthreads();
    for (int d = 1; d < 256; d <<= 1) {
        int x = (t >= d) ? lds[t - d] : 0;
        __syncthreads();
        lds[t] += x;
        __syncthreads();
    }
    if (idx < N_NODES) off[idx] = base + lds[t] - v;
    if (b == 0 && t == 0) off[N_NODES] = E_TOT;
}

__global__ __launch_bounds__(256) void fill_csr_k(const int* __restrict__ ei,
                                                  const int* __restrict__ src_off, const int* __restrict__ dst_off,
                                                  int* __restrict__ src_cur, int* __restrict__ dst_cur,
                                                  int* __restrict__ src_list, int* __restrict__ dst_list) {
    int e = blockIdx.x * 256 + threadIdx.x;
    if (e >= E_TOT) return;
    int s = edge_src(ei, e), d = edge_dst(ei, e);
    int ps = atomicAdd(&src_cur[s], 1);
    src_list[src_off[s] + ps] = e;
    int pd = atomicAdd(&dst_cur[d], 1);
    dst_list[dst_off[d] + pd] = e;
}

// ---------------- layout converters ----------------
// f32 [M][K] row-major -> bf16 fragment-major Ap[K/8][Mp][8]; pad rows zeroed
__global__ __launch_bounds__(256) void conv_a_k(const float* __restrict__ A, u16* __restrict__ Ap,
                                                int M, int Mp, int K) {
    int i = blockIdx.x * 256 + threadIdx.x;
    int total = (K >> 3) * Mp;
    if (i >= total) return;
    int r = i % Mp;
    int kb = i / Mp;
    u16* o = Ap + (size_t)i * 8;
    u16 tmp[8];
    if (r < M) {
        const float* a = A + (size_t)r * K + kb * 8;
        #pragma unroll
        for (int j = 0; j < 8; ++j) tmp[j] = f2bf(a[j]);
    } else {
        #pragma unroll
        for (int j = 0; j < 8; ++j) tmp[j] = 0;
    }
    *(ushort4*)o = *(ushort4*)tmp;
    *(ushort4*)(o + 4) = *(ushort4*)(tmp + 4);
}

// f32 [K][N] row-major -> bf16 fragment-major Bp[K/8][N][8] (Bp[kb][n][j] = B[kb*8+j][n])
__global__ __launch_bounds__(256) void conv_b_k(const float* __restrict__ B, u16* __restrict__ Bp,
                                                int K, int N) {
    int i = blockIdx.x * 256 + threadIdx.x;
    int total = (K >> 3) * N;
    if (i >= total) return;
    int n = i % N;
    int kb = i / N;
    u16 tmp[8];
    #pragma unroll
    for (int j = 0; j < 8; ++j) tmp[j] = f2bf(B[(size_t)(kb * 8 + j) * N + n]);
    u16* o = Bp + (size_t)i * 8;
    *(ushort4*)o = *(ushort4*)tmp;
    *(ushort4*)(o + 4) = *(ushort4*)(tmp + 4);
}

// f32 W[K][N] row-major -> per-lane B-frag table [Kpad/32][N/16][64][8], zero-padded beyond K
__global__ __launch_bounds__(256) void conv_wfrag_k(const float* __restrict__ W, u16* __restrict__ o,
                                                    int K, int Kpad, int N) {
    int i = blockIdx.x * 256 + threadIdx.x;
    int total = (Kpad / 32) * (N / 16) * 64 * 8;
    if (i >= total) return;
    int j = i & 7, lane = (i >> 3) & 63, rest = i >> 9;
    int ntn = N / 16;
    int nt = rest % ntn, ks = rest / ntn;
    int lm = lane & 15, quad = lane >> 4;
    int k = ks * 32 + quad * 8 + j, n = nt * 16 + lm;
    o[i] = (k < K) ? f2bf(W[(size_t)k * N + n]) : (u16)0;
}

// ---------------- MFMA GEMM: C[M][N] = epi(Ap @ Bp), frag-major operands, no LDS ----------------
// block tile 128x128, 4 waves in 2x2, wave tile 64x64 (4x4 frags of 16x16x32)
// EPI 0: C = A@B                              (store bf16, row-major)
// EPI 3: C = relu(extra + bias2 + alpha * leaky(A@B + bias, 0.01))   (store bf16)
template<int EPI>
__global__ __launch_bounds__(256) void mfma_gemm_k(
    const u16* __restrict__ Ap, const u16* __restrict__ Bp, u16* __restrict__ C,
    int M, int Mp, int Nn, int K,
    const float* __restrict__ bias, const u16* __restrict__ extra,
    const float* __restrict__ bias2, const float* __restrict__ alpha_p)
{
    const int t = threadIdx.x;
    const int wave = t >> 6, lane = t & 63;
    const int wm = (wave >> 1) * 64, wn = (wave & 1) * 64;
    const int bm = blockIdx.y * 128, bn = blockIdx.x * 128;
    const int lm = lane & 15, quad = lane >> 4;

    size_t rbase[4], cbase[4];
    #pragma unroll
    for (int mi = 0; mi < 4; ++mi) rbase[mi] = (size_t)(bm + wm + mi * 16 + lm) * 8;
    #pragma unroll
    for (int nj = 0; nj < 4; ++nj) cbase[nj] = (size_t)(bn + wn + nj * 16 + lm) * 8;

    f32x4 acc[4][4] = {};

    for (int k0 = 0; k0 < K; k0 += 32) {
        int kb = (k0 >> 3) + quad;
        size_t abase = (size_t)kb * Mp * 8;
        size_t bbase = (size_t)kb * Nn * 8;
        short8 af[4], bf_[4];
        #pragma unroll
        for (int mi = 0; mi < 4; ++mi) af[mi] = *(const short8*)(Ap + abase + rbase[mi]);
        #pragma unroll
        for (int nj = 0; nj < 4; ++nj) bf_[nj] = *(const short8*)(Bp + bbase + cbase[nj]);
        #pragma unroll
        for (int mi = 0; mi < 4; ++mi)
            #pragma unroll
            for (int nj = 0; nj < 4; ++nj)
                acc[mi][nj] = __builtin_amdgcn_mfma_f32_16x16x32_bf16(af[mi], bf_[nj], acc[mi][nj], 0, 0, 0);
    }

    // C/D layout: col = lane&15, row = quad*4 + reg
    const int orow = bm + wm + quad * 4;
    const int ocol = bn + wn + lm;
    if (EPI == 0) {
        #pragma unroll
        for (int mi = 0; mi < 4; ++mi)
            #pragma unroll
            for (int r = 0; r < 4; ++r) {
                int rr = orow + mi * 16 + r;
                if (rr >= M) continue;
                #pragma unroll
                for (int nj = 0; nj < 4; ++nj)
                    C[(size_t)rr * Nn + ocol + nj * 16] = f2bf(acc[mi][nj][r]);
            }
    } else {
        float alpha = *alpha_p;
        #pragma unroll
        for (int mi = 0; mi < 4; ++mi)
            #pragma unroll
            for (int r = 0; r < 4; ++r) {
                int rr = orow + mi * 16 + r;
                if (rr >= M) continue;
                #pragma unroll
                for (int nj = 0; nj < 4; ++nj) {
                    int c = ocol + nj * 16;
                    float v = acc[mi][nj][r] + bias[c];
                    v = v > 0.f ? v : 0.01f * v;
                    float o = bf2f(extra[(size_t)rr * Nn + c]) + bias2[c] + alpha * v;
                    o = fmaxf(o, 0.f);
                    C[(size_t)rr * Nn + c] = f2bf(o);
                }
            }
    }
}

// ---------------- t1 = leaky(ep @ p1w1, 0.2), K=16, written in frag-major Ap layout ----------------
__global__ __launch_bounds__(256) void gemm_t1_k(
    const float* __restrict__ ep, const float* __restrict__ W, u16* __restrict__ t1p)
{
    __shared__ float Bs[16][64];
    const int bm = blockIdx.y * 64, bn = blockIdx.x * 64;
    const int t = threadIdx.x;
    const int tx = t & 15, ty = t >> 4;
    *(float4*)&Bs[t >> 4][(t & 15) * 4] = *(const float4*)&W[(size_t)(t >> 4) * H1 + bn + (t & 15) * 4];
    __syncthreads();
    const int r0 = bm + ty * 4;
    const int c0 = bn + tx * 4;
    for (int i = 0; i < 4; ++i) {
        int r = r0 + i;
        if (r >= N_NODES) continue;
        float av[16];
        #pragma unroll
        for (int j4 = 0; j4 < 16; j4 += 4) {
            float4 v = *(const float4*)(ep + (size_t)r * NCP + j4);
            av[j4] = v.x; av[j4 + 1] = v.y; av[j4 + 2] = v.z; av[j4 + 3] = v.w;
        }
        u16 pk[4];
        #pragma unroll
        for (int q = 0; q < 4; ++q) {
            float s = 0.f;
            #pragma unroll
            for (int k = 0; k < 16; ++k) s = fmaf(av[k], Bs[k][tx * 4 + q], s);
            s = s > 0.f ? s : 0.2f * s;
            pk[q] = f2bf(s);
        }
        u16* o = t1p + ((size_t)(c0 >> 3) * M_PAD + r) * 8 + (c0 & 7);
        *(ushort4*)o = *(ushort4*)pk;
    }
}

// ---------------- N=16 GEMM (xh2 = h @ W_src2), bf16 A, K multiple of 64 ----------------
__global__ __launch_bounds__(256) void gemm_n16_k(
    const u16* __restrict__ A, const float* __restrict__ B, float* __restrict__ C,
    int M, int K)
{
    __shared__ float As[16][64];   // [row][k]
    __shared__ float Bs[64][16];   // [k][col]
    const int row0 = blockIdx.x * 16;
    const int t = threadIdx.x;
    const int r = t >> 4, c = t & 15;
    const int ar = t >> 4, ak4 = (t & 15) * 4;
    const int bk = t >> 2, bc4 = (t & 3) * 4;
    float acc = 0.f;
    for (int k0 = 0; k0 < K; k0 += 64) {
        float4 av = make_float4(0.f, 0.f, 0.f, 0.f);
        if (row0 + ar < M) {
            ushort4 h4 = *(const ushort4*)(A + (size_t)(row0 + ar) * K + k0 + ak4);
            av = make_float4(bf2f(h4.x), bf2f(h4.y), bf2f(h4.z), bf2f(h4.w));
        }
        *(float4*)&As[ar][ak4] = av;
        *(float4*)&Bs[bk][bc4] = *(const float4*)(B + (size_t)(k0 + bk) * 16 + bc4);
        __syncthreads();
        #pragma unroll
        for (int kk = 0; kk < 64; ++kk)
            acc = fmaf(As[r][kk], Bs[kk][c], acc);
        __syncthreads();
    }
    if (row0 + r < M) C[(size_t)(row0 + r) * 16 + c] = acc;
}

// ---------------- fused MFMA edge MLPs: eb = exp(mlp1(kr)), eb2 = exp(mlp2(kr)) ----------------
// one wave per 16-edge tile; weights live in VGPRs as B-frags; LDS tile for C->A transform.
#define TSTR 72   // LDS tile row stride in bf16 elems (144 B: 16B-aligned frag reads, <=2-way banks)
__global__ __launch_bounds__(256) void edge_mlps_k(
    const float* __restrict__ kr,
    const u16* __restrict__ w1f, const u16* __restrict__ w2f, const float* __restrict__ b2a,
    const u16* __restrict__ w3f, const u16* __restrict__ w4f, const float* __restrict__ b2b,
    u16* __restrict__ eb, u16* __restrict__ eb2)
{
    __shared__ __align__(16) u16 T[4][16 * TSTR];
    const int t = threadIdx.x, wv = t >> 6, lane = t & 63;
    const int lm = lane & 15, quad = lane >> 4;
    const int tile = blockIdx.x * 4 + wv;
    const int e0 = tile * 16;
    if (e0 >= E_TOT) return;
    u16* Tw = T[wv];

    // weight fragments -> VGPRs (per-lane)
    short8 W1[4], W2[2][4];
    #pragma unroll
    for (int nt = 0; nt < 4; ++nt) W1[nt] = *(const short8*)(w1f + ((size_t)nt * 64 + lane) * 8);
    #pragma unroll
    for (int ks = 0; ks < 2; ++ks)
        #pragma unroll
        for (int nt = 0; nt < 4; ++nt)
            W2[ks][nt] = *(const short8*)(w2f + (((size_t)ks * 4 + nt) * 64 + lane) * 8);
    short8 W3 = *(const short8*)(w3f + (size_t)lane * 8);
    short8 W4 = *(const short8*)(w4f + (size_t)lane * 8);
    float b2av[4];
    #pragma unroll
    for (int nt = 0; nt < 4; ++nt) b2av[nt] = b2a[nt * 16 + lm];
    float b2bv = b2b[lm];

    // A-frag from kr: edge m = e0+lm, k = quad*8+j (K=16 zero-padded to 32)
    short8 af = {};
    if (quad < 2) {
        const float* kp = kr + (size_t)(e0 + lm) * NC + quad * 8;
        float4 v0 = *(const float4*)kp;
        float4 v1 = *(const float4*)(kp + 4);
        u16 tmp[8] = {f2bf(v0.x), f2bf(v0.y), f2bf(v0.z), f2bf(v0.w),
                      f2bf(v1.x), f2bf(v1.y), f2bf(v1.z), f2bf(v1.w)};
        af = *(const short8*)tmp;
    }

    // ---- MLP1 layer 1: [16 edges x 64] = kr @ w1, leaky 0.2 ----
    f32x4 a1[4] = {};
    #pragma unroll
    for (int nt = 0; nt < 4; ++nt)
        a1[nt] = __builtin_amdgcn_mfma_f32_16x16x32_bf16(af, W1[nt], a1[nt], 0, 0, 0);
    #pragma unroll
    for (int nt = 0; nt < 4; ++nt)
        #pragma unroll
        for (int r = 0; r < 4; ++r) {
            float v = a1[nt][r];
            v = v > 0.f ? v : 0.2f * v;
            Tw[(quad * 4 + r) * TSTR + nt * 16 + lm] = f2bf(v);
        }
    __builtin_amdgcn_s_waitcnt(0);   // drain LDS writes before same-wave reads

    // ---- MLP1 layer 2: K=64 from LDS tile ----
    short8 a2[2];
    #pragma unroll
    for (int ks = 0; ks < 2; ++ks)
        a2[ks] = *(const short8*)&Tw[lm * TSTR + ks * 32 + quad * 8];
    f32x4 c2[4] = {};
    #pragma unroll
    for (int nt = 0; nt < 4; ++nt)
        #pragma unroll
        for (int ks = 0; ks < 2; ++ks)
            c2[nt] = __builtin_amdgcn_mfma_f32_16x16x32_bf16(a2[ks], W2[ks][nt], c2[nt], 0, 0, 0);
    // epilogue: + b2, exp -> LDS
    #pragma unroll
    for (int nt = 0; nt < 4; ++nt)
        #pragma unroll
        for (int r = 0; r < 4; ++r)
            Tw[(quad * 4 + r) * TSTR + nt * 16 + lm] = f2bf(__expf(c2[nt][r] + b2av[nt]));
    __builtin_amdgcn_s_waitcnt(0);
    // repack: coalesced 16B stores of full rows
    #pragma unroll
    for (int p = 0; p < 2; ++p) {
        int c = p * 64 + lane;
        int row = c >> 3, off = (c & 7) * 8;
        short8 v = *(const short8*)&Tw[row * TSTR + off];
        *(short8*)(eb + (size_t)(e0 + row) * HID + off) = v;
    }

    // ---- MLP2 (16->16->16), reuses kr A-frag ----
    f32x4 b1 = __builtin_amdgcn_mfma_f32_16x16x32_bf16(af, W3, (f32x4){}, 0, 0, 0);
    __builtin_amdgcn_s_waitcnt(0);   // eb repack reads done before overwrite
    #pragma unroll
    for (int r = 0; r < 4; ++r) {
        float v = b1[r];
        v = v > 0.f ? v : 0.2f * v;
        Tw[(quad * 4 + r) * TSTR + lm] = f2bf(v);
    }
    __builtin_amdgcn_s_waitcnt(0);
    // A-frag: cols 16..31 hold stale finite values, but W4 is zero there -> no effect
    short8 a3 = *(const short8*)&Tw[lm * TSTR + quad * 8];
    f32x4 c3 = __builtin_amdgcn_mfma_f32_16x16x32_bf16(a3, W4, (f32x4){}, 0, 0, 0);
    #pragma unroll
    for (int r = 0; r < 4; ++r)
        Tw[(quad * 4 + r) * TSTR + lm] = f2bf(__expf(c3[r] + b2bv));
    __builtin_amdgcn_s_waitcnt(0);
    if (lane < 32) {
        int row = lane >> 1, off = (lane & 1) * 8;
        short8 v = *(const short8*)&Tw[row * TSTR + off];
        *(short8*)(eb2 + (size_t)(e0 + row) * NCLS + off) = v;
    }
}

// ---------------- inverse softmax denominator, layer 1 (wave per src) ----------------
__global__ __launch_bounds__(256) void s1sum_k(
    const u16* __restrict__ eb, const int* __restrict__ src_off, const int* __restrict__ src_list,
    float* __restrict__ inv1)
{
    int gid = blockIdx.x * 256 + threadIdx.x;
    int wid = gid >> 6, lane = gid & 63;
    if (wid >= N_NODES) return;
    int o0 = src_off[wid], o1 = src_off[wid + 1];
    float sum = 0.f;
    for (int i = o0; i < o1; ++i) {
        int el = src_list[i];
        sum += bf2f(eb[(size_t)el * HID + lane]);
    }
    inv1[(size_t)wid * HID + lane] = 1.f / (sum + 1e-16f);
}

// ---------------- message pass 1 (wave per dst, 8 heads x 64 ch), no atomics ----------------
__global__ __launch_bounds__(256) void msg1_k(
    const u16* __restrict__ eb, const float* __restrict__ inv1,
    const u16* __restrict__ xb, const int* __restrict__ ei,
    const int* __restrict__ dst_off, const int* __restrict__ dst_list,
    u16* __restrict__ aggb)
{
    int gid = blockIdx.x * 256 + threadIdx.x;
    int wid = gid >> 6, lane = gid & 63;
    if (wid >= N_NODES) return;
    int o0 = dst_off[wid], o1 = dst_off[wid + 1];
    float acc[HEADS] = {0.f, 0.f, 0.f, 0.f, 0.f, 0.f, 0.f, 0.f};
    for (int i = o0; i < o1; ++i) {
        int el = dst_list[i];
        int s = edge_src(ei, el);
        float a = bf2f(eb[(size_t)el * HID + lane]) * inv1[(size_t)s * HID + lane];
        const u16* xr = xb + (size_t)s * H1 + lane;
        #pragma unroll
        for (int h = 0; h < HEADS; ++h)
            acc[h] = fmaf(a, bf2f(xr[h * 64]), acc[h]);
    }
    u16* ar = aggb + (size_t)wid * H1 + lane;
    #pragma unroll
    for (int h = 0; h < HEADS; ++h) ar[h * 64] = f2bf(acc[h]);
}

// ---------------- inverse denominator, layer 2 (16 threads per src) ----------------
__global__ __launch_bounds__(256) void s2sum_k(
    const u16* __restrict__ eb, const int* __restrict__ src_off, const int* __restrict__ src_list,
    float* __restrict__ inv2)
{
    int t = threadIdx.x;
    int g = blockIdx.x * 16 + (t >> 4), c = t & 15;
    if (g >= N_NODES) return;
    int o0 = src_off[g], o1 = src_off[g + 1];
    float sum = 0.f;
    for (int i = o0; i < o1; ++i) {
        int el = src_list[i];
        sum += bf2f(eb[(size_t)el * NCLS + c]);
    }
    inv2[(size_t)g * NCLS + c] = 1.f / (sum + 1e-16f);
}

// ---------------- message pass 2 (16 threads per dst), no atomics ----------------
__global__ __launch_bounds__(256) void msg2_k(
    const u16* __restrict__ eb, const float* __restrict__ inv2,
    const float* __restrict__ xh2, const int* __restrict__ ei,
    const int* __restrict__ dst_off, const int* __restrict__ dst_list,
    float* __restrict__ agg2)
{
    int t = threadIdx.x;
    int g = blockIdx.x * 16 + (t >> 4), c = t & 15;
    if (g >= N_NODES) return;
    int o0 = dst_off[g], o1 = dst_off[g + 1];
    float acc = 0.f;
    for (int i = o0; i < o1; ++i) {
        int el = dst_list[i];
        int s = edge_src(ei, el);
        float a = bf2f(eb[(size_t)el * NCLS + c]) * inv2[(size_t)s * NCLS + c];
        acc = fmaf(a, xh2[(size_t)s * NCLS + c], acc);
    }
    agg2[(size_t)g * NCLS + c] = acc;
}

// ---------------- final: o = agg2 + bias2 + alpha*p2; log_softmax ----------------
__global__ __launch_bounds__(256) void final_k(
    const float* __restrict__ agg2, const float* __restrict__ ep,
    const float* __restrict__ pw1, const float* __restrict__ pw2,
    const float* __restrict__ pb2, const float* __restrict__ bias,
    const float* __restrict__ alpha_p, float* __restrict__ out)
{
    __shared__ float s1w[256], s2w[256], sb[16], sbias[16];
    const int t = threadIdx.x;
    s1w[t] = pw1[t];
    s2w[t] = pw2[t];
    if (t < 16) { sb[t] = pb2[t]; sbias[t] = bias[t]; }
    __syncthreads();
    const int v = blockIdx.x * 256 + t;
    if (v >= N_NODES) return;
    float alpha = *alpha_p;
    float e_[16];
    #pragma unroll
    for (int j4 = 0; j4 < 16; j4 += 4) {
        float4 vv = *(const float4*)(ep + (size_t)v * 16 + j4);
        e_[j4] = vv.x; e_[j4 + 1] = vv.y; e_[j4 + 2] = vv.z; e_[j4 + 3] = vv.w;
    }
    float t2[16];
    #pragma unroll
    for (int c = 0; c < 16; ++c) {
        float s = 0.f;
        #pragma unroll
        for (int j = 0; j < 16; ++j) s = fmaf(e_[j], s1w[j * 16 + c], s);
        t2[c] = s > 0.f ? s : 0.2f * s;
    }
    float o[16];
    #pragma unroll
    for (int c4 = 0; c4 < 16; c4 += 4) {
        float4 ag = *(const float4*)(agg2 + (size_t)v * 16 + c4);
        float agv[4] = {ag.x, ag.y, ag.z, ag.w};
        #pragma unroll
        for (int q = 0; q < 4; ++q) {
            int c = c4 + q;
            float p = sb[c];
            #pragma unroll
            for (int j = 0; j < 16; ++j) p = fmaf(t2[j], s2w[j * 16 + c], p);
            p = p > 0.f ? p : 0.01f * p;
            o[c] = agv[q] + sbias[c] + alpha * p;
        }
    }
    float mx = o[0];
    #pragma unroll
    for (int c = 1; c < 16; ++c) mx = fmaxf(mx, o[c]);
    float se = 0.f;
    #pragma unroll
    for (int c = 0; c < 16; ++c) se += expf(o[c] - mx);
    float lse = mx + logf(se);
    #pragma unroll
    for (int c4 = 0; c4 < 16; c4 += 4)
        *(float4*)(out + (size_t)v * 16 + c4) =
            make_float4(o[c4] - lse, o[c4 + 1] - lse, o[c4 + 2] - lse, o[c4 + 3] - lse);
}

extern "C" void kernel_launch(void* const* d_in, const int* in_sizes, int n_in,
                              void* d_out, int out_size, void* d_ws, size_t ws_size,
                              hipStream_t stream) {
    const float* x    = (const float*)d_in[0];
    const int*   ei   = (const int*)d_in[1];
    const float* alpha= (const float*)d_in[2];
    const float* kr   = (const float*)d_in[3];
    const float* ep   = (const float*)d_in[4];
    const float* W1   = (const float*)d_in[5];
    const float* h1w1 = (const float*)d_in[6];
    const float* h1w2 = (const float*)d_in[7];
    const float* h1b2 = (const float*)d_in[8];
    const float* p1w1 = (const float*)d_in[9];
    const float* p1w2 = (const float*)d_in[10];
    const float* p1b2 = (const float*)d_in[11];
    const float* b1   = (const float*)d_in[12];
    const float* W2   = (const float*)d_in[13];
    const float* h2w1 = (const float*)d_in[14];
    const float* h2w2 = (const float*)d_in[15];
    const float* h2b2 = (const float*)d_in[16];
    const float* p2w1 = (const float*)d_in[17];
    const float* p2w2 = (const float*)d_in[18];
    const float* p2b2 = (const float*)d_in[19];
    const float* b2   = (const float*)d_in[20];
    float* out = (float*)d_out;

    // ---- workspace bump allocator (~236 MB) ----
    char* p = (char*)d_ws;
    auto alloc = [&](size_t bytes) { char* r = p; p += (bytes + 255) & ~(size_t)255; return r; };

    char* r0    = alloc((size_t)64 * M_PAD * 16);          // 51.25 MB: xb (row-major bf16 N x 512), then t1p (frag-major)
    u16*  xb    = (u16*)r0;
    u16*  t1p   = (u16*)r0;
    u16*  aggb  = (u16*)alloc((size_t)N_NODES * H1 * 2);   // 51.2 MB bf16
    char* ebr   = alloc((size_t)E_TOT * HID * 2);          // 83.2 MB: eb (E'x64), then hb (Nx512)
    u16*  eb    = (u16*)ebr;
    u16*  hb    = (u16*)ebr;
    u16*  eb2   = (u16*)alloc((size_t)E_TOT * NCLS * 2);   // 20.8 MB (written early by edge_mlps_k)
    char* xpr   = alloc((size_t)16 * M_PAD * 16);          // 12.81 MB: xp (frag-major x), then inv1 (Nx64 f32)
    u16*  xp    = (u16*)xpr;
    float* inv1 = (float*)xpr;
    u16*  W1p   = (u16*)alloc((size_t)16 * H1 * 16);       // 128 KB
    u16*  p1w2p = (u16*)alloc((size_t)64 * H1 * 16);       // 512 KB
    u16*  w1f   = (u16*)alloc(2048 * 2);                   // mlp1 w1 frags [1][4][64][8]
    u16*  w2f   = (u16*)alloc(4096 * 2);                   // mlp1 w2 frags [2][4][64][8]
    u16*  w3f   = (u16*)alloc(512 * 2);                    // mlp2 w1 frags [1][1][64][8]
    u16*  w4f   = (u16*)alloc(512 * 2);                    // mlp2 w2 frags
    int* src_cnt  = (int*)alloc(N_NODES * 4);
    int* dst_cnt  = (int*)alloc(N_NODES * 4);
    int* src_cur  = (int*)alloc(N_NODES * 4);
    int* dst_cur  = (int*)alloc(N_NODES * 4);
    int* partials = (int*)alloc(2 * NBLK * 4);
    int* src_off  = (int*)alloc((N_NODES + 1) * 4);
    int* dst_off  = (int*)alloc((N_NODES + 1) * 4);
    int* src_list = (int*)alloc((size_t)E_TOT * 4);
    int* dst_list = (int*)alloc((size_t)E_TOT * 4);
    float* xh2  = (float*)alloc((size_t)N_NODES * NCLS * 4);
    float* agg2 = (float*)alloc((size_t)N_NODES * NCLS * 4);
    float* inv2 = (float*)alloc((size_t)N_NODES * NCLS * 4);

    const dim3 blk(256);
    const int EB = (E_TOT + 255) / 256;
    const int WB = (N_NODES * 64 + 255) / 256;
    const int GB16 = (N_NODES + 15) / 16;
    const dim3 gmm(512 / 128, M_PAD / 128);                 // (4, 391)
    const int MLPB = (E_TOT / 16 + 3) / 4;                  // 10157 blocks, 4 wave-tiles each

    // ---- CSR build + weight/layout conversion ----
    hipMemsetAsync(src_cnt, 0, (char*)partials - (char*)src_cnt, stream);  // cnts + curs (contiguous allocs)
    count_k<<<EB, blk, 0, stream>>>(ei, src_cnt, dst_cnt);
    scanA_k<<<2 * NBLK, blk, 0, stream>>>(src_cnt, dst_cnt, partials);
    scanB_k<<<1, 512, 0, stream>>>(partials);
    scanC_k<<<2 * NBLK, blk, 0, stream>>>(src_cnt, dst_cnt, partials, src_off, dst_off);
    fill_csr_k<<<EB, blk, 0, stream>>>(ei, src_off, dst_off, src_cur, dst_cur, src_list, dst_list);
    conv_a_k<<<(16 * M_PAD + 255) / 256, blk, 0, stream>>>(x, xp, N_NODES, M_PAD, F_IN);
    conv_b_k<<<(16 * H1 + 255) / 256, blk, 0, stream>>>(W1, W1p, F_IN, H1);
    conv_b_k<<<(64 * H1 + 255) / 256, blk, 0, stream>>>(p1w2, p1w2p, H1, H1);
    conv_wfrag_k<<<8, blk, 0, stream>>>(h1w1, w1f, 16, 32, 64);
    conv_wfrag_k<<<16, blk, 0, stream>>>(h1w2, w2f, 64, 64, 64);
    conv_wfrag_k<<<2, blk, 0, stream>>>(h2w1, w3f, 16, 32, 16);
    conv_wfrag_k<<<2, blk, 0, stream>>>(h2w2, w4f, 16, 32, 16);

    // ---- layer 1 ----
    mfma_gemm_k<0><<<gmm, blk, 0, stream>>>(xp, W1p, xb, N_NODES, M_PAD, H1, F_IN,
                                            nullptr, nullptr, nullptr, nullptr);
    edge_mlps_k<<<MLPB, blk, 0, stream>>>(kr, w1f, w2f, h1b2, w3f, w4f, h2b2, eb, eb2);
    s1sum_k<<<WB, blk, 0, stream>>>(eb, src_off, src_list, inv1);
    msg1_k<<<WB, blk, 0, stream>>>(eb, inv1, xb, ei, dst_off, dst_list, aggb);
    gemm_t1_k<<<dim3(8, (N_NODES + 63) / 64), blk, 0, stream>>>(ep, p1w1, t1p);   // overwrites xb region
    mfma_gemm_k<3><<<gmm, blk, 0, stream>>>(t1p, p1w2p, hb, N_NODES, M_PAD, H1, H1,
                                            p1b2, aggb, b1, alpha);               // hb overwrites eb region

    // ---- layer 2 ----
    gemm_n16_k<<<(N_NODES + 15) / 16, blk, 0, stream>>>(hb, W2, xh2, N_NODES, H1);
    s2sum_k<<<GB16, blk, 0, stream>>>(eb2, src_off, src_list, inv2);
    msg2_k<<<GB16, blk, 0, stream>>>(eb2, inv2, xh2, ei, dst_off, dst_list, agg2);
    final_k<<<(N_NODES + 255) / 256, blk, 0, stream>>>(agg2, ep, p2w1, p2w2, p2b2, b2, alpha, out);
}

// Round 6
// 755.094 us; speedup vs baseline: 1.8519x; 1.0423x over previous
//
#include <hip/hip_runtime.h>
#include <math.h>

#define N_NODES 50000
#define M_PAD   50048    // N_NODES padded to multiple of 128 for MFMA tiles
#define N_EDGES 600000
#define E_TOT   650000   // N_EDGES + N_NODES (self loops appended)
#define F_IN    128
#define HID     64
#define HEADS   8
#define H1      512      // HEADS*HID
#define NCLS    16
#define NC      16
#define NCP     16
#define NBLK    ((N_NODES + 255) / 256)   // 196 scan blocks per array

typedef unsigned short u16;
typedef __attribute__((ext_vector_type(8))) short short8;   // 8 bf16 = 4 VGPRs (MFMA A/B frag)
typedef __attribute__((ext_vector_type(4))) float f32x4;    // MFMA C/D frag

__device__ __forceinline__ float bf2f(u16 h) {
    return __uint_as_float(((unsigned)h) << 16);
}
__device__ __forceinline__ u16 f2bf(float f) {
    unsigned u = __float_as_uint(f);
    u += 0x7fffu + ((u >> 16) & 1u);
    return (u16)(u >> 16);
}
__device__ __forceinline__ int edge_src(const int* __restrict__ ei, int e) {
    return (e < N_EDGES) ? ei[e] : (e - N_EDGES);
}
__device__ __forceinline__ int edge_dst(const int* __restrict__ ei, int e) {
    return (e < N_EDGES) ? ei[N_EDGES + e] : (e - N_EDGES);
}

// ---------------- CSR build ----------------
__global__ __launch_bounds__(256) void count_k(const int* __restrict__ ei,
                                               int* __restrict__ src_cnt, int* __restrict__ dst_cnt) {
    int e = blockIdx.x * 256 + threadIdx.x;
    if (e >= E_TOT) return;
    atomicAdd(&src_cnt[edge_src(ei, e)], 1);
    atomicAdd(&dst_cnt[edge_dst(ei, e)], 1);
}

// Phase A: per-block partial sums. grid = 2*NBLK (src blocks, then dst blocks).
__global__ __launch_bounds__(256) void scanA_k(const int* __restrict__ src_cnt,
                                               const int* __restrict__ dst_cnt,
                                               int* __restrict__ partials) {
    int pass = blockIdx.x >= NBLK;
    int b = blockIdx.x - pass * NBLK;
    const int* cnt = pass ? dst_cnt : src_cnt;
    int idx = b * 256 + threadIdx.x;
    int v = (idx < N_NODES) ? cnt[idx] : 0;
    __shared__ int red[4];
    #pragma unroll
    for (int off = 32; off; off >>= 1) v += __shfl_down(v, off, 64);
    if ((threadIdx.x & 63) == 0) red[threadIdx.x >> 6] = v;
    __syncthreads();
    if (threadIdx.x == 0) partials[blockIdx.x] = red[0] + red[1] + red[2] + red[3];
}

// Phase B: two independent exclusive scans of NBLK partials (src seg, dst seg), one block.
__global__ __launch_bounds__(512) void scanB_k(int* __restrict__ partials) {
    __shared__ int lds[512];
    int t = threadIdx.x;           // 512 threads: t<256 -> src segment, else dst
    int seg = t >> 8, i = t & 255;
    int v = (i < NBLK) ? partials[seg * NBLK + i] : 0;
    lds[t] = v;
    __syncthreads();
    for (int d = 1; d < 256; d <<= 1) {
        int x = (i >= d) ? lds[seg * 256 + i - d] : 0;
        __syncthreads();
        lds[t] += x;
        __syncthreads();
    }
    if (i < NBLK) partials[seg * NBLK + i] = lds[t] - v;   // exclusive
}

// Phase C: block-local exclusive scan + block offset -> off[]; off[N]=E_TOT constant.
__global__ __launch_bounds__(256) void scanC_k(const int* __restrict__ src_cnt,
                                               const int* __restrict__ dst_cnt,
                                               const int* __restrict__ partials,
                                               int* __restrict__ src_off, int* __restrict__ dst_off) {
    int pass = blockIdx.x >= NBLK;
    int b = blockIdx.x - pass * NBLK;
    const int* cnt = pass ? dst_cnt : src_cnt;
    int* off = pass ? dst_off : src_off;
    int base = partials[blockIdx.x];
    __shared__ int lds[256];
    int t = threadIdx.x;
    int idx = b * 256 + t;
    int v = (idx < N_NODES) ? cnt[idx] : 0;
    lds[t] = v;
    __syncthreads();
    for (int d = 1; d < 256; d <<= 1) {
        int x = (t >= d) ? lds[t - d] : 0;
        __syncthreads();
        lds[t] += x;
        __syncthreads();
    }
    if (idx < N_NODES) off[idx] = base + lds[t] - v;
    if (b == 0 && t == 0) off[N_NODES] = E_TOT;
}

// fill: rkd[e] = slot of e in dst-CSR; dsrc[slot] = src node; src_list[src slot] = dst-slot id
__global__ __launch_bounds__(256) void fill_csr_k(const int* __restrict__ ei,
                                                  const int* __restrict__ src_off, const int* __restrict__ dst_off,
                                                  int* __restrict__ src_cur, int* __restrict__ dst_cur,
                                                  int* __restrict__ src_list, int* __restrict__ rkd,
                                                  int* __restrict__ dsrc) {
    int e = blockIdx.x * 256 + threadIdx.x;
    if (e >= E_TOT) return;
    int s = edge_src(ei, e), d = edge_dst(ei, e);
    int pd = atomicAdd(&dst_cur[d], 1);
    int rd = dst_off[d] + pd;
    rkd[e] = rd;
    dsrc[rd] = s;
    int ps = atomicAdd(&src_cur[s], 1);
    src_list[src_off[s] + ps] = rd;
}

// ---------------- layout converters ----------------
// f32 [M][K] row-major -> bf16 fragment-major Ap[K/8][Mp][8]; pad rows zeroed
__global__ __launch_bounds__(256) void conv_a_k(const float* __restrict__ A, u16* __restrict__ Ap,
                                                int M, int Mp, int K) {
    int i = blockIdx.x * 256 + threadIdx.x;
    int total = (K >> 3) * Mp;
    if (i >= total) return;
    int r = i % Mp;
    int kb = i / Mp;
    u16* o = Ap + (size_t)i * 8;
    u16 tmp[8];
    if (r < M) {
        const float* a = A + (size_t)r * K + kb * 8;
        #pragma unroll
        for (int j = 0; j < 8; ++j) tmp[j] = f2bf(a[j]);
    } else {
        #pragma unroll
        for (int j = 0; j < 8; ++j) tmp[j] = 0;
    }
    *(ushort4*)o = *(ushort4*)tmp;
    *(ushort4*)(o + 4) = *(ushort4*)(tmp + 4);
}

// f32 [K][N] row-major -> bf16 fragment-major Bp[K/8][N][8] (Bp[kb][n][j] = B[kb*8+j][n])
__global__ __launch_bounds__(256) void conv_b_k(const float* __restrict__ B, u16* __restrict__ Bp,
                                                int K, int N) {
    int i = blockIdx.x * 256 + threadIdx.x;
    int total = (K >> 3) * N;
    if (i >= total) return;
    int n = i % N;
    int kb = i / N;
    u16 tmp[8];
    #pragma unroll
    for (int j = 0; j < 8; ++j) tmp[j] = f2bf(B[(size_t)(kb * 8 + j) * N + n]);
    u16* o = Bp + (size_t)i * 8;
    *(ushort4*)o = *(ushort4*)tmp;
    *(ushort4*)(o + 4) = *(ushort4*)(tmp + 4);
}

// f32 W[K][N] row-major -> per-lane B-frag table [Kpad/32][N/16][64][8], zero-padded beyond K
__global__ __launch_bounds__(256) void conv_wfrag_k(const float* __restrict__ W, u16* __restrict__ o,
                                                    int K, int Kpad, int N) {
    int i = blockIdx.x * 256 + threadIdx.x;
    int total = (Kpad / 32) * (N / 16) * 64 * 8;
    if (i >= total) return;
    int j = i & 7, lane = (i >> 3) & 63, rest = i >> 9;
    int ntn = N / 16;
    int nt = rest % ntn, ks = rest / ntn;
    int lm = lane & 15, quad = lane >> 4;
    int k = ks * 32 + quad * 8 + j, n = nt * 16 + lm;
    o[i] = (k < K) ? f2bf(W[(size_t)k * N + n]) : (u16)0;
}

// ---------------- MFMA GEMM: C[M][N] = epi(Ap @ Bp), frag-major operands, no LDS ----------------
template<int EPI>
__global__ __launch_bounds__(256) void mfma_gemm_k(
    const u16* __restrict__ Ap, const u16* __restrict__ Bp, u16* __restrict__ C,
    int M, int Mp, int Nn, int K,
    const float* __restrict__ bias, const u16* __restrict__ extra,
    const float* __restrict__ bias2, const float* __restrict__ alpha_p)
{
    const int t = threadIdx.x;
    const int wave = t >> 6, lane = t & 63;
    const int wm = (wave >> 1) * 64, wn = (wave & 1) * 64;
    const int bm = blockIdx.y * 128, bn = blockIdx.x * 128;
    const int lm = lane & 15, quad = lane >> 4;

    size_t rbase[4], cbase[4];
    #pragma unroll
    for (int mi = 0; mi < 4; ++mi) rbase[mi] = (size_t)(bm + wm + mi * 16 + lm) * 8;
    #pragma unroll
    for (int nj = 0; nj < 4; ++nj) cbase[nj] = (size_t)(bn + wn + nj * 16 + lm) * 8;

    f32x4 acc[4][4] = {};

    for (int k0 = 0; k0 < K; k0 += 32) {
        int kb = (k0 >> 3) + quad;
        size_t abase = (size_t)kb * Mp * 8;
        size_t bbase = (size_t)kb * Nn * 8;
        short8 af[4], bf_[4];
        #pragma unroll
        for (int mi = 0; mi < 4; ++mi) af[mi] = *(const short8*)(Ap + abase + rbase[mi]);
        #pragma unroll
        for (int nj = 0; nj < 4; ++nj) bf_[nj] = *(const short8*)(Bp + bbase + cbase[nj]);
        #pragma unroll
        for (int mi = 0; mi < 4; ++mi)
            #pragma unroll
            for (int nj = 0; nj < 4; ++nj)
                acc[mi][nj] = __builtin_amdgcn_mfma_f32_16x16x32_bf16(af[mi], bf_[nj], acc[mi][nj], 0, 0, 0);
    }

    // C/D layout: col = lane&15, row = quad*4 + reg
    const int orow = bm + wm + quad * 4;
    const int ocol = bn + wn + lm;
    if (EPI == 0) {
        #pragma unroll
        for (int mi = 0; mi < 4; ++mi)
            #pragma unroll
            for (int r = 0; r < 4; ++r) {
                int rr = orow + mi * 16 + r;
                if (rr >= M) continue;
                #pragma unroll
                for (int nj = 0; nj < 4; ++nj)
                    C[(size_t)rr * Nn + ocol + nj * 16] = f2bf(acc[mi][nj][r]);
            }
    } else {
        float alpha = *alpha_p;
        #pragma unroll
        for (int mi = 0; mi < 4; ++mi)
            #pragma unroll
            for (int r = 0; r < 4; ++r) {
                int rr = orow + mi * 16 + r;
                if (rr >= M) continue;
                #pragma unroll
                for (int nj = 0; nj < 4; ++nj) {
                    int c = ocol + nj * 16;
                    float v = acc[mi][nj][r] + bias[c];
                    v = v > 0.f ? v : 0.01f * v;
                    float o = bf2f(extra[(size_t)rr * Nn + c]) + bias2[c] + alpha * v;
                    o = fmaxf(o, 0.f);
                    C[(size_t)rr * Nn + c] = f2bf(o);
                }
            }
    }
}

// ---------------- t1 = leaky(ep @ p1w1, 0.2), K=16, written in frag-major Ap layout ----------------
__global__ __launch_bounds__(256) void gemm_t1_k(
    const float* __restrict__ ep, const float* __restrict__ W, u16* __restrict__ t1p)
{
    __shared__ float Bs[16][64];
    const int bm = blockIdx.y * 64, bn = blockIdx.x * 64;
    const int t = threadIdx.x;
    const int tx = t & 15, ty = t >> 4;
    *(float4*)&Bs[t >> 4][(t & 15) * 4] = *(const float4*)&W[(size_t)(t >> 4) * H1 + bn + (t & 15) * 4];
    __syncthreads();
    const int r0 = bm + ty * 4;
    const int c0 = bn + tx * 4;
    for (int i = 0; i < 4; ++i) {
        int r = r0 + i;
        if (r >= N_NODES) continue;
        float av[16];
        #pragma unroll
        for (int j4 = 0; j4 < 16; j4 += 4) {
            float4 v = *(const float4*)(ep + (size_t)r * NCP + j4);
            av[j4] = v.x; av[j4 + 1] = v.y; av[j4 + 2] = v.z; av[j4 + 3] = v.w;
        }
        u16 pk[4];
        #pragma unroll
        for (int q = 0; q < 4; ++q) {
            float s = 0.f;
            #pragma unroll
            for (int k = 0; k < 16; ++k) s = fmaf(av[k], Bs[k][tx * 4 + q], s);
            s = s > 0.f ? s : 0.2f * s;
            pk[q] = f2bf(s);
        }
        u16* o = t1p + ((size_t)(c0 >> 3) * M_PAD + r) * 8 + (c0 & 7);
        *(ushort4*)o = *(ushort4*)pk;
    }
}

// ---------------- N=16 GEMM (xh2 = h @ W_src2), bf16 A, K multiple of 64 ----------------
__global__ __launch_bounds__(256) void gemm_n16_k(
    const u16* __restrict__ A, const float* __restrict__ B, float* __restrict__ C,
    int M, int K)
{
    __shared__ float As[16][64];   // [row][k]
    __shared__ float Bs[64][16];   // [k][col]
    const int row0 = blockIdx.x * 16;
    const int t = threadIdx.x;
    const int r = t >> 4, c = t & 15;
    const int ar = t >> 4, ak4 = (t & 15) * 4;
    const int bk = t >> 2, bc4 = (t & 3) * 4;
    float acc = 0.f;
    for (int k0 = 0; k0 < K; k0 += 64) {
        float4 av = make_float4(0.f, 0.f, 0.f, 0.f);
        if (row0 + ar < M) {
            ushort4 h4 = *(const ushort4*)(A + (size_t)(row0 + ar) * K + k0 + ak4);
            av = make_float4(bf2f(h4.x), bf2f(h4.y), bf2f(h4.z), bf2f(h4.w));
        }
        *(float4*)&As[ar][ak4] = av;
        *(float4*)&Bs[bk][bc4] = *(const float4*)(B + (size_t)(k0 + bk) * 16 + bc4);
        __syncthreads();
        #pragma unroll
        for (int kk = 0; kk < 64; ++kk)
            acc = fmaf(As[r][kk], Bs[kk][c], acc);
        __syncthreads();
    }
    if (row0 + r < M) C[(size_t)(row0 + r) * 16 + c] = acc;
}

// ---------------- fused MFMA edge MLPs -> dst-slot-ordered ebd / ebd2 ----------------
#define TSTR 72   // LDS tile row stride in bf16 elems (144 B: 16B-aligned frag reads, <=2-way banks)
__global__ __launch_bounds__(256) void edge_mlps_k(
    const float* __restrict__ kr, const int* __restrict__ rkd,
    const u16* __restrict__ w1f, const u16* __restrict__ w2f, const float* __restrict__ b2a,
    const u16* __restrict__ w3f, const u16* __restrict__ w4f, const float* __restrict__ b2b,
    u16* __restrict__ ebd, u16* __restrict__ ebd2)
{
    __shared__ __align__(16) u16 T[4][16 * TSTR];
    const int t = threadIdx.x, wv = t >> 6, lane = t & 63;
    const int lm = lane & 15, quad = lane >> 4;
    const int tile = blockIdx.x * 4 + wv;
    const int e0 = tile * 16;
    if (e0 >= E_TOT) return;
    u16* Tw = T[wv];

    // weight fragments -> VGPRs (per-lane)
    short8 W1[4], W2[2][4];
    #pragma unroll
    for (int nt = 0; nt < 4; ++nt) W1[nt] = *(const short8*)(w1f + ((size_t)nt * 64 + lane) * 8);
    #pragma unroll
    for (int ks = 0; ks < 2; ++ks)
        #pragma unroll
        for (int nt = 0; nt < 4; ++nt)
            W2[ks][nt] = *(const short8*)(w2f + (((size_t)ks * 4 + nt) * 64 + lane) * 8);
    short8 W3 = *(const short8*)(w3f + (size_t)lane * 8);
    short8 W4 = *(const short8*)(w4f + (size_t)lane * 8);
    float b2av[4];
    #pragma unroll
    for (int nt = 0; nt < 4; ++nt) b2av[nt] = b2a[nt * 16 + lm];
    float b2bv = b2b[lm];

    // A-frag from kr: edge m = e0+lm, k = quad*8+j (K=16 zero-padded to 32)
    short8 af = {};
    if (quad < 2) {
        const float* kp = kr + (size_t)(e0 + lm) * NC + quad * 8;
        float4 v0 = *(const float4*)kp;
        float4 v1 = *(const float4*)(kp + 4);
        u16 tmp[8] = {f2bf(v0.x), f2bf(v0.y), f2bf(v0.z), f2bf(v0.w),
                      f2bf(v1.x), f2bf(v1.y), f2bf(v1.z), f2bf(v1.w)};
        af = *(const short8*)tmp;
    }

    // ---- MLP1 layer 1: [16 edges x 64] = kr @ w1, leaky 0.2 ----
    f32x4 a1[4] = {};
    #pragma unroll
    for (int nt = 0; nt < 4; ++nt)
        a1[nt] = __builtin_amdgcn_mfma_f32_16x16x32_bf16(af, W1[nt], a1[nt], 0, 0, 0);
    #pragma unroll
    for (int nt = 0; nt < 4; ++nt)
        #pragma unroll
        for (int r = 0; r < 4; ++r) {
            float v = a1[nt][r];
            v = v > 0.f ? v : 0.2f * v;
            Tw[(quad * 4 + r) * TSTR + nt * 16 + lm] = f2bf(v);
        }
    __builtin_amdgcn_s_waitcnt(0);   // drain LDS writes before same-wave reads

    // ---- MLP1 layer 2: K=64 from LDS tile ----
    short8 a2[2];
    #pragma unroll
    for (int ks = 0; ks < 2; ++ks)
        a2[ks] = *(const short8*)&Tw[lm * TSTR + ks * 32 + quad * 8];
    f32x4 c2[4] = {};
    #pragma unroll
    for (int nt = 0; nt < 4; ++nt)
        #pragma unroll
        for (int ks = 0; ks < 2; ++ks)
            c2[nt] = __builtin_amdgcn_mfma_f32_16x16x32_bf16(a2[ks], W2[ks][nt], c2[nt], 0, 0, 0);
    // epilogue: + b2, exp -> LDS
    #pragma unroll
    for (int nt = 0; nt < 4; ++nt)
        #pragma unroll
        for (int r = 0; r < 4; ++r)
            Tw[(quad * 4 + r) * TSTR + nt * 16 + lm] = f2bf(__expf(c2[nt][r] + b2av[nt]));
    __builtin_amdgcn_s_waitcnt(0);
    // repack: 16B row-chunks scattered to dst-slot rows (8 lanes per 128B row)
    #pragma unroll
    for (int p = 0; p < 2; ++p) {
        int c = p * 64 + lane;
        int row = c >> 3, off = (c & 7) * 8;
        int rd = rkd[e0 + row];
        short8 v = *(const short8*)&Tw[row * TSTR + off];
        *(short8*)(ebd + (size_t)rd * HID + off) = v;
    }

    // ---- MLP2 (16->16->16), reuses kr A-frag ----
    f32x4 b1 = __builtin_amdgcn_mfma_f32_16x16x32_bf16(af, W3, (f32x4){}, 0, 0, 0);
    __builtin_amdgcn_s_waitcnt(0);   // eb repack reads done before overwrite
    #pragma unroll
    for (int r = 0; r < 4; ++r) {
        float v = b1[r];
        v = v > 0.f ? v : 0.2f * v;
        Tw[(quad * 4 + r) * TSTR + lm] = f2bf(v);
    }
    __builtin_amdgcn_s_waitcnt(0);
    // A-frag: cols 16..31 hold stale finite values, but W4 is zero there -> no effect
    short8 a3 = *(const short8*)&Tw[lm * TSTR + quad * 8];
    f32x4 c3 = __builtin_amdgcn_mfma_f32_16x16x32_bf16(a3, W4, (f32x4){}, 0, 0, 0);
    #pragma unroll
    for (int r = 0; r < 4; ++r)
        Tw[(quad * 4 + r) * TSTR + lm] = f2bf(__expf(c3[r] + b2bv));
    __builtin_amdgcn_s_waitcnt(0);
    if (lane < 32) {
        int row = lane >> 1, off = (lane & 1) * 8;
        int rd = rkd[e0 + row];
        short8 v = *(const short8*)&Tw[row * TSTR + off];
        *(short8*)(ebd2 + (size_t)rd * NCLS + off) = v;
    }
}

// ---------------- inverse softmax denominator, layer 1 (wave per src), bf16 out ----------------
__global__ __launch_bounds__(256) void s1sum_k(
    const u16* __restrict__ ebd, const int* __restrict__ src_off, const int* __restrict__ src_list,
    u16* __restrict__ inv1b)
{
    int gid = blockIdx.x * 256 + threadIdx.x;
    int wid = gid >> 6, lane = gid & 63;
    if (wid >= N_NODES) return;
    int o0 = src_off[wid], o1 = src_off[wid + 1];
    float sum = 0.f;
    for (int i = o0; i < o1; ++i) {
        int sl = src_list[i];
        sum += bf2f(ebd[(size_t)sl * HID + lane]);
    }
    inv1b[(size_t)wid * HID + lane] = f2bf(1.f / (sum + 1e-16f));
}

// ---------------- message pass 1: wave per dst, sequential slots, 16B/lane loads ----------------
__global__ __launch_bounds__(256) void msg1_k(
    const u16* __restrict__ ebd, const u16* __restrict__ inv1b,
    const u16* __restrict__ xb, const int* __restrict__ dsrc,
    const int* __restrict__ dst_off, u16* __restrict__ aggb)
{
    int gid = blockIdx.x * 256 + threadIdx.x;
    int wid = gid >> 6, lane = gid & 63;
    if (wid >= N_NODES) return;
    int o0 = dst_off[wid], o1 = dst_off[wid + 1];
    const int a_off = (lane & 7) * 8;     // alpha channel block (ch = lane*8+j mod 64)
    float acc[8] = {};
    for (int i = o0; i < o1; ++i) {
        int s = dsrc[i];
        short8 a8 = *(const short8*)(ebd + (size_t)i * HID + a_off);
        short8 v8 = *(const short8*)(inv1b + (size_t)s * HID + a_off);
        short8 x8 = *(const short8*)(xb + (size_t)s * H1 + lane * 8);
        #pragma unroll
        for (int j = 0; j < 8; ++j) {
            float a = bf2f(((u16)a8[j])) * bf2f(((u16)v8[j]));
            acc[j] = fmaf(a, bf2f(((u16)x8[j])), acc[j]);
        }
    }
    u16 pk[8];
    #pragma unroll
    for (int j = 0; j < 8; ++j) pk[j] = f2bf(acc[j]);
    *(short8*)(aggb + (size_t)wid * H1 + lane * 8) = *(const short8*)pk;
}

// ---------------- inverse denominator, layer 2 (16 threads per src) ----------------
__global__ __launch_bounds__(256) void s2sum_k(
    const u16* __restrict__ ebd2, const int* __restrict__ src_off, const int* __restrict__ src_list,
    float* __restrict__ inv2)
{
    int t = threadIdx.x;
    int g = blockIdx.x * 16 + (t >> 4), c = t & 15;
    if (g >= N_NODES) return;
    int o0 = src_off[g], o1 = src_off[g + 1];
    float sum = 0.f;
    for (int i = o0; i < o1; ++i) {
        int sl = src_list[i];
        sum += bf2f(ebd2[(size_t)sl * NCLS + c]);
    }
    inv2[(size_t)g * NCLS + c] = 1.f / (sum + 1e-16f);
}

// ---------------- message pass 2 (16 threads per dst), sequential slots ----------------
__global__ __launch_bounds__(256) void msg2_k(
    const u16* __restrict__ ebd2, const float* __restrict__ inv2,
    const float* __restrict__ xh2, const int* __restrict__ dsrc,
    const int* __restrict__ dst_off, float* __restrict__ agg2)
{
    int t = threadIdx.x;
    int g = blockIdx.x * 16 + (t >> 4), c = t & 15;
    if (g >= N_NODES) return;
    int o0 = dst_off[g], o1 = dst_off[g + 1];
    float acc = 0.f;
    for (int i = o0; i < o1; ++i) {
        int s = dsrc[i];
        float a = bf2f(ebd2[(size_t)i * NCLS + c]) * inv2[(size_t)s * NCLS + c];
        acc = fmaf(a, xh2[(size_t)s * NCLS + c], acc);
    }
    agg2[(size_t)g * NCLS + c] = acc;
}

// ---------------- final: o = agg2 + bias2 + alpha*p2; log_softmax ----------------
__global__ __launch_bounds__(256) void final_k(
    const float* __restrict__ agg2, const float* __restrict__ ep,
    const float* __restrict__ pw1, const float* __restrict__ pw2,
    const float* __restrict__ pb2, const float* __restrict__ bias,
    const float* __restrict__ alpha_p, float* __restrict__ out)
{
    __shared__ float s1w[256], s2w[256], sb[16], sbias[16];
    const int t = threadIdx.x;
    s1w[t] = pw1[t];
    s2w[t] = pw2[t];
    if (t < 16) { sb[t] = pb2[t]; sbias[t] = bias[t]; }
    __syncthreads();
    const int v = blockIdx.x * 256 + t;
    if (v >= N_NODES) return;
    float alpha = *alpha_p;
    float e_[16];
    #pragma unroll
    for (int j4 = 0; j4 < 16; j4 += 4) {
        float4 vv = *(const float4*)(ep + (size_t)v * 16 + j4);
        e_[j4] = vv.x; e_[j4 + 1] = vv.y; e_[j4 + 2] = vv.z; e_[j4 + 3] = vv.w;
    }
    float t2[16];
    #pragma unroll
    for (int c = 0; c < 16; ++c) {
        float s = 0.f;
        #pragma unroll
        for (int j = 0; j < 16; ++j) s = fmaf(e_[j], s1w[j * 16 + c], s);
        t2[c] = s > 0.f ? s : 0.2f * s;
    }
    float o[16];
    #pragma unroll
    for (int c4 = 0; c4 < 16; c4 += 4) {
        float4 ag = *(const float4*)(agg2 + (size_t)v * 16 + c4);
        float agv[4] = {ag.x, ag.y, ag.z, ag.w};
        #pragma unroll
        for (int q = 0; q < 4; ++q) {
            int c = c4 + q;
            float p = sb[c];
            #pragma unroll
            for (int j = 0; j < 16; ++j) p = fmaf(t2[j], s2w[j * 16 + c], p);
            p = p > 0.f ? p : 0.01f * p;
            o[c] = agv[q] + sbias[c] + alpha * p;
        }
    }
    float mx = o[0];
    #pragma unroll
    for (int c = 1; c < 16; ++c) mx = fmaxf(mx, o[c]);
    float se = 0.f;
    #pragma unroll
    for (int c = 0; c < 16; ++c) se += expf(o[c] - mx);
    float lse = mx + logf(se);
    #pragma unroll
    for (int c4 = 0; c4 < 16; c4 += 4)
        *(float4*)(out + (size_t)v * 16 + c4) =
            make_float4(o[c4] - lse, o[c4 + 1] - lse, o[c4 + 2] - lse, o[c4 + 3] - lse);
}

extern "C" void kernel_launch(void* const* d_in, const int* in_sizes, int n_in,
                              void* d_out, int out_size, void* d_ws, size_t ws_size,
                              hipStream_t stream) {
    const float* x    = (const float*)d_in[0];
    const int*   ei   = (const int*)d_in[1];
    const float* alpha= (const float*)d_in[2];
    const float* kr   = (const float*)d_in[3];
    const float* ep   = (const float*)d_in[4];
    const float* W1   = (const float*)d_in[5];
    const float* h1w1 = (const float*)d_in[6];
    const float* h1w2 = (const float*)d_in[7];
    const float* h1b2 = (const float*)d_in[8];
    const float* p1w1 = (const float*)d_in[9];
    const float* p1w2 = (const float*)d_in[10];
    const float* p1b2 = (const float*)d_in[11];
    const float* b1   = (const float*)d_in[12];
    const float* W2   = (const float*)d_in[13];
    const float* h2w1 = (const float*)d_in[14];
    const float* h2w2 = (const float*)d_in[15];
    const float* h2b2 = (const float*)d_in[16];
    const float* p2w1 = (const float*)d_in[17];
    const float* p2w2 = (const float*)d_in[18];
    const float* p2b2 = (const float*)d_in[19];
    const float* b2   = (const float*)d_in[20];
    float* out = (float*)d_out;

    // ---- workspace bump allocator (~242 MB) ----
    char* p = (char*)d_ws;
    auto alloc = [&](size_t bytes) { char* r = p; p += (bytes + 255) & ~(size_t)255; return r; };

    char* r0    = alloc((size_t)64 * M_PAD * 16);          // 51.25 MB: xb (row-major bf16 N x 512), then t1p (frag-major)
    u16*  xb    = (u16*)r0;
    u16*  t1p   = (u16*)r0;
    u16*  aggb  = (u16*)alloc((size_t)N_NODES * H1 * 2);   // 51.2 MB bf16
    char* ebr   = alloc((size_t)E_TOT * HID * 2);          // 83.2 MB: ebd (dst-ordered), then hb (Nx512)
    u16*  ebd   = (u16*)ebr;
    u16*  hb    = (u16*)ebr;
    u16*  ebd2  = (u16*)alloc((size_t)E_TOT * NCLS * 2);   // 20.8 MB
    char* xpr   = alloc((size_t)16 * M_PAD * 16);          // 12.81 MB: xp (frag-major x), then inv1b (Nx64 bf16)
    u16*  xp    = (u16*)xpr;
    u16*  inv1b = (u16*)xpr;
    u16*  W1p   = (u16*)alloc((size_t)16 * H1 * 16);       // 128 KB
    u16*  p1w2p = (u16*)alloc((size_t)64 * H1 * 16);       // 512 KB
    u16*  w1f   = (u16*)alloc(2048 * 2);                   // mlp1 w1 frags
    u16*  w2f   = (u16*)alloc(4096 * 2);                   // mlp1 w2 frags
    u16*  w3f   = (u16*)alloc(512 * 2);                    // mlp2 w1 frags
    u16*  w4f   = (u16*)alloc(512 * 2);                    // mlp2 w2 frags
    int* src_cnt  = (int*)alloc(N_NODES * 4);
    int* dst_cnt  = (int*)alloc(N_NODES * 4);
    int* src_cur  = (int*)alloc(N_NODES * 4);
    int* dst_cur  = (int*)alloc(N_NODES * 4);
    int* partials = (int*)alloc(2 * NBLK * 4);
    int* src_off  = (int*)alloc((N_NODES + 1) * 4);
    int* dst_off  = (int*)alloc((N_NODES + 1) * 4);
    int* src_list = (int*)alloc((size_t)E_TOT * 4);        // dst-slot ids grouped by src
    int* rkd      = (int*)alloc((size_t)E_TOT * 4);        // e -> dst slot
    int* dsrc     = (int*)alloc((size_t)E_TOT * 4);        // dst slot -> src node
    float* xh2  = (float*)alloc((size_t)N_NODES * NCLS * 4);
    float* agg2 = (float*)alloc((size_t)N_NODES * NCLS * 4);
    float* inv2 = (float*)alloc((size_t)N_NODES * NCLS * 4);

    const dim3 blk(256);
    const int EB = (E_TOT + 255) / 256;
    const int WB = (N_NODES * 64 + 255) / 256;
    const int GB16 = (N_NODES + 15) / 16;
    const dim3 gmm(512 / 128, M_PAD / 128);                 // (4, 391)
    const int MLPB = (E_TOT / 16 + 3) / 4;

    // ---- CSR build + weight/layout conversion ----
    hipMemsetAsync(src_cnt, 0, (char*)partials - (char*)src_cnt, stream);
    count_k<<<EB, blk, 0, stream>>>(ei, src_cnt, dst_cnt);
    scanA_k<<<2 * NBLK, blk, 0, stream>>>(src_cnt, dst_cnt, partials);
    scanB_k<<<1, 512, 0, stream>>>(partials);
    scanC_k<<<2 * NBLK, blk, 0, stream>>>(src_cnt, dst_cnt, partials, src_off, dst_off);
    fill_csr_k<<<EB, blk, 0, stream>>>(ei, src_off, dst_off, src_cur, dst_cur, src_list, rkd, dsrc);
    conv_a_k<<<(16 * M_PAD + 255) / 256, blk, 0, stream>>>(x, xp, N_NODES, M_PAD, F_IN);
    conv_b_k<<<(16 * H1 + 255) / 256, blk, 0, stream>>>(W1, W1p, F_IN, H1);
    conv_b_k<<<(64 * H1 + 255) / 256, blk, 0, stream>>>(p1w2, p1w2p, H1, H1);
    conv_wfrag_k<<<8, blk, 0, stream>>>(h1w1, w1f, 16, 32, 64);
    conv_wfrag_k<<<16, blk, 0, stream>>>(h1w2, w2f, 64, 64, 64);
    conv_wfrag_k<<<2, blk, 0, stream>>>(h2w1, w3f, 16, 32, 16);
    conv_wfrag_k<<<2, blk, 0, stream>>>(h2w2, w4f, 16, 32, 16);

    // ---- layer 1 ----
    mfma_gemm_k<0><<<gmm, blk, 0, stream>>>(xp, W1p, xb, N_NODES, M_PAD, H1, F_IN,
                                            nullptr, nullptr, nullptr, nullptr);
    edge_mlps_k<<<MLPB, blk, 0, stream>>>(kr, rkd, w1f, w2f, h1b2, w3f, w4f, h2b2, ebd, ebd2);
    s1sum_k<<<WB, blk, 0, stream>>>(ebd, src_off, src_list, inv1b);
    msg1_k<<<WB, blk, 0, stream>>>(ebd, inv1b, xb, dsrc, dst_off, aggb);
    gemm_t1_k<<<dim3(8, (N_NODES + 63) / 64), blk, 0, stream>>>(ep, p1w1, t1p);   // overwrites xb region
    mfma_gemm_k<3><<<gmm, blk, 0, stream>>>(t1p, p1w2p, hb, N_NODES, M_PAD, H1, H1,
                                            p1b2, aggb, b1, alpha);               // hb overwrites ebd region

    // ---- layer 2 ----
    gemm_n16_k<<<(N_NODES + 15) / 16, blk, 0, stream>>>(hb, W2, xh2, N_NODES, H1);
    s2sum_k<<<GB16, blk, 0, stream>>>(ebd2, src_off, src_list, inv2);
    msg2_k<<<GB16, blk, 0, stream>>>(ebd2, inv2, xh2, dsrc, dst_off, agg2);
    final_k<<<(N_NODES + 255) / 256, blk, 0, stream>>>(agg2, ep, p2w1, p2w2, p2b2, b2, alpha, out);
}

// Round 7
// 733.933 us; speedup vs baseline: 1.9053x; 1.0288x over previous
//
#include <hip/hip_runtime.h>
#include <math.h>

#define N_NODES 50000
#define M_PAD   50048    // N_NODES padded to multiple of 128 for MFMA tiles
#define N_EDGES 600000
#define E_TOT   650000   // N_EDGES + N_NODES (self loops appended)
#define F_IN    128
#define HID     64
#define HEADS   8
#define H1      512      // HEADS*HID
#define NCLS    16
#define NC      16
#define NCP     16
#define NBLK    ((N_NODES + 255) / 256)   // 196 scan blocks per array

typedef unsigned short u16;
typedef __attribute__((ext_vector_type(8))) short short8;   // 8 bf16 = 4 VGPRs (MFMA A/B frag)
typedef __attribute__((ext_vector_type(4))) float f32x4;    // MFMA C/D frag

__device__ __forceinline__ float bf2f(u16 h) {
    return __uint_as_float(((unsigned)h) << 16);
}
__device__ __forceinline__ u16 f2bf(float f) {
    unsigned u = __float_as_uint(f);
    u += 0x7fffu + ((u >> 16) & 1u);
    return (u16)(u >> 16);
}
__device__ __forceinline__ int edge_src(const int* __restrict__ ei, int e) {
    return (e < N_EDGES) ? ei[e] : (e - N_EDGES);
}
__device__ __forceinline__ int edge_dst(const int* __restrict__ ei, int e) {
    return (e < N_EDGES) ? ei[N_EDGES + e] : (e - N_EDGES);
}

// ---------------- CSR build ----------------
__global__ __launch_bounds__(256) void count_k(const int* __restrict__ ei,
                                               int* __restrict__ src_cnt, int* __restrict__ dst_cnt) {
    int e = blockIdx.x * 256 + threadIdx.x;
    if (e >= E_TOT) return;
    atomicAdd(&src_cnt[edge_src(ei, e)], 1);
    atomicAdd(&dst_cnt[edge_dst(ei, e)], 1);
}

// Phase A: per-block partial sums. grid = 2*NBLK (src blocks, then dst blocks).
__global__ __launch_bounds__(256) void scanA_k(const int* __restrict__ src_cnt,
                                               const int* __restrict__ dst_cnt,
                                               int* __restrict__ partials) {
    int pass = blockIdx.x >= NBLK;
    int b = blockIdx.x - pass * NBLK;
    const int* cnt = pass ? dst_cnt : src_cnt;
    int idx = b * 256 + threadIdx.x;
    int v = (idx < N_NODES) ? cnt[idx] : 0;
    __shared__ int red[4];
    #pragma unroll
    for (int off = 32; off; off >>= 1) v += __shfl_down(v, off, 64);
    if ((threadIdx.x & 63) == 0) red[threadIdx.x >> 6] = v;
    __syncthreads();
    if (threadIdx.x == 0) partials[blockIdx.x] = red[0] + red[1] + red[2] + red[3];
}

// Phase B: two independent exclusive scans of NBLK partials (src seg, dst seg), one block.
__global__ __launch_bounds__(512) void scanB_k(int* __restrict__ partials) {
    __shared__ int lds[512];
    int t = threadIdx.x;           // 512 threads: t<256 -> src segment, else dst
    int seg = t >> 8, i = t & 255;
    int v = (i < NBLK) ? partials[seg * NBLK + i] : 0;
    lds[t] = v;
    __syncthreads();
    for (int d = 1; d < 256; d <<= 1) {
        int x = (i >= d) ? lds[seg * 256 + i - d] : 0;
        __syncthreads();
        lds[t] += x;
        __syncthreads();
    }
    if (i < NBLK) partials[seg * NBLK + i] = lds[t] - v;   // exclusive
}

// Phase C: block-local exclusive scan + block offset -> off[]; off[N]=E_TOT constant.
__global__ __launch_bounds__(256) void scanC_k(const int* __restrict__ src_cnt,
                                               const int* __restrict__ dst_cnt,
                                               const int* __restrict__ partials,
                                               int* __restrict__ src_off, int* __restrict__ dst_off) {
    int pass = blockIdx.x >= NBLK;
    int b = blockIdx.x - pass * NBLK;
    const int* cnt = pass ? dst_cnt : src_cnt;
    int* off = pass ? dst_off : src_off;
    int base = partials[blockIdx.x];
    __shared__ int lds[256];
    int t = threadIdx.x;
    int idx = b * 256 + t;
    int v = (idx < N_NODES) ? cnt[idx] : 0;
    lds[t] = v;
    __syncthreads();
    for (int d = 1; d < 256; d <<= 1) {
        int x = (t >= d) ? lds[t - d] : 0;
        __syncthreads();
        lds[t] += x;
        __syncthreads();
    }
    if (idx < N_NODES) off[idx] = base + lds[t] - v;
    if (b == 0 && t == 0) off[N_NODES] = E_TOT;
}

// fill: rkd[e] = slot of e in dst-CSR; dsrc[slot] = src node; src_list[src slot] = dst-slot id
__global__ __launch_bounds__(256) void fill_csr_k(const int* __restrict__ ei,
                                                  const int* __restrict__ src_off, const int* __restrict__ dst_off,
                                                  int* __restrict__ src_cur, int* __restrict__ dst_cur,
                                                  int* __restrict__ src_list, int* __restrict__ rkd,
                                                  int* __restrict__ dsrc) {
    int e = blockIdx.x * 256 + threadIdx.x;
    if (e >= E_TOT) return;
    int s = edge_src(ei, e), d = edge_dst(ei, e);
    int pd = atomicAdd(&dst_cur[d], 1);
    int rd = dst_off[d] + pd;
    rkd[e] = rd;
    dsrc[rd] = s;
    int ps = atomicAdd(&src_cur[s], 1);
    src_list[src_off[s] + ps] = rd;
}

// ---------------- layout converters ----------------
// f32 [M][K] row-major -> bf16 fragment-major Ap[K/8][Mp][8]; pad rows zeroed
__global__ __launch_bounds__(256) void conv_a_k(const float* __restrict__ A, u16* __restrict__ Ap,
                                                int M, int Mp, int K) {
    int i = blockIdx.x * 256 + threadIdx.x;
    int total = (K >> 3) * Mp;
    if (i >= total) return;
    int r = i % Mp;
    int kb = i / Mp;
    u16* o = Ap + (size_t)i * 8;
    u16 tmp[8];
    if (r < M) {
        const float* a = A + (size_t)r * K + kb * 8;
        #pragma unroll
        for (int j = 0; j < 8; ++j) tmp[j] = f2bf(a[j]);
    } else {
        #pragma unroll
        for (int j = 0; j < 8; ++j) tmp[j] = 0;
    }
    *(ushort4*)o = *(ushort4*)tmp;
    *(ushort4*)(o + 4) = *(ushort4*)(tmp + 4);
}

// f32 [K][N] row-major -> bf16 fragment-major Bp[K/8][N][8] (Bp[kb][n][j] = B[kb*8+j][n])
__global__ __launch_bounds__(256) void conv_b_k(const float* __restrict__ B, u16* __restrict__ Bp,
                                                int K, int N) {
    int i = blockIdx.x * 256 + threadIdx.x;
    int total = (K >> 3) * N;
    if (i >= total) return;
    int n = i % N;
    int kb = i / N;
    u16 tmp[8];
    #pragma unroll
    for (int j = 0; j < 8; ++j) tmp[j] = f2bf(B[(size_t)(kb * 8 + j) * N + n]);
    u16* o = Bp + (size_t)i * 8;
    *(ushort4*)o = *(ushort4*)tmp;
    *(ushort4*)(o + 4) = *(ushort4*)(tmp + 4);
}

// f32 W[K][N] row-major -> per-lane B-frag table [Kpad/32][N/16][64][8], zero-padded beyond K
__global__ __launch_bounds__(256) void conv_wfrag_k(const float* __restrict__ W, u16* __restrict__ o,
                                                    int K, int Kpad, int N) {
    int i = blockIdx.x * 256 + threadIdx.x;
    int total = (Kpad / 32) * (N / 16) * 64 * 8;
    if (i >= total) return;
    int j = i & 7, lane = (i >> 3) & 63, rest = i >> 9;
    int ntn = N / 16;
    int nt = rest % ntn, ks = rest / ntn;
    int lm = lane & 15, quad = lane >> 4;
    int k = ks * 32 + quad * 8 + j, n = nt * 16 + lm;
    o[i] = (k < K) ? f2bf(W[(size_t)k * N + n]) : (u16)0;
}

// ---------------- MFMA GEMM: C[M][N] = epi(Ap @ Bp), frag-major operands, no LDS ----------------
template<int EPI>
__global__ __launch_bounds__(256) void mfma_gemm_k(
    const u16* __restrict__ Ap, const u16* __restrict__ Bp, u16* __restrict__ C,
    int M, int Mp, int Nn, int K,
    const float* __restrict__ bias, const u16* __restrict__ extra,
    const float* __restrict__ bias2, const float* __restrict__ alpha_p)
{
    const int t = threadIdx.x;
    const int wave = t >> 6, lane = t & 63;
    const int wm = (wave >> 1) * 64, wn = (wave & 1) * 64;
    const int bm = blockIdx.y * 128, bn = blockIdx.x * 128;
    const int lm = lane & 15, quad = lane >> 4;

    size_t rbase[4], cbase[4];
    #pragma unroll
    for (int mi = 0; mi < 4; ++mi) rbase[mi] = (size_t)(bm + wm + mi * 16 + lm) * 8;
    #pragma unroll
    for (int nj = 0; nj < 4; ++nj) cbase[nj] = (size_t)(bn + wn + nj * 16 + lm) * 8;

    f32x4 acc[4][4] = {};

    for (int k0 = 0; k0 < K; k0 += 32) {
        int kb = (k0 >> 3) + quad;
        size_t abase = (size_t)kb * Mp * 8;
        size_t bbase = (size_t)kb * Nn * 8;
        short8 af[4], bf_[4];
        #pragma unroll
        for (int mi = 0; mi < 4; ++mi) af[mi] = *(const short8*)(Ap + abase + rbase[mi]);
        #pragma unroll
        for (int nj = 0; nj < 4; ++nj) bf_[nj] = *(const short8*)(Bp + bbase + cbase[nj]);
        #pragma unroll
        for (int mi = 0; mi < 4; ++mi)
            #pragma unroll
            for (int nj = 0; nj < 4; ++nj)
                acc[mi][nj] = __builtin_amdgcn_mfma_f32_16x16x32_bf16(af[mi], bf_[nj], acc[mi][nj], 0, 0, 0);
    }

    // C/D layout: col = lane&15, row = quad*4 + reg
    const int orow = bm + wm + quad * 4;
    const int ocol = bn + wn + lm;
    if (EPI == 0) {
        #pragma unroll
        for (int mi = 0; mi < 4; ++mi)
            #pragma unroll
            for (int r = 0; r < 4; ++r) {
                int rr = orow + mi * 16 + r;
                if (rr >= M) continue;
                #pragma unroll
                for (int nj = 0; nj < 4; ++nj)
                    C[(size_t)rr * Nn + ocol + nj * 16] = f2bf(acc[mi][nj][r]);
            }
    } else {
        float alpha = *alpha_p;
        #pragma unroll
        for (int mi = 0; mi < 4; ++mi)
            #pragma unroll
            for (int r = 0; r < 4; ++r) {
                int rr = orow + mi * 16 + r;
                if (rr >= M) continue;
                #pragma unroll
                for (int nj = 0; nj < 4; ++nj) {
                    int c = ocol + nj * 16;
                    float v = acc[mi][nj][r] + bias[c];
                    v = v > 0.f ? v : 0.01f * v;
                    float o = bf2f(extra[(size_t)rr * Nn + c]) + bias2[c] + alpha * v;
                    o = fmaxf(o, 0.f);
                    C[(size_t)rr * Nn + c] = f2bf(o);
                }
            }
    }
}

// ---------------- t1 = leaky(ep @ p1w1, 0.2), K=16, written in frag-major Ap layout ----------------
__global__ __launch_bounds__(256) void gemm_t1_k(
    const float* __restrict__ ep, const float* __restrict__ W, u16* __restrict__ t1p)
{
    __shared__ float Bs[16][64];
    const int bm = blockIdx.y * 64, bn = blockIdx.x * 64;
    const int t = threadIdx.x;
    const int tx = t & 15, ty = t >> 4;
    *(float4*)&Bs[t >> 4][(t & 15) * 4] = *(const float4*)&W[(size_t)(t >> 4) * H1 + bn + (t & 15) * 4];
    __syncthreads();
    const int r0 = bm + ty * 4;
    const int c0 = bn + tx * 4;
    for (int i = 0; i < 4; ++i) {
        int r = r0 + i;
        if (r >= N_NODES) continue;
        float av[16];
        #pragma unroll
        for (int j4 = 0; j4 < 16; j4 += 4) {
            float4 v = *(const float4*)(ep + (size_t)r * NCP + j4);
            av[j4] = v.x; av[j4 + 1] = v.y; av[j4 + 2] = v.z; av[j4 + 3] = v.w;
        }
        u16 pk[4];
        #pragma unroll
        for (int q = 0; q < 4; ++q) {
            float s = 0.f;
            #pragma unroll
            for (int k = 0; k < 16; ++k) s = fmaf(av[k], Bs[k][tx * 4 + q], s);
            s = s > 0.f ? s : 0.2f * s;
            pk[q] = f2bf(s);
        }
        u16* o = t1p + ((size_t)(c0 >> 3) * M_PAD + r) * 8 + (c0 & 7);
        *(ushort4*)o = *(ushort4*)pk;
    }
}

// ---------------- N=16 GEMM (xh2 = h @ W_src2), bf16 A, K multiple of 64 ----------------
__global__ __launch_bounds__(256) void gemm_n16_k(
    const u16* __restrict__ A, const float* __restrict__ B, float* __restrict__ C,
    int M, int K)
{
    __shared__ float As[16][64];   // [row][k]
    __shared__ float Bs[64][16];   // [k][col]
    const int row0 = blockIdx.x * 16;
    const int t = threadIdx.x;
    const int r = t >> 4, c = t & 15;
    const int ar = t >> 4, ak4 = (t & 15) * 4;
    const int bk = t >> 2, bc4 = (t & 3) * 4;
    float acc = 0.f;
    for (int k0 = 0; k0 < K; k0 += 64) {
        float4 av = make_float4(0.f, 0.f, 0.f, 0.f);
        if (row0 + ar < M) {
            ushort4 h4 = *(const ushort4*)(A + (size_t)(row0 + ar) * K + k0 + ak4);
            av = make_float4(bf2f(h4.x), bf2f(h4.y), bf2f(h4.z), bf2f(h4.w));
        }
        *(float4*)&As[ar][ak4] = av;
        *(float4*)&Bs[bk][bc4] = *(const float4*)(B + (size_t)(k0 + bk) * 16 + bc4);
        __syncthreads();
        #pragma unroll
        for (int kk = 0; kk < 64; ++kk)
            acc = fmaf(As[r][kk], Bs[kk][c], acc);
        __syncthreads();
    }
    if (row0 + r < M) C[(size_t)(row0 + r) * 16 + c] = acc;
}

// ---------------- fused MFMA edge MLPs -> dst-slot-ordered ebd / ebd2 ----------------
#define TSTR 72   // LDS tile row stride in bf16 elems (144 B: 16B-aligned frag reads, <=2-way banks)
__global__ __launch_bounds__(256) void edge_mlps_k(
    const float* __restrict__ kr, const int* __restrict__ rkd,
    const u16* __restrict__ w1f, const u16* __restrict__ w2f, const float* __restrict__ b2a,
    const u16* __restrict__ w3f, const u16* __restrict__ w4f, const float* __restrict__ b2b,
    u16* __restrict__ ebd, u16* __restrict__ ebd2)
{
    __shared__ __align__(16) u16 T[4][16 * TSTR];
    const int t = threadIdx.x, wv = t >> 6, lane = t & 63;
    const int lm = lane & 15, quad = lane >> 4;
    const int tile = blockIdx.x * 4 + wv;
    const int e0 = tile * 16;
    if (e0 >= E_TOT) return;
    u16* Tw = T[wv];

    // weight fragments -> VGPRs (per-lane)
    short8 W1[4], W2[2][4];
    #pragma unroll
    for (int nt = 0; nt < 4; ++nt) W1[nt] = *(const short8*)(w1f + ((size_t)nt * 64 + lane) * 8);
    #pragma unroll
    for (int ks = 0; ks < 2; ++ks)
        #pragma unroll
        for (int nt = 0; nt < 4; ++nt)
            W2[ks][nt] = *(const short8*)(w2f + (((size_t)ks * 4 + nt) * 64 + lane) * 8);
    short8 W3 = *(const short8*)(w3f + (size_t)lane * 8);
    short8 W4 = *(const short8*)(w4f + (size_t)lane * 8);
    float b2av[4];
    #pragma unroll
    for (int nt = 0; nt < 4; ++nt) b2av[nt] = b2a[nt * 16 + lm];
    float b2bv = b2b[lm];

    // A-frag from kr: edge m = e0+lm, k = quad*8+j (K=16 zero-padded to 32)
    short8 af = {};
    if (quad < 2) {
        const float* kp = kr + (size_t)(e0 + lm) * NC + quad * 8;
        float4 v0 = *(const float4*)kp;
        float4 v1 = *(const float4*)(kp + 4);
        u16 tmp[8] = {f2bf(v0.x), f2bf(v0.y), f2bf(v0.z), f2bf(v0.w),
                      f2bf(v1.x), f2bf(v1.y), f2bf(v1.z), f2bf(v1.w)};
        af = *(const short8*)tmp;
    }

    // ---- MLP1 layer 1: [16 edges x 64] = kr @ w1, leaky 0.2 ----
    f32x4 a1[4] = {};
    #pragma unroll
    for (int nt = 0; nt < 4; ++nt)
        a1[nt] = __builtin_amdgcn_mfma_f32_16x16x32_bf16(af, W1[nt], a1[nt], 0, 0, 0);
    #pragma unroll
    for (int nt = 0; nt < 4; ++nt)
        #pragma unroll
        for (int r = 0; r < 4; ++r) {
            float v = a1[nt][r];
            v = v > 0.f ? v : 0.2f * v;
            Tw[(quad * 4 + r) * TSTR + nt * 16 + lm] = f2bf(v);
        }
    __builtin_amdgcn_s_waitcnt(0);   // drain LDS writes before same-wave reads

    // ---- MLP1 layer 2: K=64 from LDS tile ----
    short8 a2[2];
    #pragma unroll
    for (int ks = 0; ks < 2; ++ks)
        a2[ks] = *(const short8*)&Tw[lm * TSTR + ks * 32 + quad * 8];
    f32x4 c2[4] = {};
    #pragma unroll
    for (int nt = 0; nt < 4; ++nt)
        #pragma unroll
        for (int ks = 0; ks < 2; ++ks)
            c2[nt] = __builtin_amdgcn_mfma_f32_16x16x32_bf16(a2[ks], W2[ks][nt], c2[nt], 0, 0, 0);
    // epilogue: + b2, exp -> LDS
    #pragma unroll
    for (int nt = 0; nt < 4; ++nt)
        #pragma unroll
        for (int r = 0; r < 4; ++r)
            Tw[(quad * 4 + r) * TSTR + nt * 16 + lm] = f2bf(__expf(c2[nt][r] + b2av[nt]));
    __builtin_amdgcn_s_waitcnt(0);
    // repack: 16B row-chunks scattered to dst-slot rows (8 lanes per 128B row)
    #pragma unroll
    for (int p = 0; p < 2; ++p) {
        int c = p * 64 + lane;
        int row = c >> 3, off = (c & 7) * 8;
        int rd = rkd[e0 + row];
        short8 v = *(const short8*)&Tw[row * TSTR + off];
        *(short8*)(ebd + (size_t)rd * HID + off) = v;
    }

    // ---- MLP2 (16->16->16), reuses kr A-frag ----
    f32x4 b1 = __builtin_amdgcn_mfma_f32_16x16x32_bf16(af, W3, (f32x4){}, 0, 0, 0);
    __builtin_amdgcn_s_waitcnt(0);   // eb repack reads done before overwrite
    #pragma unroll
    for (int r = 0; r < 4; ++r) {
        float v = b1[r];
        v = v > 0.f ? v : 0.2f * v;
        Tw[(quad * 4 + r) * TSTR + lm] = f2bf(v);
    }
    __builtin_amdgcn_s_waitcnt(0);
    // A-frag: cols 16..31 hold stale finite values, but W4 is zero there -> no effect
    short8 a3 = *(const short8*)&Tw[lm * TSTR + quad * 8];
    f32x4 c3 = __builtin_amdgcn_mfma_f32_16x16x32_bf16(a3, W4, (f32x4){}, 0, 0, 0);
    #pragma unroll
    for (int r = 0; r < 4; ++r)
        Tw[(quad * 4 + r) * TSTR + lm] = f2bf(__expf(c3[r] + b2bv));
    __builtin_amdgcn_s_waitcnt(0);
    if (lane < 32) {
        int row = lane >> 1, off = (lane & 1) * 8;
        int rd = rkd[e0 + row];
        short8 v = *(const short8*)&Tw[row * TSTR + off];
        *(short8*)(ebd2 + (size_t)rd * NCLS + off) = v;
    }
}

// ---------------- inverse softmax denominator, layer 1 (wave per src), bf16 out ----------------
__global__ __launch_bounds__(256) void s1sum_k(
    const u16* __restrict__ ebd, const int* __restrict__ src_off, const int* __restrict__ src_list,
    u16* __restrict__ inv1b)
{
    int gid = blockIdx.x * 256 + threadIdx.x;
    int wid = gid >> 6, lane = gid & 63;
    if (wid >= N_NODES) return;
    int o0 = src_off[wid], o1 = src_off[wid + 1];
    float s0 = 0.f, s1 = 0.f, s2 = 0.f, s3 = 0.f;
    int i = o0;
    for (; i + 3 < o1; i += 4) {
        int l0 = src_list[i], l1 = src_list[i + 1], l2 = src_list[i + 2], l3 = src_list[i + 3];
        s0 += bf2f(ebd[(size_t)l0 * HID + lane]);
        s1 += bf2f(ebd[(size_t)l1 * HID + lane]);
        s2 += bf2f(ebd[(size_t)l2 * HID + lane]);
        s3 += bf2f(ebd[(size_t)l3 * HID + lane]);
    }
    for (; i < o1; ++i) {
        int sl = src_list[i];
        s0 += bf2f(ebd[(size_t)sl * HID + lane]);
    }
    float sum = (s0 + s1) + (s2 + s3);
    inv1b[(size_t)wid * HID + lane] = f2bf(1.f / (sum + 1e-16f));
}

// ---------------- message pass 1: wave per dst, sequential slots, NT streams, unroll 2 ----------------
__global__ __launch_bounds__(256) void msg1_k(
    const u16* __restrict__ ebd, const u16* __restrict__ inv1b,
    const u16* __restrict__ xb, const int* __restrict__ dsrc,
    const int* __restrict__ dst_off, u16* __restrict__ aggb)
{
    int gid = blockIdx.x * 256 + threadIdx.x;
    int wid = gid >> 6, lane = gid & 63;
    if (wid >= N_NODES) return;
    int o0 = dst_off[wid], o1 = dst_off[wid + 1];
    const int a_off = (lane & 7) * 8;     // alpha channel block (ch = lane*8+j mod 64)
    const int x_off = lane * 8;
    float acc[8] = {};
    int i = o0;
    for (; i + 1 < o1; i += 2) {
        int s0 = __builtin_nontemporal_load(dsrc + i);
        int s1 = __builtin_nontemporal_load(dsrc + i + 1);
        short8 a0 = __builtin_nontemporal_load((const short8*)(ebd + (size_t)i * HID + a_off));
        short8 a1 = __builtin_nontemporal_load((const short8*)(ebd + (size_t)(i + 1) * HID + a_off));
        short8 v0 = *(const short8*)(inv1b + (size_t)s0 * HID + a_off);
        short8 v1 = *(const short8*)(inv1b + (size_t)s1 * HID + a_off);
        short8 x0 = *(const short8*)(xb + (size_t)s0 * H1 + x_off);
        short8 x1 = *(const short8*)(xb + (size_t)s1 * H1 + x_off);
        #pragma unroll
        for (int j = 0; j < 8; ++j) {
            float aa0 = bf2f((u16)a0[j]) * bf2f((u16)v0[j]);
            float aa1 = bf2f((u16)a1[j]) * bf2f((u16)v1[j]);
            acc[j] = fmaf(aa0, bf2f((u16)x0[j]), acc[j]);
            acc[j] = fmaf(aa1, bf2f((u16)x1[j]), acc[j]);
        }
    }
    if (i < o1) {
        int s = __builtin_nontemporal_load(dsrc + i);
        short8 a8 = __builtin_nontemporal_load((const short8*)(ebd + (size_t)i * HID + a_off));
        short8 v8 = *(const short8*)(inv1b + (size_t)s * HID + a_off);
        short8 x8 = *(const short8*)(xb + (size_t)s * H1 + x_off);
        #pragma unroll
        for (int j = 0; j < 8; ++j) {
            float a = bf2f((u16)a8[j]) * bf2f((u16)v8[j]);
            acc[j] = fmaf(a, bf2f((u16)x8[j]), acc[j]);
        }
    }
    u16 pk[8];
    #pragma unroll
    for (int j = 0; j < 8; ++j) pk[j] = f2bf(acc[j]);
    __builtin_nontemporal_store(*(const short8*)pk, (short8*)(aggb + (size_t)wid * H1 + x_off));
}

// ---------------- inverse denominator, layer 2 (16 threads per src) ----------------
__global__ __launch_bounds__(256) void s2sum_k(
    const u16* __restrict__ ebd2, const int* __restrict__ src_off, const int* __restrict__ src_list,
    float* __restrict__ inv2)
{
    int t = threadIdx.x;
    int g = blockIdx.x * 16 + (t >> 4), c = t & 15;
    if (g >= N_NODES) return;
    int o0 = src_off[g], o1 = src_off[g + 1];
    float sum = 0.f;
    for (int i = o0; i < o1; ++i) {
        int sl = src_list[i];
        sum += bf2f(ebd2[(size_t)sl * NCLS + c]);
    }
    inv2[(size_t)g * NCLS + c] = 1.f / (sum + 1e-16f);
}

// ---------------- message pass 2 (16 threads per dst), sequential slots ----------------
__global__ __launch_bounds__(256) void msg2_k(
    const u16* __restrict__ ebd2, const float* __restrict__ inv2,
    const float* __restrict__ xh2, const int* __restrict__ dsrc,
    const int* __restrict__ dst_off, float* __restrict__ agg2)
{
    int t = threadIdx.x;
    int g = blockIdx.x * 16 + (t >> 4), c = t & 15;
    if (g >= N_NODES) return;
    int o0 = dst_off[g], o1 = dst_off[g + 1];
    float acc = 0.f;
    for (int i = o0; i < o1; ++i) {
        int s = dsrc[i];
        float a = bf2f(ebd2[(size_t)i * NCLS + c]) * inv2[(size_t)s * NCLS + c];
        acc = fmaf(a, xh2[(size_t)s * NCLS + c], acc);
    }
    agg2[(size_t)g * NCLS + c] = acc;
}

// ---------------- final: o = agg2 + bias2 + alpha*p2; log_softmax ----------------
__global__ __launch_bounds__(256) void final_k(
    const float* __restrict__ agg2, const float* __restrict__ ep,
    const float* __restrict__ pw1, const float* __restrict__ pw2,
    const float* __restrict__ pb2, const float* __restrict__ bias,
    const float* __restrict__ alpha_p, float* __restrict__ out)
{
    __shared__ float s1w[256], s2w[256], sb[16], sbias[16];
    const int t = threadIdx.x;
    s1w[t] = pw1[t];
    s2w[t] = pw2[t];
    if (t < 16) { sb[t] = pb2[t]; sbias[t] = bias[t]; }
    __syncthreads();
    const int v = blockIdx.x * 256 + t;
    if (v >= N_NODES) return;
    float alpha = *alpha_p;
    float e_[16];
    #pragma unroll
    for (int j4 = 0; j4 < 16; j4 += 4) {
        float4 vv = *(const float4*)(ep + (size_t)v * 16 + j4);
        e_[j4] = vv.x; e_[j4 + 1] = vv.y; e_[j4 + 2] = vv.z; e_[j4 + 3] = vv.w;
    }
    float t2[16];
    #pragma unroll
    for (int c = 0; c < 16; ++c) {
        float s = 0.f;
        #pragma unroll
        for (int j = 0; j < 16; ++j) s = fmaf(e_[j], s1w[j * 16 + c], s);
        t2[c] = s > 0.f ? s : 0.2f * s;
    }
    float o[16];
    #pragma unroll
    for (int c4 = 0; c4 < 16; c4 += 4) {
        float4 ag = *(const float4*)(agg2 + (size_t)v * 16 + c4);
        float agv[4] = {ag.x, ag.y, ag.z, ag.w};
        #pragma unroll
        for (int q = 0; q < 4; ++q) {
            int c = c4 + q;
            float p = sb[c];
            #pragma unroll
            for (int j = 0; j < 16; ++j) p = fmaf(t2[j], s2w[j * 16 + c], p);
            p = p > 0.f ? p : 0.01f * p;
            o[c] = agv[q] + sbias[c] + alpha * p;
        }
    }
    float mx = o[0];
    #pragma unroll
    for (int c = 1; c < 16; ++c) mx = fmaxf(mx, o[c]);
    float se = 0.f;
    #pragma unroll
    for (int c = 0; c < 16; ++c) se += expf(o[c] - mx);
    float lse = mx + logf(se);
    #pragma unroll
    for (int c4 = 0; c4 < 16; c4 += 4)
        *(float4*)(out + (size_t)v * 16 + c4) =
            make_float4(o[c4] - lse, o[c4 + 1] - lse, o[c4 + 2] - lse, o[c4 + 3] - lse);
}

extern "C" void kernel_launch(void* const* d_in, const int* in_sizes, int n_in,
                              void* d_out, int out_size, void* d_ws, size_t ws_size,
                              hipStream_t stream) {
    const float* x    = (const float*)d_in[0];
    const int*   ei   = (const int*)d_in[1];
    const float* alpha= (const float*)d_in[2];
    const float* kr   = (const float*)d_in[3];
    const float* ep   = (const float*)d_in[4];
    const float* W1   = (const float*)d_in[5];
    const float* h1w1 = (const float*)d_in[6];
    const float* h1w2 = (const float*)d_in[7];
    const float* h1b2 = (const float*)d_in[8];
    const float* p1w1 = (const float*)d_in[9];
    const float* p1w2 = (const float*)d_in[10];
    const float* p1b2 = (const float*)d_in[11];
    const float* b1   = (const float*)d_in[12];
    const float* W2   = (const float*)d_in[13];
    const float* h2w1 = (const float*)d_in[14];
    const float* h2w2 = (const float*)d_in[15];
    const float* h2b2 = (const float*)d_in[16];
    const float* p2w1 = (const float*)d_in[17];
    const float* p2w2 = (const float*)d_in[18];
    const float* p2b2 = (const float*)d_in[19];
    const float* b2   = (const float*)d_in[20];
    float* out = (float*)d_out;

    // ---- workspace bump allocator (~242 MB) ----
    char* p = (char*)d_ws;
    auto alloc = [&](size_t bytes) { char* r = p; p += (bytes + 255) & ~(size_t)255; return r; };

    char* r0    = alloc((size_t)64 * M_PAD * 16);          // 51.25 MB: xb (row-major bf16 N x 512), then t1p (frag-major)
    u16*  xb    = (u16*)r0;
    u16*  t1p   = (u16*)r0;
    u16*  aggb  = (u16*)alloc((size_t)N_NODES * H1 * 2);   // 51.2 MB bf16
    char* ebr   = alloc((size_t)E_TOT * HID * 2);          // 83.2 MB: ebd (dst-ordered), then hb (Nx512)
    u16*  ebd   = (u16*)ebr;
    u16*  hb    = (u16*)ebr;
    u16*  ebd2  = (u16*)alloc((size_t)E_TOT * NCLS * 2);   // 20.8 MB
    char* xpr   = alloc((size_t)16 * M_PAD * 16);          // 12.81 MB: xp (frag-major x), then inv1b (Nx64 bf16)
    u16*  xp    = (u16*)xpr;
    u16*  inv1b = (u16*)xpr;
    u16*  W1p   = (u16*)alloc((size_t)16 * H1 * 16);       // 128 KB
    u16*  p1w2p = (u16*)alloc((size_t)64 * H1 * 16);       // 512 KB
    u16*  w1f   = (u16*)alloc(2048 * 2);                   // mlp1 w1 frags
    u16*  w2f   = (u16*)alloc(4096 * 2);                   // mlp1 w2 frags
    u16*  w3f   = (u16*)alloc(512 * 2);                    // mlp2 w1 frags
    u16*  w4f   = (u16*)alloc(512 * 2);                    // mlp2 w2 frags
    int* src_cnt  = (int*)alloc(N_NODES * 4);
    int* dst_cnt  = (int*)alloc(N_NODES * 4);
    int* src_cur  = (int*)alloc(N_NODES * 4);
    int* dst_cur  = (int*)alloc(N_NODES * 4);
    int* partials = (int*)alloc(2 * NBLK * 4);
    int* src_off  = (int*)alloc((N_NODES + 1) * 4);
    int* dst_off  = (int*)alloc((N_NODES + 1) * 4);
    int* src_list = (int*)alloc((size_t)E_TOT * 4);        // dst-slot ids grouped by src
    int* rkd      = (int*)alloc((size_t)E_TOT * 4);        // e -> dst slot
    int* dsrc     = (int*)alloc((size_t)E_TOT * 4);        // dst slot -> src node
    float* xh2  = (float*)alloc((size_t)N_NODES * NCLS * 4);
    float* agg2 = (float*)alloc((size_t)N_NODES * NCLS * 4);
    float* inv2 = (float*)alloc((size_t)N_NODES * NCLS * 4);

    const dim3 blk(256);
    const int EB = (E_TOT + 255) / 256;
    const int WB = (N_NODES * 64 + 255) / 256;
    const int GB16 = (N_NODES + 15) / 16;
    const dim3 gmm(512 / 128, M_PAD / 128);                 // (4, 391)
    const int MLPB = (E_TOT / 16 + 3) / 4;

    // ---- CSR build + weight/layout conversion ----
    hipMemsetAsync(src_cnt, 0, (char*)partials - (char*)src_cnt, stream);
    count_k<<<EB, blk, 0, stream>>>(ei, src_cnt, dst_cnt);
    scanA_k<<<2 * NBLK, blk, 0, stream>>>(src_cnt, dst_cnt, partials);
    scanB_k<<<1, 512, 0, stream>>>(partials);
    scanC_k<<<2 * NBLK, blk, 0, stream>>>(src_cnt, dst_cnt, partials, src_off, dst_off);
    fill_csr_k<<<EB, blk, 0, stream>>>(ei, src_off, dst_off, src_cur, dst_cur, src_list, rkd, dsrc);
    conv_a_k<<<(16 * M_PAD + 255) / 256, blk, 0, stream>>>(x, xp, N_NODES, M_PAD, F_IN);
    conv_b_k<<<(16 * H1 + 255) / 256, blk, 0, stream>>>(W1, W1p, F_IN, H1);
    conv_b_k<<<(64 * H1 + 255) / 256, blk, 0, stream>>>(p1w2, p1w2p, H1, H1);
    conv_wfrag_k<<<8, blk, 0, stream>>>(h1w1, w1f, 16, 32, 64);
    conv_wfrag_k<<<16, blk, 0, stream>>>(h1w2, w2f, 64, 64, 64);
    conv_wfrag_k<<<2, blk, 0, stream>>>(h2w1, w3f, 16, 32, 16);
    conv_wfrag_k<<<2, blk, 0, stream>>>(h2w2, w4f, 16, 32, 16);

    // ---- layer 1 ----
    mfma_gemm_k<0><<<gmm, blk, 0, stream>>>(xp, W1p, xb, N_NODES, M_PAD, H1, F_IN,
                                            nullptr, nullptr, nullptr, nullptr);
    edge_mlps_k<<<MLPB, blk, 0, stream>>>(kr, rkd, w1f, w2f, h1b2, w3f, w4f, h2b2, ebd, ebd2);
    s1sum_k<<<WB, blk, 0, stream>>>(ebd, src_off, src_list, inv1b);
    msg1_k<<<WB, blk, 0, stream>>>(ebd, inv1b, xb, dsrc, dst_off, aggb);
    gemm_t1_k<<<dim3(8, (N_NODES + 63) / 64), blk, 0, stream>>>(ep, p1w1, t1p);   // overwrites xb region
    mfma_gemm_k<3><<<gmm, blk, 0, stream>>>(t1p, p1w2p, hb, N_NODES, M_PAD, H1, H1,
                                            p1b2, aggb, b1, alpha);               // hb overwrites ebd region

    // ---- layer 2 ----
    gemm_n16_k<<<(N_NODES + 15) / 16, blk, 0, stream>>>(hb, W2, xh2, N_NODES, H1);
    s2sum_k<<<GB16, blk, 0, stream>>>(ebd2, src_off, src_list, inv2);
    msg2_k<<<GB16, blk, 0, stream>>>(ebd2, inv2, xh2, dsrc, dst_off, agg2);
    final_k<<<(N_NODES + 255) / 256, blk, 0, stream>>>(agg2, ep, p2w1, p2w2, p2b2, b2, alpha, out);
}

// Round 8
// 720.093 us; speedup vs baseline: 1.9419x; 1.0192x over previous
//
#include <hip/hip_runtime.h>
#include <math.h>

#define N_NODES 50000
#define M_PAD   50048    // N_NODES padded to multiple of 128 for MFMA tiles
#define N_EDGES 600000
#define E_TOT   650000   // N_EDGES + N_NODES (self loops appended)
#define F_IN    128
#define HID     64
#define HEADS   8
#define H1      512      // HEADS*HID
#define NCLS    16
#define NC      16
#define NCP     16
#define NBLK    ((N_NODES + 255) / 256)   // 196 scan blocks per array

typedef unsigned short u16;
typedef __attribute__((ext_vector_type(8))) short short8;   // 8 bf16 = 4 VGPRs (MFMA A/B frag)
typedef __attribute__((ext_vector_type(4))) float f32x4;    // MFMA C/D frag

__device__ __forceinline__ float bf2f(u16 h) {
    return __uint_as_float(((unsigned)h) << 16);
}
__device__ __forceinline__ u16 f2bf(float f) {
    unsigned u = __float_as_uint(f);
    u += 0x7fffu + ((u >> 16) & 1u);
    return (u16)(u >> 16);
}
__device__ __forceinline__ int edge_src(const int* __restrict__ ei, int e) {
    return (e < N_EDGES) ? ei[e] : (e - N_EDGES);
}
__device__ __forceinline__ int edge_dst(const int* __restrict__ ei, int e) {
    return (e < N_EDGES) ? ei[N_EDGES + e] : (e - N_EDGES);
}

// ---------------- CSR build ----------------
__global__ __launch_bounds__(256) void count_k(const int* __restrict__ ei,
                                               int* __restrict__ src_cnt, int* __restrict__ dst_cnt) {
    int e = blockIdx.x * 256 + threadIdx.x;
    if (e >= E_TOT) return;
    atomicAdd(&src_cnt[edge_src(ei, e)], 1);
    atomicAdd(&dst_cnt[edge_dst(ei, e)], 1);
}

// Phase A: per-block partial sums. grid = 2*NBLK (src blocks, then dst blocks).
__global__ __launch_bounds__(256) void scanA_k(const int* __restrict__ src_cnt,
                                               const int* __restrict__ dst_cnt,
                                               int* __restrict__ partials) {
    int pass = blockIdx.x >= NBLK;
    int b = blockIdx.x - pass * NBLK;
    const int* cnt = pass ? dst_cnt : src_cnt;
    int idx = b * 256 + threadIdx.x;
    int v = (idx < N_NODES) ? cnt[idx] : 0;
    __shared__ int red[4];
    #pragma unroll
    for (int off = 32; off; off >>= 1) v += __shfl_down(v, off, 64);
    if ((threadIdx.x & 63) == 0) red[threadIdx.x >> 6] = v;
    __syncthreads();
    if (threadIdx.x == 0) partials[blockIdx.x] = red[0] + red[1] + red[2] + red[3];
}

// Phase B: two independent exclusive scans of NBLK partials (src seg, dst seg), one block.
__global__ __launch_bounds__(512) void scanB_k(int* __restrict__ partials) {
    __shared__ int lds[512];
    int t = threadIdx.x;           // 512 threads: t<256 -> src segment, else dst
    int seg = t >> 8, i = t & 255;
    int v = (i < NBLK) ? partials[seg * NBLK + i] : 0;
    lds[t] = v;
    __syncthreads();
    for (int d = 1; d < 256; d <<= 1) {
        int x = (i >= d) ? lds[seg * 256 + i - d] : 0;
        __syncthreads();
        lds[t] += x;
        __syncthreads();
    }
    if (i < NBLK) partials[seg * NBLK + i] = lds[t] - v;   // exclusive
}

// Phase C: block-local exclusive scan + block offset -> off[]; off[N]=E_TOT constant.
__global__ __launch_bounds__(256) void scanC_k(const int* __restrict__ src_cnt,
                                               const int* __restrict__ dst_cnt,
                                               const int* __restrict__ partials,
                                               int* __restrict__ src_off, int* __restrict__ dst_off) {
    int pass = blockIdx.x >= NBLK;
    int b = blockIdx.x - pass * NBLK;
    const int* cnt = pass ? dst_cnt : src_cnt;
    int* off = pass ? dst_off : src_off;
    int base = partials[blockIdx.x];
    __shared__ int lds[256];
    int t = threadIdx.x;
    int idx = b * 256 + t;
    int v = (idx < N_NODES) ? cnt[idx] : 0;
    lds[t] = v;
    __syncthreads();
    for (int d = 1; d < 256; d <<= 1) {
        int x = (t >= d) ? lds[t - d] : 0;
        __syncthreads();
        lds[t] += x;
        __syncthreads();
    }
    if (idx < N_NODES) off[idx] = base + lds[t] - v;
    if (b == 0 && t == 0) off[N_NODES] = E_TOT;
}

// fill: rkd[e] = slot of e in dst-CSR; dsrc[slot] = src node; src_list[src slot] = dst-slot id
__global__ __launch_bounds__(256) void fill_csr_k(const int* __restrict__ ei,
                                                  const int* __restrict__ src_off, const int* __restrict__ dst_off,
                                                  int* __restrict__ src_cur, int* __restrict__ dst_cur,
                                                  int* __restrict__ src_list, int* __restrict__ rkd,
                                                  int* __restrict__ dsrc) {
    int e = blockIdx.x * 256 + threadIdx.x;
    if (e >= E_TOT) return;
    int s = edge_src(ei, e), d = edge_dst(ei, e);
    int pd = atomicAdd(&dst_cur[d], 1);
    int rd = dst_off[d] + pd;
    rkd[e] = rd;
    dsrc[rd] = s;
    int ps = atomicAdd(&src_cur[s], 1);
    src_list[src_off[s] + ps] = rd;
}

// ---------------- layout converters ----------------
// f32 [M][K] row-major -> bf16 fragment-major Ap[K/8][Mp][8]; pad rows zeroed
__global__ __launch_bounds__(256) void conv_a_k(const float* __restrict__ A, u16* __restrict__ Ap,
                                                int M, int Mp, int K) {
    int i = blockIdx.x * 256 + threadIdx.x;
    int total = (K >> 3) * Mp;
    if (i >= total) return;
    int r = i % Mp;
    int kb = i / Mp;
    u16* o = Ap + (size_t)i * 8;
    u16 tmp[8];
    if (r < M) {
        const float* a = A + (size_t)r * K + kb * 8;
        #pragma unroll
        for (int j = 0; j < 8; ++j) tmp[j] = f2bf(a[j]);
    } else {
        #pragma unroll
        for (int j = 0; j < 8; ++j) tmp[j] = 0;
    }
    *(ushort4*)o = *(ushort4*)tmp;
    *(ushort4*)(o + 4) = *(ushort4*)(tmp + 4);
}

// f32 [K][N] row-major -> bf16 fragment-major Bp[K/8][N][8] (Bp[kb][n][j] = B[kb*8+j][n])
__global__ __launch_bounds__(256) void conv_b_k(const float* __restrict__ B, u16* __restrict__ Bp,
                                                int K, int N) {
    int i = blockIdx.x * 256 + threadIdx.x;
    int total = (K >> 3) * N;
    if (i >= total) return;
    int n = i % N;
    int kb = i / N;
    u16 tmp[8];
    #pragma unroll
    for (int j = 0; j < 8; ++j) tmp[j] = f2bf(B[(size_t)(kb * 8 + j) * N + n]);
    u16* o = Bp + (size_t)i * 8;
    *(ushort4*)o = *(ushort4*)tmp;
    *(ushort4*)(o + 4) = *(ushort4*)(tmp + 4);
}

// all 4 edge-MLP weight tables -> per-lane B-frag layout, one launch
__device__ __forceinline__ void wfrag_one(const float* W, u16* o, int i, int K, int N) {
    int j = i & 7, lane = (i >> 3) & 63, rest = i >> 9;
    int nt = rest % (N / 16), ks = rest / (N / 16);
    int lm = lane & 15, quad = lane >> 4;
    int k = ks * 32 + quad * 8 + j, n = nt * 16 + lm;
    o[i] = (k < K) ? f2bf(W[(size_t)k * N + n]) : (u16)0;
}
__global__ __launch_bounds__(256) void wfrag_all_k(
    const float* __restrict__ h1w1, const float* __restrict__ h1w2,
    const float* __restrict__ h2w1, const float* __restrict__ h2w2,
    u16* __restrict__ w1f, u16* __restrict__ w2f,
    u16* __restrict__ w3f, u16* __restrict__ w4f) {
    int i = blockIdx.x * 256 + threadIdx.x;   // total 2048+4096+512+512 = 7168
    if (i < 2048)      wfrag_one(h1w1, w1f, i, 16, 64);          // Kpad 32, N 64
    else if (i < 6144) wfrag_one(h1w2, w2f, i - 2048, 64, 64);   // Kpad 64, N 64
    else if (i < 6656) wfrag_one(h2w1, w3f, i - 6144, 16, 16);
    else if (i < 7168) wfrag_one(h2w2, w4f, i - 6656, 16, 16);
}

// ---------------- MFMA GEMM: C[M][N] = epi(Ap @ Bp), frag-major operands, no LDS ----------------
template<int EPI>
__global__ __launch_bounds__(256) void mfma_gemm_k(
    const u16* __restrict__ Ap, const u16* __restrict__ Bp, u16* __restrict__ C,
    int M, int Mp, int Nn, int K,
    const float* __restrict__ bias, const u16* __restrict__ extra,
    const float* __restrict__ bias2, const float* __restrict__ alpha_p)
{
    const int t = threadIdx.x;
    const int wave = t >> 6, lane = t & 63;
    const int wm = (wave >> 1) * 64, wn = (wave & 1) * 64;
    const int bm = blockIdx.y * 128, bn = blockIdx.x * 128;
    const int lm = lane & 15, quad = lane >> 4;

    size_t rbase[4], cbase[4];
    #pragma unroll
    for (int mi = 0; mi < 4; ++mi) rbase[mi] = (size_t)(bm + wm + mi * 16 + lm) * 8;
    #pragma unroll
    for (int nj = 0; nj < 4; ++nj) cbase[nj] = (size_t)(bn + wn + nj * 16 + lm) * 8;

    f32x4 acc[4][4] = {};

    for (int k0 = 0; k0 < K; k0 += 32) {
        int kb = (k0 >> 3) + quad;
        size_t abase = (size_t)kb * Mp * 8;
        size_t bbase = (size_t)kb * Nn * 8;
        short8 af[4], bf_[4];
        #pragma unroll
        for (int mi = 0; mi < 4; ++mi) af[mi] = *(const short8*)(Ap + abase + rbase[mi]);
        #pragma unroll
        for (int nj = 0; nj < 4; ++nj) bf_[nj] = *(const short8*)(Bp + bbase + cbase[nj]);
        #pragma unroll
        for (int mi = 0; mi < 4; ++mi)
            #pragma unroll
            for (int nj = 0; nj < 4; ++nj)
                acc[mi][nj] = __builtin_amdgcn_mfma_f32_16x16x32_bf16(af[mi], bf_[nj], acc[mi][nj], 0, 0, 0);
    }

    // C/D layout: col = lane&15, row = quad*4 + reg
    const int orow = bm + wm + quad * 4;
    const int ocol = bn + wn + lm;
    if (EPI == 0) {
        #pragma unroll
        for (int mi = 0; mi < 4; ++mi)
            #pragma unroll
            for (int r = 0; r < 4; ++r) {
                int rr = orow + mi * 16 + r;
                if (rr >= M) continue;
                #pragma unroll
                for (int nj = 0; nj < 4; ++nj)
                    C[(size_t)rr * Nn + ocol + nj * 16] = f2bf(acc[mi][nj][r]);
            }
    } else {
        float alpha = *alpha_p;
        #pragma unroll
        for (int mi = 0; mi < 4; ++mi)
            #pragma unroll
            for (int r = 0; r < 4; ++r) {
                int rr = orow + mi * 16 + r;
                if (rr >= M) continue;
                #pragma unroll
                for (int nj = 0; nj < 4; ++nj) {
                    int c = ocol + nj * 16;
                    float v = acc[mi][nj][r] + bias[c];
                    v = v > 0.f ? v : 0.01f * v;
                    float o = bf2f(extra[(size_t)rr * Nn + c]) + bias2[c] + alpha * v;
                    o = fmaxf(o, 0.f);
                    C[(size_t)rr * Nn + c] = f2bf(o);
                }
            }
    }
}

// ---------------- t1 = leaky(ep @ p1w1, 0.2), K=16, written in frag-major Ap layout ----------------
__global__ __launch_bounds__(256) void gemm_t1_k(
    const float* __restrict__ ep, const float* __restrict__ W, u16* __restrict__ t1p)
{
    __shared__ float Bs[16][64];
    const int bm = blockIdx.y * 64, bn = blockIdx.x * 64;
    const int t = threadIdx.x;
    const int tx = t & 15, ty = t >> 4;
    *(float4*)&Bs[t >> 4][(t & 15) * 4] = *(const float4*)&W[(size_t)(t >> 4) * H1 + bn + (t & 15) * 4];
    __syncthreads();
    const int r0 = bm + ty * 4;
    const int c0 = bn + tx * 4;
    for (int i = 0; i < 4; ++i) {
        int r = r0 + i;
        if (r >= N_NODES) continue;
        float av[16];
        #pragma unroll
        for (int j4 = 0; j4 < 16; j4 += 4) {
            float4 v = *(const float4*)(ep + (size_t)r * NCP + j4);
            av[j4] = v.x; av[j4 + 1] = v.y; av[j4 + 2] = v.z; av[j4 + 3] = v.w;
        }
        u16 pk[4];
        #pragma unroll
        for (int q = 0; q < 4; ++q) {
            float s = 0.f;
            #pragma unroll
            for (int k = 0; k < 16; ++k) s = fmaf(av[k], Bs[k][tx * 4 + q], s);
            s = s > 0.f ? s : 0.2f * s;
            pk[q] = f2bf(s);
        }
        u16* o = t1p + ((size_t)(c0 >> 3) * M_PAD + r) * 8 + (c0 & 7);
        *(ushort4*)o = *(ushort4*)pk;
    }
}

// ---------------- N=16 GEMM (xh2 = h @ W_src2), bf16 A, K multiple of 64 ----------------
__global__ __launch_bounds__(256) void gemm_n16_k(
    const u16* __restrict__ A, const float* __restrict__ B, float* __restrict__ C,
    int M, int K)
{
    __shared__ float As[16][64];   // [row][k]
    __shared__ float Bs[64][16];   // [k][col]
    const int row0 = blockIdx.x * 16;
    const int t = threadIdx.x;
    const int r = t >> 4, c = t & 15;
    const int ar = t >> 4, ak4 = (t & 15) * 4;
    const int bk = t >> 2, bc4 = (t & 3) * 4;
    float acc = 0.f;
    for (int k0 = 0; k0 < K; k0 += 64) {
        float4 av = make_float4(0.f, 0.f, 0.f, 0.f);
        if (row0 + ar < M) {
            ushort4 h4 = *(const ushort4*)(A + (size_t)(row0 + ar) * K + k0 + ak4);
            av = make_float4(bf2f(h4.x), bf2f(h4.y), bf2f(h4.z), bf2f(h4.w));
        }
        *(float4*)&As[ar][ak4] = av;
        *(float4*)&Bs[bk][bc4] = *(const float4*)(B + (size_t)(k0 + bk) * 16 + bc4);
        __syncthreads();
        #pragma unroll
        for (int kk = 0; kk < 64; ++kk)
            acc = fmaf(As[r][kk], Bs[kk][c], acc);
        __syncthreads();
    }
    if (row0 + r < M) C[(size_t)(row0 + r) * 16 + c] = acc;
}

// ---------------- fused MFMA edge MLPs -> dst-slot-ordered ebd / ebd2 ----------------
#define TSTR 72   // LDS tile row stride in bf16 elems (144 B: 16B-aligned frag reads, <=2-way banks)
__global__ __launch_bounds__(256) void edge_mlps_k(
    const float* __restrict__ kr, const int* __restrict__ rkd,
    const u16* __restrict__ w1f, const u16* __restrict__ w2f, const float* __restrict__ b2a,
    const u16* __restrict__ w3f, const u16* __restrict__ w4f, const float* __restrict__ b2b,
    u16* __restrict__ ebd, u16* __restrict__ ebd2)
{
    __shared__ __align__(16) u16 T[4][16 * TSTR];
    const int t = threadIdx.x, wv = t >> 6, lane = t & 63;
    const int lm = lane & 15, quad = lane >> 4;
    const int tile = blockIdx.x * 4 + wv;
    const int e0 = tile * 16;
    if (e0 >= E_TOT) return;
    u16* Tw = T[wv];

    // weight fragments -> VGPRs (per-lane)
    short8 W1[4], W2[2][4];
    #pragma unroll
    for (int nt = 0; nt < 4; ++nt) W1[nt] = *(const short8*)(w1f + ((size_t)nt * 64 + lane) * 8);
    #pragma unroll
    for (int ks = 0; ks < 2; ++ks)
        #pragma unroll
        for (int nt = 0; nt < 4; ++nt)
            W2[ks][nt] = *(const short8*)(w2f + (((size_t)ks * 4 + nt) * 64 + lane) * 8);
    short8 W3 = *(const short8*)(w3f + (size_t)lane * 8);
    short8 W4 = *(const short8*)(w4f + (size_t)lane * 8);
    float b2av[4];
    #pragma unroll
    for (int nt = 0; nt < 4; ++nt) b2av[nt] = b2a[nt * 16 + lm];
    float b2bv = b2b[lm];

    // A-frag from kr: edge m = e0+lm, k = quad*8+j (K=16 zero-padded to 32)
    short8 af = {};
    if (quad < 2) {
        const float* kp = kr + (size_t)(e0 + lm) * NC + quad * 8;
        float4 v0 = *(const float4*)kp;
        float4 v1 = *(const float4*)(kp + 4);
        u16 tmp[8] = {f2bf(v0.x), f2bf(v0.y), f2bf(v0.z), f2bf(v0.w),
                      f2bf(v1.x), f2bf(v1.y), f2bf(v1.z), f2bf(v1.w)};
        af = *(const short8*)tmp;
    }

    // ---- MLP1 layer 1: [16 edges x 64] = kr @ w1, leaky 0.2 ----
    f32x4 a1[4] = {};
    #pragma unroll
    for (int nt = 0; nt < 4; ++nt)
        a1[nt] = __builtin_amdgcn_mfma_f32_16x16x32_bf16(af, W1[nt], a1[nt], 0, 0, 0);
    #pragma unroll
    for (int nt = 0; nt < 4; ++nt)
        #pragma unroll
        for (int r = 0; r < 4; ++r) {
            float v = a1[nt][r];
            v = v > 0.f ? v : 0.2f * v;
            Tw[(quad * 4 + r) * TSTR + nt * 16 + lm] = f2bf(v);
        }
    __builtin_amdgcn_s_waitcnt(0);   // drain LDS writes before same-wave reads

    // ---- MLP1 layer 2: K=64 from LDS tile ----
    short8 a2[2];
    #pragma unroll
    for (int ks = 0; ks < 2; ++ks)
        a2[ks] = *(const short8*)&Tw[lm * TSTR + ks * 32 + quad * 8];
    f32x4 c2[4] = {};
    #pragma unroll
    for (int nt = 0; nt < 4; ++nt)
        #pragma unroll
        for (int ks = 0; ks < 2; ++ks)
            c2[nt] = __builtin_amdgcn_mfma_f32_16x16x32_bf16(a2[ks], W2[ks][nt], c2[nt], 0, 0, 0);
    // epilogue: + b2, exp -> LDS
    #pragma unroll
    for (int nt = 0; nt < 4; ++nt)
        #pragma unroll
        for (int r = 0; r < 4; ++r)
            Tw[(quad * 4 + r) * TSTR + nt * 16 + lm] = f2bf(__expf(c2[nt][r] + b2av[nt]));
    __builtin_amdgcn_s_waitcnt(0);
    // repack: 16B row-chunks scattered to dst-slot rows (8 lanes per 128B row)
    #pragma unroll
    for (int p = 0; p < 2; ++p) {
        int c = p * 64 + lane;
        int row = c >> 3, off = (c & 7) * 8;
        int rd = rkd[e0 + row];
        short8 v = *(const short8*)&Tw[row * TSTR + off];
        *(short8*)(ebd + (size_t)rd * HID + off) = v;
    }

    // ---- MLP2 (16->16->16), reuses kr A-frag ----
    f32x4 b1 = __builtin_amdgcn_mfma_f32_16x16x32_bf16(af, W3, (f32x4){}, 0, 0, 0);
    __builtin_amdgcn_s_waitcnt(0);   // eb repack reads done before overwrite
    #pragma unroll
    for (int r = 0; r < 4; ++r) {
        float v = b1[r];
        v = v > 0.f ? v : 0.2f * v;
        Tw[(quad * 4 + r) * TSTR + lm] = f2bf(v);
    }
    __builtin_amdgcn_s_waitcnt(0);
    // A-frag: cols 16..31 hold stale finite values, but W4 is zero there -> no effect
    short8 a3 = *(const short8*)&Tw[lm * TSTR + quad * 8];
    f32x4 c3 = __builtin_amdgcn_mfma_f32_16x16x32_bf16(a3, W4, (f32x4){}, 0, 0, 0);
    #pragma unroll
    for (int r = 0; r < 4; ++r)
        Tw[(quad * 4 + r) * TSTR + lm] = f2bf(__expf(c3[r] + b2bv));
    __builtin_amdgcn_s_waitcnt(0);
    if (lane < 32) {
        int row = lane >> 1, off = (lane & 1) * 8;
        int rd = rkd[e0 + row];
        short8 v = *(const short8*)&Tw[row * TSTR + off];
        *(short8*)(ebd2 + (size_t)rd * NCLS + off) = v;
    }
}

// ---------------- layer-1 softmax denom + in-place scale of xb (wave per src) ----------------
// lane = channel c in [0,64); sums exp over out-edges, then xb[s][h*64+c] *= 1/sum for all 8 heads.
__global__ __launch_bounds__(256) void s1inv_k(
    const u16* __restrict__ ebd, const int* __restrict__ src_off, const int* __restrict__ src_list,
    u16* __restrict__ xb)
{
    int gid = blockIdx.x * 256 + threadIdx.x;
    int wid = gid >> 6, lane = gid & 63;
    if (wid >= N_NODES) return;
    int o0 = src_off[wid], o1 = src_off[wid + 1];
    float s0 = 0.f, s1 = 0.f, s2 = 0.f, s3 = 0.f;
    int i = o0;
    for (; i + 3 < o1; i += 4) {
        int l0 = src_list[i], l1 = src_list[i + 1], l2 = src_list[i + 2], l3 = src_list[i + 3];
        s0 += bf2f(ebd[(size_t)l0 * HID + lane]);
        s1 += bf2f(ebd[(size_t)l1 * HID + lane]);
        s2 += bf2f(ebd[(size_t)l2 * HID + lane]);
        s3 += bf2f(ebd[(size_t)l3 * HID + lane]);
    }
    for (; i < o1; ++i) {
        int sl = src_list[i];
        s0 += bf2f(ebd[(size_t)sl * HID + lane]);
    }
    float inv = 1.f / (((s0 + s1) + (s2 + s3)) + 1e-16f);
    u16* xr = xb + (size_t)wid * H1 + lane;
    #pragma unroll
    for (int h = 0; h < HEADS; ++h)
        xr[h * 64] = f2bf(bf2f(xr[h * 64]) * inv);
}

// ---------------- message pass 1: wave per dst, sequential slots, pre-scaled xb, unroll 4 ----------------
__global__ __launch_bounds__(256) void msg1_k(
    const u16* __restrict__ ebd, const u16* __restrict__ xb,
    const int* __restrict__ dsrc, const int* __restrict__ dst_off,
    u16* __restrict__ aggb)
{
    int gid = blockIdx.x * 256 + threadIdx.x;
    int wid = gid >> 6, lane = gid & 63;
    if (wid >= N_NODES) return;
    int o0 = dst_off[wid], o1 = dst_off[wid + 1];
    const int a_off = (lane & 7) * 8;     // alpha channel block (ch = lane*8+j mod 64)
    const int x_off = lane * 8;
    float acc[8] = {};
    int i = o0;
    for (; i + 3 < o1; i += 4) {
        int s0 = __builtin_nontemporal_load(dsrc + i);
        int s1 = __builtin_nontemporal_load(dsrc + i + 1);
        int s2 = __builtin_nontemporal_load(dsrc + i + 2);
        int s3 = __builtin_nontemporal_load(dsrc + i + 3);
        short8 a0 = __builtin_nontemporal_load((const short8*)(ebd + (size_t)i * HID + a_off));
        short8 a1 = __builtin_nontemporal_load((const short8*)(ebd + (size_t)(i + 1) * HID + a_off));
        short8 a2 = __builtin_nontemporal_load((const short8*)(ebd + (size_t)(i + 2) * HID + a_off));
        short8 a3 = __builtin_nontemporal_load((const short8*)(ebd + (size_t)(i + 3) * HID + a_off));
        short8 x0 = *(const short8*)(xb + (size_t)s0 * H1 + x_off);
        short8 x1 = *(const short8*)(xb + (size_t)s1 * H1 + x_off);
        short8 x2 = *(const short8*)(xb + (size_t)s2 * H1 + x_off);
        short8 x3 = *(const short8*)(xb + (size_t)s3 * H1 + x_off);
        #pragma unroll
        for (int j = 0; j < 8; ++j) {
            acc[j] = fmaf(bf2f((u16)a0[j]), bf2f((u16)x0[j]), acc[j]);
            acc[j] = fmaf(bf2f((u16)a1[j]), bf2f((u16)x1[j]), acc[j]);
            acc[j] = fmaf(bf2f((u16)a2[j]), bf2f((u16)x2[j]), acc[j]);
            acc[j] = fmaf(bf2f((u16)a3[j]), bf2f((u16)x3[j]), acc[j]);
        }
    }
    for (; i < o1; ++i) {
        int s = __builtin_nontemporal_load(dsrc + i);
        short8 a8 = __builtin_nontemporal_load((const short8*)(ebd + (size_t)i * HID + a_off));
        short8 x8 = *(const short8*)(xb + (size_t)s * H1 + x_off);
        #pragma unroll
        for (int j = 0; j < 8; ++j)
            acc[j] = fmaf(bf2f((u16)a8[j]), bf2f((u16)x8[j]), acc[j]);
    }
    u16 pk[8];
    #pragma unroll
    for (int j = 0; j < 8; ++j) pk[j] = f2bf(acc[j]);
    __builtin_nontemporal_store(*(const short8*)pk, (short8*)(aggb + (size_t)wid * H1 + x_off));
}

// ---------------- inverse denominator, layer 2 (16 threads per src) ----------------
__global__ __launch_bounds__(256) void s2sum_k(
    const u16* __restrict__ ebd2, const int* __restrict__ src_off, const int* __restrict__ src_list,
    float* __restrict__ inv2)
{
    int t = threadIdx.x;
    int g = blockIdx.x * 16 + (t >> 4), c = t & 15;
    if (g >= N_NODES) return;
    int o0 = src_off[g], o1 = src_off[g + 1];
    float sum = 0.f;
    for (int i = o0; i < o1; ++i) {
        int sl = src_list[i];
        sum += bf2f(ebd2[(size_t)sl * NCLS + c]);
    }
    inv2[(size_t)g * NCLS + c] = 1.f / (sum + 1e-16f);
}

// ---------------- message pass 2 (16 threads per dst), sequential slots ----------------
__global__ __launch_bounds__(256) void msg2_k(
    const u16* __restrict__ ebd2, const float* __restrict__ inv2,
    const float* __restrict__ xh2, const int* __restrict__ dsrc,
    const int* __restrict__ dst_off, float* __restrict__ agg2)
{
    int t = threadIdx.x;
    int g = blockIdx.x * 16 + (t >> 4), c = t & 15;
    if (g >= N_NODES) return;
    int o0 = dst_off[g], o1 = dst_off[g + 1];
    float acc = 0.f;
    for (int i = o0; i < o1; ++i) {
        int s = dsrc[i];
        float a = bf2f(ebd2[(size_t)i * NCLS + c]) * inv2[(size_t)s * NCLS + c];
        acc = fmaf(a, xh2[(size_t)s * NCLS + c], acc);
    }
    agg2[(size_t)g * NCLS + c] = acc;
}

// ---------------- final: o = agg2 + bias2 + alpha*p2; log_softmax ----------------
__global__ __launch_bounds__(256) void final_k(
    const float* __restrict__ agg2, const float* __restrict__ ep,
    const float* __restrict__ pw1, const float* __restrict__ pw2,
    const float* __restrict__ pb2, const float* __restrict__ bias,
    const float* __restrict__ alpha_p, float* __restrict__ out)
{
    __shared__ float s1w[256], s2w[256], sb[16], sbias[16];
    const int t = threadIdx.x;
    s1w[t] = pw1[t];
    s2w[t] = pw2[t];
    if (t < 16) { sb[t] = pb2[t]; sbias[t] = bias[t]; }
    __syncthreads();
    const int v = blockIdx.x * 256 + t;
    if (v >= N_NODES) return;
    float alpha = *alpha_p;
    float e_[16];
    #pragma unroll
    for (int j4 = 0; j4 < 16; j4 += 4) {
        float4 vv = *(const float4*)(ep + (size_t)v * 16 + j4);
        e_[j4] = vv.x; e_[j4 + 1] = vv.y; e_[j4 + 2] = vv.z; e_[j4 + 3] = vv.w;
    }
    float t2[16];
    #pragma unroll
    for (int c = 0; c < 16; ++c) {
        float s = 0.f;
        #pragma unroll
        for (int j = 0; j < 16; ++j) s = fmaf(e_[j], s1w[j * 16 + c], s);
        t2[c] = s > 0.f ? s : 0.2f * s;
    }
    float o[16];
    #pragma unroll
    for (int c4 = 0; c4 < 16; c4 += 4) {
        float4 ag = *(const float4*)(agg2 + (size_t)v * 16 + c4);
        float agv[4] = {ag.x, ag.y, ag.z, ag.w};
        #pragma unroll
        for (int q = 0; q < 4; ++q) {
            int c = c4 + q;
            float p = sb[c];
            #pragma unroll
            for (int j = 0; j < 16; ++j) p = fmaf(t2[j], s2w[j * 16 + c], p);
            p = p > 0.f ? p : 0.01f * p;
            o[c] = agv[q] + sbias[c] + alpha * p;
        }
    }
    float mx = o[0];
    #pragma unroll
    for (int c = 1; c < 16; ++c) mx = fmaxf(mx, o[c]);
    float se = 0.f;
    #pragma unroll
    for (int c = 0; c < 16; ++c) se += expf(o[c] - mx);
    float lse = mx + logf(se);
    #pragma unroll
    for (int c4 = 0; c4 < 16; c4 += 4)
        *(float4*)(out + (size_t)v * 16 + c4) =
            make_float4(o[c4] - lse, o[c4 + 1] - lse, o[c4 + 2] - lse, o[c4 + 3] - lse);
}

extern "C" void kernel_launch(void* const* d_in, const int* in_sizes, int n_in,
                              void* d_out, int out_size, void* d_ws, size_t ws_size,
                              hipStream_t stream) {
    const float* x    = (const float*)d_in[0];
    const int*   ei   = (const int*)d_in[1];
    const float* alpha= (const float*)d_in[2];
    const float* kr   = (const float*)d_in[3];
    const float* ep   = (const float*)d_in[4];
    const float* W1   = (const float*)d_in[5];
    const float* h1w1 = (const float*)d_in[6];
    const float* h1w2 = (const float*)d_in[7];
    const float* h1b2 = (const float*)d_in[8];
    const float* p1w1 = (const float*)d_in[9];
    const float* p1w2 = (const float*)d_in[10];
    const float* p1b2 = (const float*)d_in[11];
    const float* b1   = (const float*)d_in[12];
    const float* W2   = (const float*)d_in[13];
    const float* h2w1 = (const float*)d_in[14];
    const float* h2w2 = (const float*)d_in[15];
    const float* h2b2 = (const float*)d_in[16];
    const float* p2w1 = (const float*)d_in[17];
    const float* p2w2 = (const float*)d_in[18];
    const float* p2b2 = (const float*)d_in[19];
    const float* b2   = (const float*)d_in[20];
    float* out = (float*)d_out;

    // ---- workspace bump allocator (~242 MB) ----
    char* p = (char*)d_ws;
    auto alloc = [&](size_t bytes) { char* r = p; p += (bytes + 255) & ~(size_t)255; return r; };

    char* r0    = alloc((size_t)64 * M_PAD * 16);          // 51.25 MB: xb (row-major bf16 N x 512), then t1p (frag-major)
    u16*  xb    = (u16*)r0;
    u16*  t1p   = (u16*)r0;
    u16*  aggb  = (u16*)alloc((size_t)N_NODES * H1 * 2);   // 51.2 MB bf16
    char* ebr   = alloc((size_t)E_TOT * HID * 2);          // 83.2 MB: ebd (dst-ordered), then hb (Nx512)
    u16*  ebd   = (u16*)ebr;
    u16*  hb    = (u16*)ebr;
    u16*  ebd2  = (u16*)alloc((size_t)E_TOT * NCLS * 2);   // 20.8 MB
    u16*  xp    = (u16*)alloc((size_t)16 * M_PAD * 16);    // 12.81 MB: xp (frag-major x)
    u16*  W1p   = (u16*)alloc((size_t)16 * H1 * 16);       // 128 KB
    u16*  p1w2p = (u16*)alloc((size_t)64 * H1 * 16);       // 512 KB
    u16*  w1f   = (u16*)alloc(2048 * 2);                   // mlp1 w1 frags
    u16*  w2f   = (u16*)alloc(4096 * 2);                   // mlp1 w2 frags
    u16*  w3f   = (u16*)alloc(512 * 2);                    // mlp2 w1 frags
    u16*  w4f   = (u16*)alloc(512 * 2);                    // mlp2 w2 frags
    int* src_cnt  = (int*)alloc(N_NODES * 4);
    int* dst_cnt  = (int*)alloc(N_NODES * 4);
    int* src_cur  = (int*)alloc(N_NODES * 4);
    int* dst_cur  = (int*)alloc(N_NODES * 4);
    int* partials = (int*)alloc(2 * NBLK * 4);
    int* src_off  = (int*)alloc((N_NODES + 1) * 4);
    int* dst_off  = (int*)alloc((N_NODES + 1) * 4);
    int* src_list = (int*)alloc((size_t)E_TOT * 4);        // dst-slot ids grouped by src
    int* rkd      = (int*)alloc((size_t)E_TOT * 4);        // e -> dst slot
    int* dsrc     = (int*)alloc((size_t)E_TOT * 4);        // dst slot -> src node
    float* xh2  = (float*)alloc((size_t)N_NODES * NCLS * 4);
    float* agg2 = (float*)alloc((size_t)N_NODES * NCLS * 4);
    float* inv2 = (float*)alloc((size_t)N_NODES * NCLS * 4);

    const dim3 blk(256);
    const int EB = (E_TOT + 255) / 256;
    const int WB = (N_NODES * 64 + 255) / 256;
    const int GB16 = (N_NODES + 15) / 16;
    const dim3 gmm(512 / 128, M_PAD / 128);                 // (4, 391)
    const int MLPB = (E_TOT / 16 + 3) / 4;

    // ---- CSR build + weight/layout conversion ----
    hipMemsetAsync(src_cnt, 0, (char*)partials - (char*)src_cnt, stream);
    count_k<<<EB, blk, 0, stream>>>(ei, src_cnt, dst_cnt);
    scanA_k<<<2 * NBLK, blk, 0, stream>>>(src_cnt, dst_cnt, partials);
    scanB_k<<<1, 512, 0, stream>>>(partials);
    scanC_k<<<2 * NBLK, blk, 0, stream>>>(src_cnt, dst_cnt, partials, src_off, dst_off);
    fill_csr_k<<<EB, blk, 0, stream>>>(ei, src_off, dst_off, src_cur, dst_cur, src_list, rkd, dsrc);
    conv_a_k<<<(16 * M_PAD + 255) / 256, blk, 0, stream>>>(x, xp, N_NODES, M_PAD, F_IN);
    conv_b_k<<<(16 * H1 + 255) / 256, blk, 0, stream>>>(W1, W1p, F_IN, H1);
    conv_b_k<<<(64 * H1 + 255) / 256, blk, 0, stream>>>(p1w2, p1w2p, H1, H1);
    wfrag_all_k<<<28, blk, 0, stream>>>(h1w1, h1w2, h2w1, h2w2, w1f, w2f, w3f, w4f);

    // ---- layer 1 ----
    mfma_gemm_k<0><<<gmm, blk, 0, stream>>>(xp, W1p, xb, N_NODES, M_PAD, H1, F_IN,
                                            nullptr, nullptr, nullptr, nullptr);
    edge_mlps_k<<<MLPB, blk, 0, stream>>>(kr, rkd, w1f, w2f, h1b2, w3f, w4f, h2b2, ebd, ebd2);
    s1inv_k<<<WB, blk, 0, stream>>>(ebd, src_off, src_list, xb);   // xb <- xb * inv (in place)
    msg1_k<<<WB, blk, 0, stream>>>(ebd, xb, dsrc, dst_off, aggb);
    gemm_t1_k<<<dim3(8, (N_NODES + 63) / 64), blk, 0, stream>>>(ep, p1w1, t1p);   // overwrites xb region
    mfma_gemm_k<3><<<gmm, blk, 0, stream>>>(t1p, p1w2p, hb, N_NODES, M_PAD, H1, H1,
                                            p1b2, aggb, b1, alpha);               // hb overwrites ebd region

    // ---- layer 2 ----
    gemm_n16_k<<<(N_NODES + 15) / 16, blk, 0, stream>>>(hb, W2, xh2, N_NODES, H1);
    s2sum_k<<<GB16, blk, 0, stream>>>(ebd2, src_off, src_list, inv2);
    msg2_k<<<GB16, blk, 0, stream>>>(ebd2, inv2, xh2, dsrc, dst_off, agg2);
    final_k<<<(N_NODES + 255) / 256, blk, 0, stream>>>(agg2, ep, p2w1, p2w2, p2b2, b2, alpha, out);
}

// Round 9
// 681.013 us; speedup vs baseline: 2.0534x; 1.0574x over previous
//
#include <hip/hip_runtime.h>
#include <math.h>

#define N_NODES 50000
#define M_PAD   50048    // N_NODES padded to multiple of 128 for MFMA tiles
#define N_EDGES 600000
#define E_TOT   650000   // N_EDGES + N_NODES (self loops appended)
#define F_IN    128
#define HID     64
#define HEADS   8
#define H1      512      // HEADS*HID
#define NCLS    16
#define NC      16
#define NCP     16
#define NBLK    ((N_NODES + 255) / 256)   // 196 scan blocks per array

typedef unsigned short u16;
typedef unsigned char  u8;
typedef __attribute__((ext_vector_type(8))) short short8;   // 8 bf16 = 4 VGPRs (MFMA A/B frag)
typedef __attribute__((ext_vector_type(4))) float f32x4;    // MFMA C/D frag
typedef __attribute__((ext_vector_type(2))) float f32x2;

__device__ __forceinline__ float bf2f(u16 h) {
    return __uint_as_float(((unsigned)h) << 16);
}
__device__ __forceinline__ u16 f2bf(float f) {
    unsigned u = __float_as_uint(f);
    u += 0x7fffu + ((u >> 16) & 1u);
    return (u16)(u >> 16);
}
__device__ __forceinline__ int edge_src(const int* __restrict__ ei, int e) {
    return (e < N_EDGES) ? ei[e] : (e - N_EDGES);
}
__device__ __forceinline__ int edge_dst(const int* __restrict__ ei, int e) {
    return (e < N_EDGES) ? ei[N_EDGES + e] : (e - N_EDGES);
}

// ---------------- CSR build ----------------
__global__ __launch_bounds__(256) void count_k(const int* __restrict__ ei,
                                               int* __restrict__ src_cnt, int* __restrict__ dst_cnt) {
    int e = blockIdx.x * 256 + threadIdx.x;
    if (e >= E_TOT) return;
    atomicAdd(&src_cnt[edge_src(ei, e)], 1);
    atomicAdd(&dst_cnt[edge_dst(ei, e)], 1);
}

// Phase A: per-block partial sums. grid = 2*NBLK (src blocks, then dst blocks).
__global__ __launch_bounds__(256) void scanA_k(const int* __restrict__ src_cnt,
                                               const int* __restrict__ dst_cnt,
                                               int* __restrict__ partials) {
    int pass = blockIdx.x >= NBLK;
    int b = blockIdx.x - pass * NBLK;
    const int* cnt = pass ? dst_cnt : src_cnt;
    int idx = b * 256 + threadIdx.x;
    int v = (idx < N_NODES) ? cnt[idx] : 0;
    __shared__ int red[4];
    #pragma unroll
    for (int off = 32; off; off >>= 1) v += __shfl_down(v, off, 64);
    if ((threadIdx.x & 63) == 0) red[threadIdx.x >> 6] = v;
    __syncthreads();
    if (threadIdx.x == 0) partials[blockIdx.x] = red[0] + red[1] + red[2] + red[3];
}

// Phase B: two independent exclusive scans of NBLK partials (src seg, dst seg), one block.
__global__ __launch_bounds__(512) void scanB_k(int* __restrict__ partials) {
    __shared__ int lds[512];
    int t = threadIdx.x;           // 512 threads: t<256 -> src segment, else dst
    int seg = t >> 8, i = t & 255;
    int v = (i < NBLK) ? partials[seg * NBLK + i] : 0;
    lds[t] = v;
    __syncthreads();
    for (int d = 1; d < 256; d <<= 1) {
        int x = (i >= d) ? lds[seg * 256 + i - d] : 0;
        __syncthreads();
        lds[t] += x;
        __syncthreads();
    }
    if (i < NBLK) partials[seg * NBLK + i] = lds[t] - v;   // exclusive
}

// Phase C: block-local exclusive scan + block offset -> off[]; off[N]=E_TOT constant.
__global__ __launch_bounds__(256) void scanC_k(const int* __restrict__ src_cnt,
                                               const int* __restrict__ dst_cnt,
                                               const int* __restrict__ partials,
                                               int* __restrict__ src_off, int* __restrict__ dst_off) {
    int pass = blockIdx.x >= NBLK;
    int b = blockIdx.x - pass * NBLK;
    const int* cnt = pass ? dst_cnt : src_cnt;
    int* off = pass ? dst_off : src_off;
    int base = partials[blockIdx.x];
    __shared__ int lds[256];
    int t = threadIdx.x;
    int idx = b * 256 + t;
    int v = (idx < N_NODES) ? cnt[idx] : 0;
    lds[t] = v;
    __syncthreads();
    for (int d = 1; d < 256; d <<= 1) {
        int x = (t >= d) ? lds[t - d] : 0;
        __syncthreads();
        lds[t] += x;
        __syncthreads();
    }
    if (idx < N_NODES) off[idx] = base + lds[t] - v;
    if (b == 0 && t == 0) off[N_NODES] = E_TOT;
}

// fill: rkd[e] = slot of e in dst-CSR; dsrc[slot] = src node; src_list[src slot] = dst-slot id
__global__ __launch_bounds__(256) void fill_csr_k(const int* __restrict__ ei,
                                                  const int* __restrict__ src_off, const int* __restrict__ dst_off,
                                                  int* __restrict__ src_cur, int* __restrict__ dst_cur,
                                                  int* __restrict__ src_list, int* __restrict__ rkd,
                                                  int* __restrict__ dsrc) {
    int e = blockIdx.x * 256 + threadIdx.x;
    if (e >= E_TOT) return;
    int s = edge_src(ei, e), d = edge_dst(ei, e);
    int pd = atomicAdd(&dst_cur[d], 1);
    int rd = dst_off[d] + pd;
    rkd[e] = rd;
    dsrc[rd] = s;
    int ps = atomicAdd(&src_cur[s], 1);
    src_list[src_off[s] + ps] = rd;
}

// ---------------- layout converters ----------------
// f32 [M][K] row-major -> bf16 fragment-major Ap[K/8][Mp][8]; pad rows zeroed
__global__ __launch_bounds__(256) void conv_a_k(const float* __restrict__ A, u16* __restrict__ Ap,
                                                int M, int Mp, int K) {
    int i = blockIdx.x * 256 + threadIdx.x;
    int total = (K >> 3) * Mp;
    if (i >= total) return;
    int r = i % Mp;
    int kb = i / Mp;
    u16* o = Ap + (size_t)i * 8;
    u16 tmp[8];
    if (r < M) {
        const float* a = A + (size_t)r * K + kb * 8;
        #pragma unroll
        for (int j = 0; j < 8; ++j) tmp[j] = f2bf(a[j]);
    } else {
        #pragma unroll
        for (int j = 0; j < 8; ++j) tmp[j] = 0;
    }
    *(ushort4*)o = *(ushort4*)tmp;
    *(ushort4*)(o + 4) = *(ushort4*)(tmp + 4);
}

// f32 [K][N] row-major -> bf16 fragment-major Bp[K/8][N][8] (Bp[kb][n][j] = B[kb*8+j][n])
__global__ __launch_bounds__(256) void conv_b_k(const float* __restrict__ B, u16* __restrict__ Bp,
                                                int K, int N) {
    int i = blockIdx.x * 256 + threadIdx.x;
    int total = (K >> 3) * N;
    if (i >= total) return;
    int n = i % N;
    int kb = i / N;
    u16 tmp[8];
    #pragma unroll
    for (int j = 0; j < 8; ++j) tmp[j] = f2bf(B[(size_t)(kb * 8 + j) * N + n]);
    u16* o = Bp + (size_t)i * 8;
    *(ushort4*)o = *(ushort4*)tmp;
    *(ushort4*)(o + 4) = *(ushort4*)(tmp + 4);
}

// all 4 edge-MLP weight tables -> per-lane B-frag layout, one launch
__device__ __forceinline__ void wfrag_one(const float* W, u16* o, int i, int K, int N) {
    int j = i & 7, lane = (i >> 3) & 63, rest = i >> 9;
    int nt = rest % (N / 16), ks = rest / (N / 16);
    int lm = lane & 15, quad = lane >> 4;
    int k = ks * 32 + quad * 8 + j, n = nt * 16 + lm;
    o[i] = (k < K) ? f2bf(W[(size_t)k * N + n]) : (u16)0;
}
__global__ __launch_bounds__(256) void wfrag_all_k(
    const float* __restrict__ h1w1, const float* __restrict__ h1w2,
    const float* __restrict__ h2w1, const float* __restrict__ h2w2,
    u16* __restrict__ w1f, u16* __restrict__ w2f,
    u16* __restrict__ w3f, u16* __restrict__ w4f) {
    int i = blockIdx.x * 256 + threadIdx.x;   // total 2048+4096+512+512 = 7168
    if (i < 2048)      wfrag_one(h1w1, w1f, i, 16, 64);          // Kpad 32, N 64
    else if (i < 6144) wfrag_one(h1w2, w2f, i - 2048, 64, 64);   // Kpad 64, N 64
    else if (i < 6656) wfrag_one(h2w1, w3f, i - 6144, 16, 16);
    else if (i < 7168) wfrag_one(h2w2, w4f, i - 6656, 16, 16);
}

// ---------------- MFMA GEMM: C[M][N] = epi(Ap @ Bp), frag-major operands, no LDS ----------------
template<int EPI>
__global__ __launch_bounds__(256) void mfma_gemm_k(
    const u16* __restrict__ Ap, const u16* __restrict__ Bp, u16* __restrict__ C,
    int M, int Mp, int Nn, int K,
    const float* __restrict__ bias, const u16* __restrict__ extra,
    const float* __restrict__ bias2, const float* __restrict__ alpha_p)
{
    const int t = threadIdx.x;
    const int wave = t >> 6, lane = t & 63;
    const int wm = (wave >> 1) * 64, wn = (wave & 1) * 64;
    const int bm = blockIdx.y * 128, bn = blockIdx.x * 128;
    const int lm = lane & 15, quad = lane >> 4;

    size_t rbase[4], cbase[4];
    #pragma unroll
    for (int mi = 0; mi < 4; ++mi) rbase[mi] = (size_t)(bm + wm + mi * 16 + lm) * 8;
    #pragma unroll
    for (int nj = 0; nj < 4; ++nj) cbase[nj] = (size_t)(bn + wn + nj * 16 + lm) * 8;

    f32x4 acc[4][4] = {};

    for (int k0 = 0; k0 < K; k0 += 32) {
        int kb = (k0 >> 3) + quad;
        size_t abase = (size_t)kb * Mp * 8;
        size_t bbase = (size_t)kb * Nn * 8;
        short8 af[4], bf_[4];
        #pragma unroll
        for (int mi = 0; mi < 4; ++mi) af[mi] = *(const short8*)(Ap + abase + rbase[mi]);
        #pragma unroll
        for (int nj = 0; nj < 4; ++nj) bf_[nj] = *(const short8*)(Bp + bbase + cbase[nj]);
        #pragma unroll
        for (int mi = 0; mi < 4; ++mi)
            #pragma unroll
            for (int nj = 0; nj < 4; ++nj)
                acc[mi][nj] = __builtin_amdgcn_mfma_f32_16x16x32_bf16(af[mi], bf_[nj], acc[mi][nj], 0, 0, 0);
    }

    // C/D layout: col = lane&15, row = quad*4 + reg
    const int orow = bm + wm + quad * 4;
    const int ocol = bn + wn + lm;
    if (EPI == 0) {
        #pragma unroll
        for (int mi = 0; mi < 4; ++mi)
            #pragma unroll
            for (int r = 0; r < 4; ++r) {
                int rr = orow + mi * 16 + r;
                if (rr >= M) continue;
                #pragma unroll
                for (int nj = 0; nj < 4; ++nj)
                    C[(size_t)rr * Nn + ocol + nj * 16] = f2bf(acc[mi][nj][r]);
            }
    } else {
        float alpha = *alpha_p;
        #pragma unroll
        for (int mi = 0; mi < 4; ++mi)
            #pragma unroll
            for (int r = 0; r < 4; ++r) {
                int rr = orow + mi * 16 + r;
                if (rr >= M) continue;
                #pragma unroll
                for (int nj = 0; nj < 4; ++nj) {
                    int c = ocol + nj * 16;
                    float v = acc[mi][nj][r] + bias[c];
                    v = v > 0.f ? v : 0.01f * v;
                    float o = bf2f(extra[(size_t)rr * Nn + c]) + bias2[c] + alpha * v;
                    o = fmaxf(o, 0.f);
                    C[(size_t)rr * Nn + c] = f2bf(o);
                }
            }
    }
}

// ---------------- t1 = leaky(ep @ p1w1, 0.2), K=16, written in frag-major Ap layout ----------------
__global__ __launch_bounds__(256) void gemm_t1_k(
    const float* __restrict__ ep, const float* __restrict__ W, u16* __restrict__ t1p)
{
    __shared__ float Bs[16][64];
    const int bm = blockIdx.y * 64, bn = blockIdx.x * 64;
    const int t = threadIdx.x;
    const int tx = t & 15, ty = t >> 4;
    *(float4*)&Bs[t >> 4][(t & 15) * 4] = *(const float4*)&W[(size_t)(t >> 4) * H1 + bn + (t & 15) * 4];
    __syncthreads();
    const int r0 = bm + ty * 4;
    const int c0 = bn + tx * 4;
    for (int i = 0; i < 4; ++i) {
        int r = r0 + i;
        if (r >= N_NODES) continue;
        float av[16];
        #pragma unroll
        for (int j4 = 0; j4 < 16; j4 += 4) {
            float4 v = *(const float4*)(ep + (size_t)r * NCP + j4);
            av[j4] = v.x; av[j4 + 1] = v.y; av[j4 + 2] = v.z; av[j4 + 3] = v.w;
        }
        u16 pk[4];
        #pragma unroll
        for (int q = 0; q < 4; ++q) {
            float s = 0.f;
            #pragma unroll
            for (int k = 0; k < 16; ++k) s = fmaf(av[k], Bs[k][tx * 4 + q], s);
            s = s > 0.f ? s : 0.2f * s;
            pk[q] = f2bf(s);
        }
        u16* o = t1p + ((size_t)(c0 >> 3) * M_PAD + r) * 8 + (c0 & 7);
        *(ushort4*)o = *(ushort4*)pk;
    }
}

// ---------------- N=16 GEMM (xh2 = h @ W_src2), bf16 A, K multiple of 64 ----------------
__global__ __launch_bounds__(256) void gemm_n16_k(
    const u16* __restrict__ A, const float* __restrict__ B, float* __restrict__ C,
    int M, int K)
{
    __shared__ float As[16][64];   // [row][k]
    __shared__ float Bs[64][16];   // [k][col]
    const int row0 = blockIdx.x * 16;
    const int t = threadIdx.x;
    const int r = t >> 4, c = t & 15;
    const int ar = t >> 4, ak4 = (t & 15) * 4;
    const int bk = t >> 2, bc4 = (t & 3) * 4;
    float acc = 0.f;
    for (int k0 = 0; k0 < K; k0 += 64) {
        float4 av = make_float4(0.f, 0.f, 0.f, 0.f);
        if (row0 + ar < M) {
            ushort4 h4 = *(const ushort4*)(A + (size_t)(row0 + ar) * K + k0 + ak4);
            av = make_float4(bf2f(h4.x), bf2f(h4.y), bf2f(h4.z), bf2f(h4.w));
        }
        *(float4*)&As[ar][ak4] = av;
        *(float4*)&Bs[bk][bc4] = *(const float4*)(B + (size_t)(k0 + bk) * 16 + bc4);
        __syncthreads();
        #pragma unroll
        for (int kk = 0; kk < 64; ++kk)
            acc = fmaf(As[r][kk], Bs[kk][c], acc);
        __syncthreads();
    }
    if (row0 + r < M) C[(size_t)(row0 + r) * 16 + c] = acc;
}

// ---------------- fused MFMA edge MLPs -> dst-slot-ordered ebd / ebd2 ----------------
#define TSTR 72   // LDS tile row stride in bf16 elems (144 B: 16B-aligned frag reads, <=2-way banks)
__global__ __launch_bounds__(256) void edge_mlps_k(
    const float* __restrict__ kr, const int* __restrict__ rkd,
    const u16* __restrict__ w1f, const u16* __restrict__ w2f, const float* __restrict__ b2a,
    const u16* __restrict__ w3f, const u16* __restrict__ w4f, const float* __restrict__ b2b,
    u16* __restrict__ ebd, u16* __restrict__ ebd2)
{
    __shared__ __align__(16) u16 T[4][16 * TSTR];
    const int t = threadIdx.x, wv = t >> 6, lane = t & 63;
    const int lm = lane & 15, quad = lane >> 4;
    const int tile = blockIdx.x * 4 + wv;
    const int e0 = tile * 16;
    if (e0 >= E_TOT) return;
    u16* Tw = T[wv];

    // weight fragments -> VGPRs (per-lane)
    short8 W1[4], W2[2][4];
    #pragma unroll
    for (int nt = 0; nt < 4; ++nt) W1[nt] = *(const short8*)(w1f + ((size_t)nt * 64 + lane) * 8);
    #pragma unroll
    for (int ks = 0; ks < 2; ++ks)
        #pragma unroll
        for (int nt = 0; nt < 4; ++nt)
            W2[ks][nt] = *(const short8*)(w2f + (((size_t)ks * 4 + nt) * 64 + lane) * 8);
    short8 W3 = *(const short8*)(w3f + (size_t)lane * 8);
    short8 W4 = *(const short8*)(w4f + (size_t)lane * 8);
    float b2av[4];
    #pragma unroll
    for (int nt = 0; nt < 4; ++nt) b2av[nt] = b2a[nt * 16 + lm];
    float b2bv = b2b[lm];

    // A-frag from kr: edge m = e0+lm, k = quad*8+j (K=16 zero-padded to 32)
    short8 af = {};
    if (quad < 2) {
        const float* kp = kr + (size_t)(e0 + lm) * NC + quad * 8;
        float4 v0 = *(const float4*)kp;
        float4 v1 = *(const float4*)(kp + 4);
        u16 tmp[8] = {f2bf(v0.x), f2bf(v0.y), f2bf(v0.z), f2bf(v0.w),
                      f2bf(v1.x), f2bf(v1.y), f2bf(v1.z), f2bf(v1.w)};
        af = *(const short8*)tmp;
    }

    // ---- MLP1 layer 1: [16 edges x 64] = kr @ w1, leaky 0.2 ----
    f32x4 a1[4] = {};
    #pragma unroll
    for (int nt = 0; nt < 4; ++nt)
        a1[nt] = __builtin_amdgcn_mfma_f32_16x16x32_bf16(af, W1[nt], a1[nt], 0, 0, 0);
    #pragma unroll
    for (int nt = 0; nt < 4; ++nt)
        #pragma unroll
        for (int r = 0; r < 4; ++r) {
            float v = a1[nt][r];
            v = v > 0.f ? v : 0.2f * v;
            Tw[(quad * 4 + r) * TSTR + nt * 16 + lm] = f2bf(v);
        }
    __builtin_amdgcn_s_waitcnt(0);   // drain LDS writes before same-wave reads

    // ---- MLP1 layer 2: K=64 from LDS tile ----
    short8 a2[2];
    #pragma unroll
    for (int ks = 0; ks < 2; ++ks)
        a2[ks] = *(const short8*)&Tw[lm * TSTR + ks * 32 + quad * 8];
    f32x4 c2[4] = {};
    #pragma unroll
    for (int nt = 0; nt < 4; ++nt)
        #pragma unroll
        for (int ks = 0; ks < 2; ++ks)
            c2[nt] = __builtin_amdgcn_mfma_f32_16x16x32_bf16(a2[ks], W2[ks][nt], c2[nt], 0, 0, 0);
    // epilogue: + b2, exp -> LDS
    #pragma unroll
    for (int nt = 0; nt < 4; ++nt)
        #pragma unroll
        for (int r = 0; r < 4; ++r)
            Tw[(quad * 4 + r) * TSTR + nt * 16 + lm] = f2bf(__expf(c2[nt][r] + b2av[nt]));
    __builtin_amdgcn_s_waitcnt(0);
    // repack: 16B row-chunks scattered to dst-slot rows (8 lanes per 128B row)
    #pragma unroll
    for (int p = 0; p < 2; ++p) {
        int c = p * 64 + lane;
        int row = c >> 3, off = (c & 7) * 8;
        int rd = rkd[e0 + row];
        short8 v = *(const short8*)&Tw[row * TSTR + off];
        *(short8*)(ebd + (size_t)rd * HID + off) = v;
    }

    // ---- MLP2 (16->16->16), reuses kr A-frag ----
    f32x4 b1 = __builtin_amdgcn_mfma_f32_16x16x32_bf16(af, W3, (f32x4){}, 0, 0, 0);
    __builtin_amdgcn_s_waitcnt(0);   // eb repack reads done before overwrite
    #pragma unroll
    for (int r = 0; r < 4; ++r) {
        float v = b1[r];
        v = v > 0.f ? v : 0.2f * v;
        Tw[(quad * 4 + r) * TSTR + lm] = f2bf(v);
    }
    __builtin_amdgcn_s_waitcnt(0);
    // A-frag: cols 16..31 hold stale finite values, but W4 is zero there -> no effect
    short8 a3 = *(const short8*)&Tw[lm * TSTR + quad * 8];
    f32x4 c3 = __builtin_amdgcn_mfma_f32_16x16x32_bf16(a3, W4, (f32x4){}, 0, 0, 0);
    #pragma unroll
    for (int r = 0; r < 4; ++r)
        Tw[(quad * 4 + r) * TSTR + lm] = f2bf(__expf(c3[r] + b2bv));
    __builtin_amdgcn_s_waitcnt(0);
    if (lane < 32) {
        int row = lane >> 1, off = (lane & 1) * 8;
        int rd = rkd[e0 + row];
        short8 v = *(const short8*)&Tw[row * TSTR + off];
        *(short8*)(ebd2 + (size_t)rd * NCLS + off) = v;
    }
}

// ---------------- layer-1 softmax denom + pre-scaled fp8 gather table (wave per src) ----------------
// Phase 1 (lane = channel c in [0,64)): denom over out-edges -> inv, broadcast via LDS.
// Phase 2 (lane = 8 contiguous channels): y = xh * inv -> fp8 e4m3, packed into the FIRST
// 512 B of the node's own 1 KB xb row (in-place safe: wave's loads precede its stores).
__global__ __launch_bounds__(256) void s1inv_k(
    const u16* __restrict__ ebd, const int* __restrict__ src_off, const int* __restrict__ src_list,
    u16* __restrict__ xb)
{
    __shared__ float sinv[4][64];
    int gid = blockIdx.x * 256 + threadIdx.x;
    int wid = gid >> 6, lane = gid & 63, wv = threadIdx.x >> 6;
    if (wid >= N_NODES) return;
    int o0 = src_off[wid], o1 = src_off[wid + 1];
    float s0 = 0.f, s1 = 0.f, s2 = 0.f, s3 = 0.f;
    int i = o0;
    for (; i + 3 < o1; i += 4) {
        int l0 = src_list[i], l1 = src_list[i + 1], l2 = src_list[i + 2], l3 = src_list[i + 3];
        s0 += bf2f(ebd[(size_t)l0 * HID + lane]);
        s1 += bf2f(ebd[(size_t)l1 * HID + lane]);
        s2 += bf2f(ebd[(size_t)l2 * HID + lane]);
        s3 += bf2f(ebd[(size_t)l3 * HID + lane]);
    }
    for (; i < o1; ++i) {
        int sl = src_list[i];
        s0 += bf2f(ebd[(size_t)sl * HID + lane]);
    }
    sinv[wv][lane] = 1.f / (((s0 + s1) + (s2 + s3)) + 1e-16f);
    __builtin_amdgcn_s_waitcnt(0);   // LDS writes visible wave-wide

    const u16* xr = xb + (size_t)wid * H1 + lane * 8;    // 8 contiguous channels
    short8 x8 = *(const short8*)xr;
    float y[8];
    #pragma unroll
    for (int j = 0; j < 8; ++j)
        y[j] = bf2f((u16)x8[j]) * sinv[wv][(lane * 8 + j) & 63];
    int p0 = 0, p1 = 0;
    p0 = __builtin_amdgcn_cvt_pk_fp8_f32(y[0], y[1], p0, false);
    p0 = __builtin_amdgcn_cvt_pk_fp8_f32(y[2], y[3], p0, true);
    p1 = __builtin_amdgcn_cvt_pk_fp8_f32(y[4], y[5], p1, false);
    p1 = __builtin_amdgcn_cvt_pk_fp8_f32(y[6], y[7], p1, true);
    uint2 pk; pk.x = (unsigned)p0; pk.y = (unsigned)p1;
    *(uint2*)((u8*)xb + (size_t)wid * (H1 * 2) + lane * 8) = pk;   // fp8 row in first 512 B
}

// ---------------- message pass 1: wave per dst, sequential slots, fp8 gather, unroll 4 ----------------
__global__ __launch_bounds__(256) void msg1_k(
    const u16* __restrict__ ebd, const u8* __restrict__ xq,
    const int* __restrict__ dsrc, const int* __restrict__ dst_off,
    u16* __restrict__ aggb)
{
    int gid = blockIdx.x * 256 + threadIdx.x;
    int wid = gid >> 6, lane = gid & 63;
    if (wid >= N_NODES) return;
    int o0 = dst_off[wid], o1 = dst_off[wid + 1];
    const int a_off = (lane & 7) * 8;     // alpha channel block (ch = lane*8+j mod 64)
    float acc[8] = {};
    int i = o0;
    for (; i + 3 < o1; i += 4) {
        int s0 = __builtin_nontemporal_load(dsrc + i);
        int s1 = __builtin_nontemporal_load(dsrc + i + 1);
        int s2 = __builtin_nontemporal_load(dsrc + i + 2);
        int s3 = __builtin_nontemporal_load(dsrc + i + 3);
        short8 a0 = __builtin_nontemporal_load((const short8*)(ebd + (size_t)i * HID + a_off));
        short8 a1 = __builtin_nontemporal_load((const short8*)(ebd + (size_t)(i + 1) * HID + a_off));
        short8 a2 = __builtin_nontemporal_load((const short8*)(ebd + (size_t)(i + 2) * HID + a_off));
        short8 a3 = __builtin_nontemporal_load((const short8*)(ebd + (size_t)(i + 3) * HID + a_off));
        uint2 q0 = *(const uint2*)(xq + (size_t)s0 * 1024 + lane * 8);
        uint2 q1 = *(const uint2*)(xq + (size_t)s1 * 1024 + lane * 8);
        uint2 q2 = *(const uint2*)(xq + (size_t)s2 * 1024 + lane * 8);
        uint2 q3 = *(const uint2*)(xq + (size_t)s3 * 1024 + lane * 8);
        const uint2 qs[4] = {q0, q1, q2, q3};
        const short8 as[4] = {a0, a1, a2, a3};
        #pragma unroll
        for (int u = 0; u < 4; ++u) {
            f32x2 d0 = __builtin_amdgcn_cvt_pk_f32_fp8((int)qs[u].x, false);
            f32x2 d1 = __builtin_amdgcn_cvt_pk_f32_fp8((int)qs[u].x, true);
            f32x2 d2 = __builtin_amdgcn_cvt_pk_f32_fp8((int)qs[u].y, false);
            f32x2 d3 = __builtin_amdgcn_cvt_pk_f32_fp8((int)qs[u].y, true);
            float xv[8] = {d0.x, d0.y, d1.x, d1.y, d2.x, d2.y, d3.x, d3.y};
            #pragma unroll
            for (int j = 0; j < 8; ++j)
                acc[j] = fmaf(bf2f((u16)as[u][j]), xv[j], acc[j]);
        }
    }
    for (; i < o1; ++i) {
        int s = __builtin_nontemporal_load(dsrc + i);
        short8 a8 = __builtin_nontemporal_load((const short8*)(ebd + (size_t)i * HID + a_off));
        uint2 q = *(const uint2*)(xq + (size_t)s * 1024 + lane * 8);
        f32x2 d0 = __builtin_amdgcn_cvt_pk_f32_fp8((int)q.x, false);
        f32x2 d1 = __builtin_amdgcn_cvt_pk_f32_fp8((int)q.x, true);
        f32x2 d2 = __builtin_amdgcn_cvt_pk_f32_fp8((int)q.y, false);
        f32x2 d3 = __builtin_amdgcn_cvt_pk_f32_fp8((int)q.y, true);
        float xv[8] = {d0.x, d0.y, d1.x, d1.y, d2.x, d2.y, d3.x, d3.y};
        #pragma unroll
        for (int j = 0; j < 8; ++j)
            acc[j] = fmaf(bf2f((u16)a8[j]), xv[j], acc[j]);
    }
    u16 pk[8];
    #pragma unroll
    for (int j = 0; j < 8; ++j) pk[j] = f2bf(acc[j]);
    __builtin_nontemporal_store(*(const short8*)pk, (short8*)(aggb + (size_t)wid * H1 + lane * 8));
}

// ---------------- inverse denominator, layer 2 (16 threads per src) ----------------
__global__ __launch_bounds__(256) void s2sum_k(
    const u16* __restrict__ ebd2, const int* __restrict__ src_off, const int* __restrict__ src_list,
    float* __restrict__ inv2)
{
    int t = threadIdx.x;
    int g = blockIdx.x * 16 + (t >> 4), c = t & 15;
    if (g >= N_NODES) return;
    int o0 = src_off[g], o1 = src_off[g + 1];
    float sum = 0.f;
    for (int i = o0; i < o1; ++i) {
        int sl = src_list[i];
        sum += bf2f(ebd2[(size_t)sl * NCLS + c]);
    }
    inv2[(size_t)g * NCLS + c] = 1.f / (sum + 1e-16f);
}

// ---------------- message pass 2 (16 threads per dst), sequential slots ----------------
__global__ __launch_bounds__(256) void msg2_k(
    const u16* __restrict__ ebd2, const float* __restrict__ inv2,
    const float* __restrict__ xh2, const int* __restrict__ dsrc,
    const int* __restrict__ dst_off, float* __restrict__ agg2)
{
    int t = threadIdx.x;
    int g = blockIdx.x * 16 + (t >> 4), c = t & 15;
    if (g >= N_NODES) return;
    int o0 = dst_off[g], o1 = dst_off[g + 1];
    float acc = 0.f;
    for (int i = o0; i < o1; ++i) {
        int s = dsrc[i];
        float a = bf2f(ebd2[(size_t)i * NCLS + c]) * inv2[(size_t)s * NCLS + c];
        acc = fmaf(a, xh2[(size_t)s * NCLS + c], acc);
    }
    agg2[(size_t)g * NCLS + c] = acc;
}

// ---------------- final: o = agg2 + bias2 + alpha*p2; log_softmax ----------------
__global__ __launch_bounds__(256) void final_k(
    const float* __restrict__ agg2, const float* __restrict__ ep,
    const float* __restrict__ pw1, const float* __restrict__ pw2,
    const float* __restrict__ pb2, const float* __restrict__ bias,
    const float* __restrict__ alpha_p, float* __restrict__ out)
{
    __shared__ float s1w[256], s2w[256], sb[16], sbias[16];
    const int t = threadIdx.x;
    s1w[t] = pw1[t];
    s2w[t] = pw2[t];
    if (t < 16) { sb[t] = pb2[t]; sbias[t] = bias[t]; }
    __syncthreads();
    const int v = blockIdx.x * 256 + t;
    if (v >= N_NODES) return;
    float alpha = *alpha_p;
    float e_[16];
    #pragma unroll
    for (int j4 = 0; j4 < 16; j4 += 4) {
        float4 vv = *(const float4*)(ep + (size_t)v * 16 + j4);
        e_[j4] = vv.x; e_[j4 + 1] = vv.y; e_[j4 + 2] = vv.z; e_[j4 + 3] = vv.w;
    }
    float t2[16];
    #pragma unroll
    for (int c = 0; c < 16; ++c) {
        float s = 0.f;
        #pragma unroll
        for (int j = 0; j < 16; ++j) s = fmaf(e_[j], s1w[j * 16 + c], s);
        t2[c] = s > 0.f ? s : 0.2f * s;
    }
    float o[16];
    #pragma unroll
    for (int c4 = 0; c4 < 16; c4 += 4) {
        float4 ag = *(const float4*)(agg2 + (size_t)v * 16 + c4);
        float agv[4] = {ag.x, ag.y, ag.z, ag.w};
        #pragma unroll
        for (int q = 0; q < 4; ++q) {
            int c = c4 + q;
            float p = sb[c];
            #pragma unroll
            for (int j = 0; j < 16; ++j) p = fmaf(t2[j], s2w[j * 16 + c], p);
            p = p > 0.f ? p : 0.01f * p;
            o[c] = agv[q] + sbias[c] + alpha * p;
        }
    }
    float mx = o[0];
    #pragma unroll
    for (int c = 1; c < 16; ++c) mx = fmaxf(mx, o[c]);
    float se = 0.f;
    #pragma unroll
    for (int c = 0; c < 16; ++c) se += expf(o[c] - mx);
    float lse = mx + logf(se);
    #pragma unroll
    for (int c4 = 0; c4 < 16; c4 += 4)
        *(float4*)(out + (size_t)v * 16 + c4) =
            make_float4(o[c4] - lse, o[c4 + 1] - lse, o[c4 + 2] - lse, o[c4 + 3] - lse);
}

extern "C" void kernel_launch(void* const* d_in, const int* in_sizes, int n_in,
                              void* d_out, int out_size, void* d_ws, size_t ws_size,
                              hipStream_t stream) {
    const float* x    = (const float*)d_in[0];
    const int*   ei   = (const int*)d_in[1];
    const float* alpha= (const float*)d_in[2];
    const float* kr   = (const float*)d_in[3];
    const float* ep   = (const float*)d_in[4];
    const float* W1   = (const float*)d_in[5];
    const float* h1w1 = (const float*)d_in[6];
    const float* h1w2 = (const float*)d_in[7];
    const float* h1b2 = (const float*)d_in[8];
    const float* p1w1 = (const float*)d_in[9];
    const float* p1w2 = (const float*)d_in[10];
    const float* p1b2 = (const float*)d_in[11];
    const float* b1   = (const float*)d_in[12];
    const float* W2   = (const float*)d_in[13];
    const float* h2w1 = (const float*)d_in[14];
    const float* h2w2 = (const float*)d_in[15];
    const float* h2b2 = (const float*)d_in[16];
    const float* p2w1 = (const float*)d_in[17];
    const float* p2w2 = (const float*)d_in[18];
    const float* p2b2 = (const float*)d_in[19];
    const float* b2   = (const float*)d_in[20];
    float* out = (float*)d_out;

    // ---- workspace bump allocator (~242 MB) ----
    char* p = (char*)d_ws;
    auto alloc = [&](size_t bytes) { char* r = p; p += (bytes + 255) & ~(size_t)255; return r; };

    char* r0    = alloc((size_t)64 * M_PAD * 16);          // 51.25 MB: xb (bf16 Nx512 -> fp8 table), then t1p
    u16*  xb    = (u16*)r0;
    u16*  t1p   = (u16*)r0;
    u16*  aggb  = (u16*)alloc((size_t)N_NODES * H1 * 2);   // 51.2 MB bf16
    char* ebr   = alloc((size_t)E_TOT * HID * 2);          // 83.2 MB: ebd (dst-ordered), then hb (Nx512)
    u16*  ebd   = (u16*)ebr;
    u16*  hb    = (u16*)ebr;
    u16*  ebd2  = (u16*)alloc((size_t)E_TOT * NCLS * 2);   // 20.8 MB
    u16*  xp    = (u16*)alloc((size_t)16 * M_PAD * 16);    // 12.81 MB: xp (frag-major x)
    u16*  W1p   = (u16*)alloc((size_t)16 * H1 * 16);       // 128 KB
    u16*  p1w2p = (u16*)alloc((size_t)64 * H1 * 16);       // 512 KB
    u16*  w1f   = (u16*)alloc(2048 * 2);                   // mlp1 w1 frags
    u16*  w2f   = (u16*)alloc(4096 * 2);                   // mlp1 w2 frags
    u16*  w3f   = (u16*)alloc(512 * 2);                    // mlp2 w1 frags
    u16*  w4f   = (u16*)alloc(512 * 2);                    // mlp2 w2 frags
    int* src_cnt  = (int*)alloc(N_NODES * 4);
    int* dst_cnt  = (int*)alloc(N_NODES * 4);
    int* src_cur  = (int*)alloc(N_NODES * 4);
    int* dst_cur  = (int*)alloc(N_NODES * 4);
    int* partials = (int*)alloc(2 * NBLK * 4);
    int* src_off  = (int*)alloc((N_NODES + 1) * 4);
    int* dst_off  = (int*)alloc((N_NODES + 1) * 4);
    int* src_list = (int*)alloc((size_t)E_TOT * 4);        // dst-slot ids grouped by src
    int* rkd      = (int*)alloc((size_t)E_TOT * 4);        // e -> dst slot
    int* dsrc     = (int*)alloc((size_t)E_TOT * 4);        // dst slot -> src node
    float* xh2  = (float*)alloc((size_t)N_NODES * NCLS * 4);
    float* agg2 = (float*)alloc((size_t)N_NODES * NCLS * 4);
    float* inv2 = (float*)alloc((size_t)N_NODES * NCLS * 4);

    const dim3 blk(256);
    const int EB = (E_TOT + 255) / 256;
    const int WB = (N_NODES * 64 + 255) / 256;
    const int GB16 = (N_NODES + 15) / 16;
    const dim3 gmm(512 / 128, M_PAD / 128);                 // (4, 391)
    const int MLPB = (E_TOT / 16 + 3) / 4;

    // ---- CSR build + weight/layout conversion ----
    hipMemsetAsync(src_cnt, 0, (char*)partials - (char*)src_cnt, stream);
    count_k<<<EB, blk, 0, stream>>>(ei, src_cnt, dst_cnt);
    scanA_k<<<2 * NBLK, blk, 0, stream>>>(src_cnt, dst_cnt, partials);
    scanB_k<<<1, 512, 0, stream>>>(partials);
    scanC_k<<<2 * NBLK, blk, 0, stream>>>(src_cnt, dst_cnt, partials, src_off, dst_off);
    fill_csr_k<<<EB, blk, 0, stream>>>(ei, src_off, dst_off, src_cur, dst_cur, src_list, rkd, dsrc);
    conv_a_k<<<(16 * M_PAD + 255) / 256, blk, 0, stream>>>(x, xp, N_NODES, M_PAD, F_IN);
    conv_b_k<<<(16 * H1 + 255) / 256, blk, 0, stream>>>(W1, W1p, F_IN, H1);
    conv_b_k<<<(64 * H1 + 255) / 256, blk, 0, stream>>>(p1w2, p1w2p, H1, H1);
    wfrag_all_k<<<28, blk, 0, stream>>>(h1w1, h1w2, h2w1, h2w2, w1f, w2f, w3f, w4f);

    // ---- layer 1 ----
    mfma_gemm_k<0><<<gmm, blk, 0, stream>>>(xp, W1p, xb, N_NODES, M_PAD, H1, F_IN,
                                            nullptr, nullptr, nullptr, nullptr);
    edge_mlps_k<<<MLPB, blk, 0, stream>>>(kr, rkd, w1f, w2f, h1b2, w3f, w4f, h2b2, ebd, ebd2);
    s1inv_k<<<WB, blk, 0, stream>>>(ebd, src_off, src_list, xb);   // xb row -> fp8 y-table (first 512 B)
    msg1_k<<<WB, blk, 0, stream>>>(ebd, (const u8*)xb, dsrc, dst_off, aggb);
    gemm_t1_k<<<dim3(8, (N_NODES + 63) / 64), blk, 0, stream>>>(ep, p1w1, t1p);   // overwrites xb region
    mfma_gemm_k<3><<<gmm, blk, 0, stream>>>(t1p, p1w2p, hb, N_NODES, M_PAD, H1, H1,
                                            p1b2, aggb, b1, alpha);               // hb overwrites ebd region

    // ---- layer 2 ----
    gemm_n16_k<<<(N_NODES + 15) / 16, blk, 0, stream>>>(hb, W2, xh2, N_NODES, H1);
    s2sum_k<<<GB16, blk, 0, stream>>>(ebd2, src_off, src_list, inv2);
    msg2_k<<<GB16, blk, 0, stream>>>(ebd2, inv2, xh2, dsrc, dst_off, agg2);
    final_k<<<(N_NODES + 255) / 256, blk, 0, stream>>>(agg2, ep, p2w1, p2w2, p2b2, b2, alpha, out);
}